// Round 1
// baseline (17436.147 us; speedup 1.0000x reference)
//
#include <hip/hip_runtime.h>

#define NN 1000000
#define NE 4000000
#define NG 25000
#define BN_EPS 1e-5f

// ---- workspace layout (bytes) ----
// GNN phase : U @0 (128e6), S @128e6 (128e6), Y @256e6 (128e6)
// stats @384e6 (320 floats), XC @384004096 (25.6e6)
// head phase: T3 @0 (294.4e6, after pool), H1 @0 (after xt-gemm), H2 @320e6
static const size_t OFF_U = 0;
static const size_t OFF_S = 128000000;
static const size_t OFF_Y = 256000000;
static const size_t OFF_STATS = 384000000;
static const size_t OFF_XC = 384004096;
static const size_t OFF_T3 = 0;
static const size_t OFF_H1 = 0;
static const size_t OFF_H2 = 320000000;

// ---------------- GNN kernels ----------------

// layer0: u = x @ W1 (78->32), s = u + b1
__global__ __launch_bounds__(256) void k_mlp1_first(
    const float* __restrict__ x, const float* __restrict__ W1, const float* __restrict__ b1,
    float* __restrict__ u, float* __restrict__ s)
{
  __shared__ float Wt[78 * 33];
  __shared__ float xt_[8 * 79];
  const int t = threadIdx.x;
  for (int id = t; id < 78 * 32; id += 256) {
    int k = id >> 5, c = id & 31;
    Wt[k * 33 + c] = W1[id];
  }
  const int c = t & 31, nl = t >> 5;
  const float b1v = b1[c];
  const int ntiles = NN / 8;
  for (int tile = blockIdx.x; tile < ntiles; tile += gridDim.x) {
    const int n0 = tile * 8;
    __syncthreads();
    for (int id = t; id < 8 * 78; id += 256) {
      int r = id / 78, k = id - r * 78;
      xt_[r * 79 + k] = x[(size_t)n0 * 78 + id];
    }
    __syncthreads();
    float acc = 0.f;
    const float* xr = xt_ + nl * 79;
#pragma unroll
    for (int k = 0; k < 78; ++k) acc = fmaf(xr[k], Wt[k * 33 + c], acc);
    u[(size_t)(n0 + nl) * 32 + c] = acc;
    s[(size_t)(n0 + nl) * 32 + c] = acc + b1v;
  }
}

// layers 1..4: h = BN(y_prev); u = h @ W1; s = u + b1
__global__ __launch_bounds__(256) void k_mlp1_mid(
    const float* __restrict__ y, const float* __restrict__ stats,
    const float* __restrict__ gamma, const float* __restrict__ beta,
    const float* __restrict__ W1, const float* __restrict__ b1,
    float* __restrict__ u, float* __restrict__ s)
{
  __shared__ float Wt[32 * 33];
  __shared__ float ht[8 * 33];
  const int t = threadIdx.x;
  for (int id = t; id < 1024; id += 256) {
    int k = id >> 5, c = id & 31;
    Wt[k * 33 + c] = W1[id];
  }
  const int c = t & 31, nl = t >> 5;
  const float b1v = b1[c];
  const float mu = stats[c] * (1.f / NN);
  float var = fmaxf(stats[32 + c] * (1.f / NN) - mu * mu, 0.f);
  const float sc = gamma[c] * rsqrtf(var + BN_EPS);
  const float sh = beta[c] - mu * sc;
  const int ntiles = NN / 8;
  for (int tile = blockIdx.x; tile < ntiles; tile += gridDim.x) {
    const int n0 = tile * 8;
    __syncthreads();
    {
      float raw = y[(size_t)n0 * 32 + t];
      ht[nl * 33 + c] = raw * sc + sh;
    }
    __syncthreads();
    float acc = 0.f;
    const float* hr = ht + nl * 33;
#pragma unroll
    for (int k = 0; k < 32; ++k) acc = fmaf(hr[k], Wt[k * 33 + c], acc);
    u[(size_t)(n0 + nl) * 32 + c] = acc;
    s[(size_t)(n0 + nl) * 32 + c] = acc + b1v;
  }
}

// edge aggregation: s[dst] += u[src]  (32 ch, 8 lanes/edge x float4)
__global__ __launch_bounds__(256) void k_edge(
    const int* __restrict__ ei, const float* __restrict__ u, float* __restrict__ s)
{
  __shared__ int es[32], ed[32];
  const int t = threadIdx.x;
  const int e0 = blockIdx.x * 32;
  if (t < 32) es[t] = ei[e0 + t];
  else if (t < 64) ed[t - 32] = ei[NE + e0 + (t - 32)];
  __syncthreads();
  const int k = t >> 3, c0 = (t & 7) * 4;
  const float4 v = *(const float4*)(u + (size_t)es[k] * 32 + c0);
  float* sp = s + (size_t)ed[k] * 32 + c0;
  unsafeAtomicAdd(sp + 0, v.x);
  unsafeAtomicAdd(sp + 1, v.y);
  unsafeAtomicAdd(sp + 2, v.z);
  unsafeAtomicAdd(sp + 3, v.w);
}

// y = relu(relu(s) @ W2 + b2); accumulate per-channel sum/sumsq
__global__ __launch_bounds__(256) void k_mlp2_stats(
    const float* __restrict__ s, const float* __restrict__ W2, const float* __restrict__ b2,
    float* __restrict__ y, float* __restrict__ stats)
{
  __shared__ float Wt[32 * 33];
  __shared__ float ht[8 * 33];
  __shared__ float red[256];
  const int t = threadIdx.x;
  for (int id = t; id < 1024; id += 256) {
    int k = id >> 5, c = id & 31;
    Wt[k * 33 + c] = W2[id];
  }
  const int c = t & 31, nl = t >> 5;
  const float b2v = b2[c];
  float rs = 0.f, rq = 0.f;
  const int ntiles = NN / 8;
  for (int tile = blockIdx.x; tile < ntiles; tile += gridDim.x) {
    const int n0 = tile * 8;
    __syncthreads();
    {
      float v = s[(size_t)n0 * 32 + t];
      ht[nl * 33 + c] = fmaxf(v, 0.f);
    }
    __syncthreads();
    float acc = b2v;
    const float* hr = ht + nl * 33;
#pragma unroll
    for (int k = 0; k < 32; ++k) acc = fmaf(hr[k], Wt[k * 33 + c], acc);
    acc = fmaxf(acc, 0.f);
    y[(size_t)(n0 + nl) * 32 + c] = acc;
    rs += acc;
    rq += acc * acc;
  }
  rs += __shfl_down(rs, 32);
  rq += __shfl_down(rq, 32);
  __syncthreads();
  const int wv_ = t >> 6, lane = t & 63;
  if (lane < 32) {
    red[wv_ * 32 + lane] = rs;
    red[128 + wv_ * 32 + lane] = rq;
  }
  __syncthreads();
  if (t < 32) {
    float a = red[t] + red[32 + t] + red[64 + t] + red[96 + t];
    float b = red[128 + t] + red[160 + t] + red[192 + t] + red[224 + t];
    unsafeAtomicAdd(&stats[t], a);
    unsafeAtomicAdd(&stats[32 + t], b);
  }
}

// per-graph pool (batch is sorted -> binary search range) + xd = relu(pooled@Wxd+b)
__global__ __launch_bounds__(64) void k_pool_xd(
    const float* __restrict__ y, const int* __restrict__ batch,
    const float* __restrict__ stats, const float* __restrict__ gamma,
    const float* __restrict__ beta, const float* __restrict__ Wxd,
    const float* __restrict__ bxd, float* __restrict__ xc)
{
  const int g = blockIdx.x, t = threadIdx.x;
  int lo = 0, n = NN;
  while (n > 0) {
    int h = n >> 1, m = lo + h;
    if (batch[m] < g) { lo = m + 1; n -= h + 1; } else n = h;
  }
  int hi = lo;
  n = NN - lo;
  while (n > 0) {
    int h = n >> 1, m = hi + h;
    if (batch[m] < g + 1) { hi = m + 1; n -= h + 1; } else n = h;
  }
  const int c = t & 31;
  const float mu = stats[4 * 64 + c] * (1.f / NN);
  float var = fmaxf(stats[4 * 64 + 32 + c] * (1.f / NN) - mu * mu, 0.f);
  const float sc = gamma[4 * 32 + c] * rsqrtf(var + BN_EPS);
  const float sh = beta[4 * 32 + c] - mu * sc;
  float acc = 0.f;
  for (int i = lo + (t >> 5); i < hi; i += 2) acc += y[(size_t)i * 32 + c];
  acc += __shfl_down(acc, 32);
  __shared__ float pl[32];
  if (t < 32) pl[t] = acc * sc + (float)(hi - lo) * sh;
  __syncthreads();
#pragma unroll
  for (int rep = 0; rep < 2; ++rep) {
    const int o = t + rep * 64;
    float a = bxd[o];
#pragma unroll
    for (int cc = 0; cc < 32; ++cc) a = fmaf(pl[cc], Wxd[cc * 128 + o], a);
    xc[(size_t)g * 256 + o] = fmaxf(a, 0.f);
  }
}

// ---------------- fused per-graph CNN ----------------
__global__ __launch_bounds__(256) void k_cnn(
    const float* __restrict__ xo,
    const float* __restrict__ w1, const float* __restrict__ b1,
    const float* __restrict__ w2, const float* __restrict__ b2,
    const float* __restrict__ w3, const float* __restrict__ b3,
    float* __restrict__ t3)
{
  __shared__ float lds[16008];  // 64032 B
  float* xot = lds;             // [0,744)
  float* w1s = lds + 744;       // 256
  float* b1s = lds + 1000;      // 32
  float* t1p = lds + 1032;      // [32][242]+pad -> [1032,8808)
  float* t2p = lds + 8808;      // [64][78]+pad  -> [8808,13832)
  float* w2t = lds + 13832;     // [64][33]      -> [13832,15944)
  float* b2s = lds + 15944;     // 64
  float* w3t = lds;             // conv3 phase: [128][65] -> [0,8320)
  float* b3s = lds + 8320;      // 128
  const int g = blockIdx.x, t = threadIdx.x;

  for (int i = t; i < 735; i += 256) xot[i] = xo[(size_t)g * 735 + i];
  w1s[t] = w1[t];
  if (t < 32) b1s[t] = b1[t];
  if (t < 64) b2s[t] = b2[t];
  __syncthreads();

  // conv1(1->32,k8) + relu + pool3 : 32 x 242 into t1p
  for (int o = t; o < 7744; o += 256) {
    const int c = o / 242, q = o - c * 242;
    const float* xp = xot + 3 * q;
    const float* wp = w1s + c * 8;
    float a0 = b1s[c], a1 = a0, a2 = a0;
#pragma unroll
    for (int tt = 0; tt < 8; ++tt) {
      const float w = wp[tt];
      a0 = fmaf(w, xp[tt], a0);
      a1 = fmaf(w, xp[tt + 1], a1);
      a2 = fmaf(w, xp[tt + 2], a2);
    }
    t1p[o] = fmaxf(fmaxf(fmaxf(a0, a1), a2), 0.f);
  }
  __syncthreads();

  // conv2(32->64,k8) + relu + pool3 : 64 x 78 into t2p
  {
    const int c2 = t >> 2, qg = t & 3;
#pragma unroll 1
    for (int chunk = 0; chunk < 2; ++chunk) {
      const int q0 = qg * 20 + chunk * 10;
      float acc[10][3];
#pragma unroll
      for (int j = 0; j < 10; ++j) {
        float b = b2s[c2];
        acc[j][0] = b; acc[j][1] = b; acc[j][2] = b;
      }
#pragma unroll 1
      for (int it = 0; it < 8; ++it) {
        __syncthreads();
        for (int id = t; id < 2048; id += 256) {
          const int cc = id >> 5, r = id & 31;
          w2t[cc * 33 + r] = w2[cc * 256 + it * 32 + r];
        }
        __syncthreads();
#pragma unroll 1
        for (int ii = 0; ii < 4; ++ii) {
          const int i = it * 4 + ii;
          float xv[37];
          const float* tp = t1p + i * 242 + 3 * q0;
#pragma unroll
          for (int jj = 0; jj < 37; ++jj) xv[jj] = tp[jj];
          float wv[8];
          const float* wp = w2t + c2 * 33 + ii * 8;
#pragma unroll
          for (int tt = 0; tt < 8; ++tt) wv[tt] = wp[tt];
#pragma unroll
          for (int j = 0; j < 10; ++j)
#pragma unroll
            for (int r = 0; r < 3; ++r) {
              float a = acc[j][r];
#pragma unroll
              for (int tt = 0; tt < 8; ++tt) a = fmaf(wv[tt], xv[3 * j + r + tt], a);
              acc[j][r] = a;
            }
        }
      }
#pragma unroll
      for (int j = 0; j < 10; ++j) {
        const int q = q0 + j;
        if (q < 78)
          t2p[c2 * 78 + q] = fmaxf(fmaxf(fmaxf(acc[j][0], acc[j][1]), acc[j][2]), 0.f);
      }
      __syncthreads();
    }
  }
  __syncthreads();

  // conv3(64->128,k8) + relu + pool3 : 128 x 23 -> t3 (flattened c*23+q)
  {
    const int c3 = t >> 1, qg = t & 1;
    const int q0 = qg * 12;
    if (t < 128) b3s[t] = b3[t];
    __syncthreads();
    float acc[12][3];
#pragma unroll
    for (int j = 0; j < 12; ++j) {
      float b = b3s[c3];
      acc[j][0] = b; acc[j][1] = b; acc[j][2] = b;
    }
#pragma unroll 1
    for (int it = 0; it < 8; ++it) {
      __syncthreads();
      for (int id = t; id < 8192; id += 256) {
        const int cc = id >> 6, r = id & 63;
        w3t[cc * 65 + r] = w3[cc * 512 + it * 64 + r];
      }
      __syncthreads();
#pragma unroll 1
      for (int ii = 0; ii < 8; ++ii) {
        const int i = it * 8 + ii;
        float xv[43];
        const float* tp = t2p + i * 78 + 3 * q0;
#pragma unroll
        for (int jj = 0; jj < 43; ++jj) xv[jj] = tp[jj];
        float wv[8];
        const float* wp = w3t + c3 * 65 + ii * 8;
#pragma unroll
        for (int tt = 0; tt < 8; ++tt) wv[tt] = wp[tt];
#pragma unroll
        for (int j = 0; j < 12; ++j)
#pragma unroll
          for (int r = 0; r < 3; ++r) {
            float a = acc[j][r];
#pragma unroll
            for (int tt = 0; tt < 8; ++tt) a = fmaf(wv[tt], xv[3 * j + r + tt], a);
            acc[j][r] = a;
          }
      }
    }
#pragma unroll
    for (int j = 0; j < 12; ++j) {
      const int q = q0 + j;
      if (q < 23)
        t3[(size_t)g * 2944 + c3 * 23 + q] =
            fmaxf(fmaxf(fmaxf(acc[j][0], acc[j][1]), acc[j][2]), 0.f);
    }
  }
}

// ---------------- generic tiled GEMM: C = [relu](A[M,K] @ W[K,N] + bias) ----------------
__global__ __launch_bounds__(256) void k_gemm(
    const float* __restrict__ A, int lda,
    const float* __restrict__ W, const float* __restrict__ bias,
    float* __restrict__ C, int ldc, int c_off,
    int M, int N, int K, int do_relu)
{
  __shared__ float As[64 * 17];
  __shared__ float Ws[16 * 64];
  const int t = threadIdx.x;
  const int m0 = blockIdx.x * 64, n0 = blockIdx.y * 64;
  const int tm = t >> 4, tn = t & 15;
  float acc[4][4] = {};
  const int lrow = t >> 2, lkq = (t & 3) * 4;
  const int wkr = t >> 4, wnc = (t & 15) * 4;
  for (int k0 = 0; k0 < K; k0 += 16) {
    float4 av = make_float4(0.f, 0.f, 0.f, 0.f);
    if (m0 + lrow < M) av = *(const float4*)(A + (size_t)(m0 + lrow) * lda + k0 + lkq);
    const float4 wv = *(const float4*)(W + (size_t)(k0 + wkr) * N + n0 + wnc);
    __syncthreads();
    As[lrow * 17 + lkq + 0] = av.x;
    As[lrow * 17 + lkq + 1] = av.y;
    As[lrow * 17 + lkq + 2] = av.z;
    As[lrow * 17 + lkq + 3] = av.w;
    *(float4*)(Ws + wkr * 64 + wnc) = wv;
    __syncthreads();
#pragma unroll
    for (int kk = 0; kk < 16; ++kk) {
      float a[4];
#pragma unroll
      for (int i_ = 0; i_ < 4; ++i_) a[i_] = As[(tm * 4 + i_) * 17 + kk];
      const float4 w = *(const float4*)(Ws + kk * 64 + tn * 4);
#pragma unroll
      for (int i_ = 0; i_ < 4; ++i_) {
        acc[i_][0] = fmaf(a[i_], w.x, acc[i_][0]);
        acc[i_][1] = fmaf(a[i_], w.y, acc[i_][1]);
        acc[i_][2] = fmaf(a[i_], w.z, acc[i_][2]);
        acc[i_][3] = fmaf(a[i_], w.w, acc[i_][3]);
      }
    }
  }
  const float4 bv = *(const float4*)(bias + n0 + tn * 4);
#pragma unroll
  for (int i_ = 0; i_ < 4; ++i_) {
    const int m = m0 + tm * 4 + i_;
    if (m < M) {
      float4 o;
      o.x = acc[i_][0] + bv.x;
      o.y = acc[i_][1] + bv.y;
      o.z = acc[i_][2] + bv.z;
      o.w = acc[i_][3] + bv.w;
      if (do_relu) {
        o.x = fmaxf(o.x, 0.f); o.y = fmaxf(o.y, 0.f);
        o.z = fmaxf(o.z, 0.f); o.w = fmaxf(o.w, 0.f);
      }
      *(float4*)(C + (size_t)m * ldc + c_off + n0 + tn * 4) = o;
    }
  }
}

// final 128 -> 1
__global__ __launch_bounds__(256) void k_out(
    const float* __restrict__ h2, const float* __restrict__ Wo,
    const float* __restrict__ bo, float* __restrict__ out)
{
  __shared__ float Ws_[128];
  const int t = threadIdx.x;
  if (t < 128) Ws_[t] = Wo[t];
  __syncthreads();
  const int g = blockIdx.x * 32 + (t >> 3), l = t & 7;
  float acc = 0.f;
  if (g < NG) {
    const float* hr = h2 + (size_t)g * 128 + l * 16;
    const float* wr = Ws_ + l * 16;
#pragma unroll
    for (int j = 0; j < 16; ++j) acc = fmaf(hr[j], wr[j], acc);
  }
  acc += __shfl_down(acc, 4, 8);
  acc += __shfl_down(acc, 2, 8);
  acc += __shfl_down(acc, 1, 8);
  if (l == 0 && g < NG) out[g] = acc + bo[0];
}

extern "C" void kernel_launch(void* const* d_in, const int* in_sizes, int n_in,
                              void* d_out, int out_size, void* d_ws, size_t ws_size,
                              hipStream_t stream) {
  const float* x    = (const float*)d_in[0];
  const int*   ei   = (const int*)d_in[1];
  const int*   batch= (const int*)d_in[2];
  const float* xo   = (const float*)d_in[3];
  const float* g1W1 = (const float*)d_in[4];
  const float* g1b1 = (const float*)d_in[5];
  const float* g1W2 = (const float*)d_in[6];
  const float* g1b2 = (const float*)d_in[7];
  const float* gsW1 = (const float*)d_in[8];
  const float* gsb1 = (const float*)d_in[9];
  const float* gsW2 = (const float*)d_in[10];
  const float* gsb2 = (const float*)d_in[11];
  const float* bng  = (const float*)d_in[12];
  const float* bnb  = (const float*)d_in[13];
  const float* Wxd  = (const float*)d_in[14];
  const float* bxd  = (const float*)d_in[15];
  const float* c1W  = (const float*)d_in[16];
  const float* c1b  = (const float*)d_in[17];
  const float* c2W  = (const float*)d_in[18];
  const float* c2b  = (const float*)d_in[19];
  const float* c3W  = (const float*)d_in[20];
  const float* c3b  = (const float*)d_in[21];
  const float* Wxt  = (const float*)d_in[22];
  const float* bxt  = (const float*)d_in[23];
  const float* W1f  = (const float*)d_in[24];
  const float* b1f  = (const float*)d_in[25];
  const float* W2f  = (const float*)d_in[26];
  const float* b2f  = (const float*)d_in[27];
  const float* Wo   = (const float*)d_in[28];
  const float* bo   = (const float*)d_in[29];

  char* ws = (char*)d_ws;
  float* U  = (float*)(ws + OFF_U);
  float* S  = (float*)(ws + OFF_S);
  float* Y  = (float*)(ws + OFF_Y);
  float* ST = (float*)(ws + OFF_STATS);
  float* XC = (float*)(ws + OFF_XC);
  float* T3 = (float*)(ws + OFF_T3);
  float* H1 = (float*)(ws + OFF_H1);
  float* H2 = (float*)(ws + OFF_H2);
  float* OUT = (float*)d_out;

  hipMemsetAsync(ST, 0, 5 * 64 * sizeof(float), stream);

  // layer 0
  k_mlp1_first<<<2048, 256, 0, stream>>>(x, g1W1, g1b1, U, S);
  k_edge<<<NE / 32, 256, 0, stream>>>(ei, U, S);
  k_mlp2_stats<<<2048, 256, 0, stream>>>(S, g1W2, g1b2, Y, ST + 0);
  // layers 1..4
  for (int l = 1; l <= 4; ++l) {
    k_mlp1_mid<<<2048, 256, 0, stream>>>(Y, ST + (l - 1) * 64, bng + (l - 1) * 32,
                                         bnb + (l - 1) * 32, gsW1 + (l - 1) * 1024,
                                         gsb1 + (l - 1) * 32, U, S);
    k_edge<<<NE / 32, 256, 0, stream>>>(ei, U, S);
    k_mlp2_stats<<<2048, 256, 0, stream>>>(S, gsW2 + (l - 1) * 1024, gsb2 + (l - 1) * 32,
                                           Y, ST + l * 64);
  }
  k_pool_xd<<<NG, 64, 0, stream>>>(Y, batch, ST, bng, bnb, Wxd, bxd, XC);
  k_cnn<<<NG, 256, 0, stream>>>(xo, c1W, c1b, c2W, c2b, c3W, c3b, T3);
  {
    dim3 grid((NG + 63) / 64, 128 / 64);
    k_gemm<<<grid, 256, 0, stream>>>(T3, 2944, Wxt, bxt, XC, 256, 128, NG, 128, 2944, 0);
  }
  {
    dim3 grid((NG + 63) / 64, 1024 / 64);
    k_gemm<<<grid, 256, 0, stream>>>(XC, 256, W1f, b1f, H1, 1024, 0, NG, 1024, 256, 1);
  }
  {
    dim3 grid((NG + 63) / 64, 128 / 64);
    k_gemm<<<grid, 256, 0, stream>>>(H1, 1024, W2f, b2f, H2, 128, 0, NG, 128, 1024, 1);
  }
  k_out<<<(NG + 31) / 32, 256, 0, stream>>>(H2, Wo, bo, OUT);
}

// Round 2
// 11935.326 us; speedup vs baseline: 1.4609x; 1.4609x over previous
//
#include <hip/hip_runtime.h>

#define NN 1000000
#define NE 4000000
#define NG 25000
#define BN_EPS 1e-5f

typedef unsigned short u16t;
typedef unsigned int u32t;
typedef __attribute__((ext_vector_type(8))) short bf16x8;
typedef __attribute__((ext_vector_type(4))) float f32x4;

__device__ inline u16t f2bf(float f) {
  u32t u = __float_as_uint(f);
  u32t r = (u + 0x7FFFu + ((u >> 16) & 1u)) >> 16;
  return (u16t)r;
}

// ---- workspace layout (bytes) ----
// GNN phase : U @0 (128e6), S @128e6 (128e6), Y @256e6 (128e6)
// stats @384e6 (320 floats), XC @384004096 (25.6e6)
// head phase: T3 @0 (294.4e6, after pool), WK @340e6 (weights bf16, prep'd after GNN),
//             H1 @0 (after xt-gemm), H2 @320e6
static const size_t OFF_U = 0;
static const size_t OFF_S = 128000000;
static const size_t OFF_Y = 256000000;
static const size_t OFF_STATS = 384000000;
static const size_t OFF_XC = 384004096;
static const size_t OFF_T3 = 0;
static const size_t OFF_WK = 340000000;  // 16B aligned; free during CNN+head phase
static const size_t OFF_H1 = 0;
static const size_t OFF_H2 = 320000000;

// ---------------- GNN kernels (unchanged) ----------------

__global__ __launch_bounds__(256) void k_mlp1_first(
    const float* __restrict__ x, const float* __restrict__ W1, const float* __restrict__ b1,
    float* __restrict__ u, float* __restrict__ s)
{
  __shared__ float Wt[78 * 33];
  __shared__ float xt_[8 * 79];
  const int t = threadIdx.x;
  for (int id = t; id < 78 * 32; id += 256) {
    int k = id >> 5, c = id & 31;
    Wt[k * 33 + c] = W1[id];
  }
  const int c = t & 31, nl = t >> 5;
  const float b1v = b1[c];
  const int ntiles = NN / 8;
  for (int tile = blockIdx.x; tile < ntiles; tile += gridDim.x) {
    const int n0 = tile * 8;
    __syncthreads();
    for (int id = t; id < 8 * 78; id += 256) {
      int r = id / 78, k = id - r * 78;
      xt_[r * 79 + k] = x[(size_t)n0 * 78 + id];
    }
    __syncthreads();
    float acc = 0.f;
    const float* xr = xt_ + nl * 79;
#pragma unroll
    for (int k = 0; k < 78; ++k) acc = fmaf(xr[k], Wt[k * 33 + c], acc);
    u[(size_t)(n0 + nl) * 32 + c] = acc;
    s[(size_t)(n0 + nl) * 32 + c] = acc + b1v;
  }
}

__global__ __launch_bounds__(256) void k_mlp1_mid(
    const float* __restrict__ y, const float* __restrict__ stats,
    const float* __restrict__ gamma, const float* __restrict__ beta,
    const float* __restrict__ W1, const float* __restrict__ b1,
    float* __restrict__ u, float* __restrict__ s)
{
  __shared__ float Wt[32 * 33];
  __shared__ float ht[8 * 33];
  const int t = threadIdx.x;
  for (int id = t; id < 1024; id += 256) {
    int k = id >> 5, c = id & 31;
    Wt[k * 33 + c] = W1[id];
  }
  const int c = t & 31, nl = t >> 5;
  const float b1v = b1[c];
  const float mu = stats[c] * (1.f / NN);
  float var = fmaxf(stats[32 + c] * (1.f / NN) - mu * mu, 0.f);
  const float sc = gamma[c] * rsqrtf(var + BN_EPS);
  const float sh = beta[c] - mu * sc;
  const int ntiles = NN / 8;
  for (int tile = blockIdx.x; tile < ntiles; tile += gridDim.x) {
    const int n0 = tile * 8;
    __syncthreads();
    {
      float raw = y[(size_t)n0 * 32 + t];
      ht[nl * 33 + c] = raw * sc + sh;
    }
    __syncthreads();
    float acc = 0.f;
    const float* hr = ht + nl * 33;
#pragma unroll
    for (int k = 0; k < 32; ++k) acc = fmaf(hr[k], Wt[k * 33 + c], acc);
    u[(size_t)(n0 + nl) * 32 + c] = acc;
    s[(size_t)(n0 + nl) * 32 + c] = acc + b1v;
  }
}

__global__ __launch_bounds__(256) void k_edge(
    const int* __restrict__ ei, const float* __restrict__ u, float* __restrict__ s)
{
  __shared__ int es[32], ed[32];
  const int t = threadIdx.x;
  const int e0 = blockIdx.x * 32;
  if (t < 32) es[t] = ei[e0 + t];
  else if (t < 64) ed[t - 32] = ei[NE + e0 + (t - 32)];
  __syncthreads();
  const int k = t >> 3, c0 = (t & 7) * 4;
  const float4 v = *(const float4*)(u + (size_t)es[k] * 32 + c0);
  float* sp = s + (size_t)ed[k] * 32 + c0;
  unsafeAtomicAdd(sp + 0, v.x);
  unsafeAtomicAdd(sp + 1, v.y);
  unsafeAtomicAdd(sp + 2, v.z);
  unsafeAtomicAdd(sp + 3, v.w);
}

__global__ __launch_bounds__(256) void k_mlp2_stats(
    const float* __restrict__ s, const float* __restrict__ W2, const float* __restrict__ b2,
    float* __restrict__ y, float* __restrict__ stats)
{
  __shared__ float Wt[32 * 33];
  __shared__ float ht[8 * 33];
  __shared__ float red[256];
  const int t = threadIdx.x;
  for (int id = t; id < 1024; id += 256) {
    int k = id >> 5, c = id & 31;
    Wt[k * 33 + c] = W2[id];
  }
  const int c = t & 31, nl = t >> 5;
  const float b2v = b2[c];
  float rs = 0.f, rq = 0.f;
  const int ntiles = NN / 8;
  for (int tile = blockIdx.x; tile < ntiles; tile += gridDim.x) {
    const int n0 = tile * 8;
    __syncthreads();
    {
      float v = s[(size_t)n0 * 32 + t];
      ht[nl * 33 + c] = fmaxf(v, 0.f);
    }
    __syncthreads();
    float acc = b2v;
    const float* hr = ht + nl * 33;
#pragma unroll
    for (int k = 0; k < 32; ++k) acc = fmaf(hr[k], Wt[k * 33 + c], acc);
    acc = fmaxf(acc, 0.f);
    y[(size_t)(n0 + nl) * 32 + c] = acc;
    rs += acc;
    rq += acc * acc;
  }
  rs += __shfl_down(rs, 32);
  rq += __shfl_down(rq, 32);
  __syncthreads();
  const int wv_ = t >> 6, lane = t & 63;
  if (lane < 32) {
    red[wv_ * 32 + lane] = rs;
    red[128 + wv_ * 32 + lane] = rq;
  }
  __syncthreads();
  if (t < 32) {
    float a = red[t] + red[32 + t] + red[64 + t] + red[96 + t];
    float b = red[128 + t] + red[160 + t] + red[192 + t] + red[224 + t];
    unsafeAtomicAdd(&stats[t], a);
    unsafeAtomicAdd(&stats[32 + t], b);
  }
}

__global__ __launch_bounds__(64) void k_pool_xd(
    const float* __restrict__ y, const int* __restrict__ batch,
    const float* __restrict__ stats, const float* __restrict__ gamma,
    const float* __restrict__ beta, const float* __restrict__ Wxd,
    const float* __restrict__ bxd, float* __restrict__ xc)
{
  const int g = blockIdx.x, t = threadIdx.x;
  int lo = 0, n = NN;
  while (n > 0) {
    int h = n >> 1, m = lo + h;
    if (batch[m] < g) { lo = m + 1; n -= h + 1; } else n = h;
  }
  int hi = lo;
  n = NN - lo;
  while (n > 0) {
    int h = n >> 1, m = hi + h;
    if (batch[m] < g + 1) { hi = m + 1; n -= h + 1; } else n = h;
  }
  const int c = t & 31;
  const float mu = stats[4 * 64 + c] * (1.f / NN);
  float var = fmaxf(stats[4 * 64 + 32 + c] * (1.f / NN) - mu * mu, 0.f);
  const float sc = gamma[4 * 32 + c] * rsqrtf(var + BN_EPS);
  const float sh = beta[4 * 32 + c] - mu * sc;
  float acc = 0.f;
  for (int i = lo + (t >> 5); i < hi; i += 2) acc += y[(size_t)i * 32 + c];
  acc += __shfl_down(acc, 32);
  __shared__ float pl[32];
  if (t < 32) pl[t] = acc * sc + (float)(hi - lo) * sh;
  __syncthreads();
#pragma unroll
  for (int rep = 0; rep < 2; ++rep) {
    const int o = t + rep * 64;
    float a = bxd[o];
#pragma unroll
    for (int cc = 0; cc < 32; ++cc) a = fmaf(pl[cc], Wxd[cc * 128 + o], a);
    xc[(size_t)g * 256 + o] = fmaxf(a, 0.f);
  }
}

// ---------------- CNN weight prep: bf16, K reordered to t*Cin+ci ----------------
__global__ __launch_bounds__(256) void k_prep(
    const float* __restrict__ w2, const float* __restrict__ w3,
    u16t* __restrict__ W2k, u16t* __restrict__ W3k)
{
  int i = blockIdx.x * 256 + threadIdx.x;
  if (i < 64 * 256) {
    int c2 = i >> 8, kk = i & 255, tt = kk >> 5, ci = kk & 31;
    W2k[i] = f2bf(w2[c2 * 256 + ci * 8 + tt]);
  }
  if (i < 128 * 512) {
    int c3 = i >> 9, kk = i & 511, tt = kk >> 6, ci = kk & 63;
    W3k[i] = f2bf(w3[c3 * 512 + ci * 8 + tt]);
  }
}

// ---------------- fused per-graph CNN, conv2/conv3 via MFMA ----------------
// LDS map (bytes):
//  XOT  f32[768]          @0      (735 valid, rest zero)
//  W1s  f32[256]          @3072
//  b2s  f32[64]           @4096
//  b3s  f32[128]          @4352
//  T1T  bf16[248][40]     @4864   (pos-major conv1 out; rows 242.. zero)  | T2T bf16[88][72] overlay
//  S2   bf16[240][72]     @24704  (conv2 raw out, pos-major)              | S3  bf16[80][136] overlay
__global__ __launch_bounds__(256) void k_cnn(
    const float* __restrict__ xo,
    const float* __restrict__ w1, const float* __restrict__ b1,
    const u16t* __restrict__ W2k, const float* __restrict__ b2,
    const u16t* __restrict__ W3k, const float* __restrict__ b3,
    float* __restrict__ t3)
{
  __shared__ __align__(16) char smem[59264];
  float* xot = (float*)(smem);
  float* w1s = (float*)(smem + 3072);
  float* b2s = (float*)(smem + 4096);
  float* b3s = (float*)(smem + 4352);
  short* T1T = (short*)(smem + 4864);
  short* T2T = (short*)(smem + 4864);
  short* S2  = (short*)(smem + 24704);
  short* S3  = (short*)(smem + 24704);

  const int g = blockIdx.x, t = threadIdx.x;
  const int w = t >> 6, l = t & 63, col = l & 15, kg = l >> 4;

  for (int i = t; i < 768; i += 256) xot[i] = (i < 735) ? xo[(size_t)g * 735 + i] : 0.f;
  w1s[t] = w1[t];
  if (t < 64) b2s[t] = b2[t];
  if (t < 128) b3s[t] = b3[t];
  if (t < 192) {  // zero T1T pad rows 242..247 (ch 0..31)
    int r = 242 + (t >> 5), c = t & 31;
    T1T[r * 40 + c] = 0;
  }
  __syncthreads();

  // conv1 (1->32, k8) fp32 + relu + pool3 -> T1T bf16 [pos][ch]
  {
    const int c = t >> 3, qg = t & 7;
    float wv[8];
#pragma unroll
    for (int j = 0; j < 8; ++j) wv[j] = w1s[c * 8 + j];
    const float bias = b1[c];
    const int q0 = qg * 31, qe = (q0 + 31 < 242) ? q0 + 31 : 242;
#pragma unroll 1
    for (int qc = q0; qc < qe; qc += 10) {
      const int cnt = (qe - qc < 10) ? qe - qc : 10;
      float xv[37];
#pragma unroll
      for (int j = 0; j < 37; ++j) xv[j] = xot[3 * qc + j];
#pragma unroll
      for (int j0 = 0; j0 < 10; ++j0) {
        if (j0 < cnt) {
          float a0 = bias, a1 = bias, a2 = bias;
#pragma unroll
          for (int tt = 0; tt < 8; ++tt) {
            a0 = fmaf(wv[tt], xv[3 * j0 + tt], a0);
            a1 = fmaf(wv[tt], xv[3 * j0 + 1 + tt], a1);
            a2 = fmaf(wv[tt], xv[3 * j0 + 2 + tt], a2);
          }
          float m = fmaxf(fmaxf(a0, a1), fmaxf(a2, 0.f));
          T1T[(qc + j0) * 40 + c] = (short)f2bf(m);
        }
      }
    }
  }
  __syncthreads();

  // conv2 (32->64, k8) MFMA: M=64(ch) x N=240(pos) x K=256. Waves split N.
  {
    f32x4 acc[4][4];
#pragma unroll
    for (int m = 0; m < 4; ++m)
#pragma unroll
      for (int i = 0; i < 4; ++i) acc[m][i] = (f32x4){0.f, 0.f, 0.f, 0.f};
    const int nt0 = w * 4;
#pragma unroll 1
    for (int kk = 0; kk < 8; ++kk) {
      bf16x8 am[4];
#pragma unroll
      for (int m = 0; m < 4; ++m)
        am[m] = *(const bf16x8*)(W2k + ((m * 16 + col) << 8) + kk * 32 + kg * 8);
#pragma unroll
      for (int i = 0; i < 4; ++i) {
        const int nt = nt0 + i;
        if (nt < 15) {
          const int row = nt * 16 + col + kk;
          bf16x8 bv = *(const bf16x8*)(T1T + row * 40 + kg * 8);
#pragma unroll
          for (int m = 0; m < 4; ++m)
            acc[m][i] = __builtin_amdgcn_mfma_f32_16x16x32_bf16(am[m], bv, acc[m][i], 0, 0, 0);
        }
      }
    }
#pragma unroll
    for (int m = 0; m < 4; ++m) {
      float bb[4];
#pragma unroll
      for (int r = 0; r < 4; ++r) bb[r] = b2s[m * 16 + kg * 4 + r];
#pragma unroll
      for (int i = 0; i < 4; ++i) {
        const int nt = nt0 + i;
        if (nt < 15) {
          const int pos = nt * 16 + col;
          union { u16t u[4]; uint2 v; } pk;
#pragma unroll
          for (int r = 0; r < 4; ++r) pk.u[r] = f2bf(fmaxf(acc[m][i][r] + bb[r], 0.f));
          *(uint2*)(S2 + pos * 72 + m * 16 + kg * 4) = pk.v;
        }
      }
    }
  }
  __syncthreads();

  // pool3 over conv2 (bf16>=0 -> integer max), write T2T [q][ch]; zero pad rows 78..87
  for (int id = t; id < 1408; id += 256) {
    if (id < 1248) {
      const int q = id >> 4, cq = id & 15;
      union { u16t u[4]; uint2 v; } a, b, c, o;
      a.v = *(const uint2*)(S2 + (3 * q) * 72 + cq * 4);
      b.v = *(const uint2*)(S2 + (3 * q + 1) * 72 + cq * 4);
      c.v = *(const uint2*)(S2 + (3 * q + 2) * 72 + cq * 4);
#pragma unroll
      for (int r = 0; r < 4; ++r) {
        u16t m = a.u[r] > b.u[r] ? a.u[r] : b.u[r];
        o.u[r] = m > c.u[r] ? m : c.u[r];
      }
      *(uint2*)(T2T + q * 72 + cq * 4) = o.v;
    } else {
      const int id2 = id - 1248;
      const int r = 78 + (id2 >> 4), cq = id2 & 15;
      *(uint2*)(T2T + r * 72 + cq * 4) = make_uint2(0u, 0u);
    }
  }
  __syncthreads();

  // conv3 (64->128, k8) MFMA: M=128 x N=80 x K=512. Waves: (M-half) x (N-group)
  {
    const int wm = w & 1, wn = w >> 1;
    const int nt0 = wn * 3, ncnt = wn ? 2 : 3;
    f32x4 acc[4][3];
#pragma unroll
    for (int m = 0; m < 4; ++m)
#pragma unroll
      for (int i = 0; i < 3; ++i) acc[m][i] = (f32x4){0.f, 0.f, 0.f, 0.f};
#pragma unroll 1
    for (int kk = 0; kk < 16; ++kk) {
      bf16x8 am[4];
#pragma unroll
      for (int m = 0; m < 4; ++m)
        am[m] = *(const bf16x8*)(W3k + ((wm * 64 + m * 16 + col) << 9) + kk * 32 + kg * 8);
      const int tt = kk >> 1, c0 = ((kk & 1) << 5) + kg * 8;
#pragma unroll
      for (int i = 0; i < 3; ++i) {
        if (i < ncnt) {
          const int row = (nt0 + i) * 16 + col + tt;
          bf16x8 bv = *(const bf16x8*)(T2T + row * 72 + c0);
#pragma unroll
          for (int m = 0; m < 4; ++m)
            acc[m][i] = __builtin_amdgcn_mfma_f32_16x16x32_bf16(am[m], bv, acc[m][i], 0, 0, 0);
        }
      }
    }
#pragma unroll
    for (int m = 0; m < 4; ++m) {
      float bb[4];
#pragma unroll
      for (int r = 0; r < 4; ++r) bb[r] = b3s[wm * 64 + m * 16 + kg * 4 + r];
#pragma unroll
      for (int i = 0; i < 3; ++i) {
        if (i < ncnt) {
          const int pos = (nt0 + i) * 16 + col;
          union { u16t u[4]; uint2 v; } pk;
#pragma unroll
          for (int r = 0; r < 4; ++r) pk.u[r] = f2bf(fmaxf(acc[m][i][r] + bb[r], 0.f));
          *(uint2*)(S3 + pos * 136 + wm * 64 + m * 16 + kg * 4) = pk.v;
        }
      }
    }
  }
  __syncthreads();

  // final pool3 + store t3 [g][c*23+q] fp32
  for (int id = t; id < 2944; id += 256) {
    const int c = id / 23, q = id - c * 23;
    u16t a = (u16t)S3[(3 * q) * 136 + c];
    u16t b = (u16t)S3[(3 * q + 1) * 136 + c];
    u16t d = (u16t)S3[(3 * q + 2) * 136 + c];
    u16t m = a > b ? a : b;
    m = m > d ? m : d;
    t3[(size_t)g * 2944 + id] = __uint_as_float((u32t)m << 16);
  }
}

// ---------------- generic tiled GEMM (unchanged) ----------------
__global__ __launch_bounds__(256) void k_gemm(
    const float* __restrict__ A, int lda,
    const float* __restrict__ W, const float* __restrict__ bias,
    float* __restrict__ C, int ldc, int c_off,
    int M, int N, int K, int do_relu)
{
  __shared__ float As[64 * 17];
  __shared__ float Ws[16 * 64];
  const int t = threadIdx.x;
  const int m0 = blockIdx.x * 64, n0 = blockIdx.y * 64;
  const int tm = t >> 4, tn = t & 15;
  float acc[4][4] = {};
  const int lrow = t >> 2, lkq = (t & 3) * 4;
  const int wkr = t >> 4, wnc = (t & 15) * 4;
  for (int k0 = 0; k0 < K; k0 += 16) {
    float4 av = make_float4(0.f, 0.f, 0.f, 0.f);
    if (m0 + lrow < M) av = *(const float4*)(A + (size_t)(m0 + lrow) * lda + k0 + lkq);
    const float4 wv = *(const float4*)(W + (size_t)(k0 + wkr) * N + n0 + wnc);
    __syncthreads();
    As[lrow * 17 + lkq + 0] = av.x;
    As[lrow * 17 + lkq + 1] = av.y;
    As[lrow * 17 + lkq + 2] = av.z;
    As[lrow * 17 + lkq + 3] = av.w;
    *(float4*)(Ws + wkr * 64 + wnc) = wv;
    __syncthreads();
#pragma unroll
    for (int kk = 0; kk < 16; ++kk) {
      float a[4];
#pragma unroll
      for (int i_ = 0; i_ < 4; ++i_) a[i_] = As[(tm * 4 + i_) * 17 + kk];
      const float4 w = *(const float4*)(Ws + kk * 64 + tn * 4);
#pragma unroll
      for (int i_ = 0; i_ < 4; ++i_) {
        acc[i_][0] = fmaf(a[i_], w.x, acc[i_][0]);
        acc[i_][1] = fmaf(a[i_], w.y, acc[i_][1]);
        acc[i_][2] = fmaf(a[i_], w.z, acc[i_][2]);
        acc[i_][3] = fmaf(a[i_], w.w, acc[i_][3]);
      }
    }
  }
  const float4 bv = *(const float4*)(bias + n0 + tn * 4);
#pragma unroll
  for (int i_ = 0; i_ < 4; ++i_) {
    const int m = m0 + tm * 4 + i_;
    if (m < M) {
      float4 o;
      o.x = acc[i_][0] + bv.x;
      o.y = acc[i_][1] + bv.y;
      o.z = acc[i_][2] + bv.z;
      o.w = acc[i_][3] + bv.w;
      if (do_relu) {
        o.x = fmaxf(o.x, 0.f); o.y = fmaxf(o.y, 0.f);
        o.z = fmaxf(o.z, 0.f); o.w = fmaxf(o.w, 0.f);
      }
      *(float4*)(C + (size_t)m * ldc + c_off + n0 + tn * 4) = o;
    }
  }
}

__global__ __launch_bounds__(256) void k_out(
    const float* __restrict__ h2, const float* __restrict__ Wo,
    const float* __restrict__ bo, float* __restrict__ out)
{
  __shared__ float Ws_[128];
  const int t = threadIdx.x;
  if (t < 128) Ws_[t] = Wo[t];
  __syncthreads();
  const int g = blockIdx.x * 32 + (t >> 3), l = t & 7;
  float acc = 0.f;
  if (g < NG) {
    const float* hr = h2 + (size_t)g * 128 + l * 16;
    const float* wr = Ws_ + l * 16;
#pragma unroll
    for (int j = 0; j < 16; ++j) acc = fmaf(hr[j], wr[j], acc);
  }
  acc += __shfl_down(acc, 4, 8);
  acc += __shfl_down(acc, 2, 8);
  acc += __shfl_down(acc, 1, 8);
  if (l == 0 && g < NG) out[g] = acc + bo[0];
}

extern "C" void kernel_launch(void* const* d_in, const int* in_sizes, int n_in,
                              void* d_out, int out_size, void* d_ws, size_t ws_size,
                              hipStream_t stream) {
  const float* x    = (const float*)d_in[0];
  const int*   ei   = (const int*)d_in[1];
  const int*   batch= (const int*)d_in[2];
  const float* xo   = (const float*)d_in[3];
  const float* g1W1 = (const float*)d_in[4];
  const float* g1b1 = (const float*)d_in[5];
  const float* g1W2 = (const float*)d_in[6];
  const float* g1b2 = (const float*)d_in[7];
  const float* gsW1 = (const float*)d_in[8];
  const float* gsb1 = (const float*)d_in[9];
  const float* gsW2 = (const float*)d_in[10];
  const float* gsb2 = (const float*)d_in[11];
  const float* bng  = (const float*)d_in[12];
  const float* bnb  = (const float*)d_in[13];
  const float* Wxd  = (const float*)d_in[14];
  const float* bxd  = (const float*)d_in[15];
  const float* c1W  = (const float*)d_in[16];
  const float* c1b  = (const float*)d_in[17];
  const float* c2W  = (const float*)d_in[18];
  const float* c2b  = (const float*)d_in[19];
  const float* c3W  = (const float*)d_in[20];
  const float* c3b  = (const float*)d_in[21];
  const float* Wxt  = (const float*)d_in[22];
  const float* bxt  = (const float*)d_in[23];
  const float* W1f  = (const float*)d_in[24];
  const float* b1f  = (const float*)d_in[25];
  const float* W2f  = (const float*)d_in[26];
  const float* b2f  = (const float*)d_in[27];
  const float* Wo   = (const float*)d_in[28];
  const float* bo   = (const float*)d_in[29];

  char* ws = (char*)d_ws;
  float* U  = (float*)(ws + OFF_U);
  float* S  = (float*)(ws + OFF_S);
  float* Y  = (float*)(ws + OFF_Y);
  float* ST = (float*)(ws + OFF_STATS);
  float* XC = (float*)(ws + OFF_XC);
  float* T3 = (float*)(ws + OFF_T3);
  u16t*  W2K = (u16t*)(ws + OFF_WK);
  u16t*  W3K = W2K + 64 * 256;
  float* H1 = (float*)(ws + OFF_H1);
  float* H2 = (float*)(ws + OFF_H2);
  float* OUT = (float*)d_out;

  hipMemsetAsync(ST, 0, 5 * 64 * sizeof(float), stream);

  k_mlp1_first<<<2048, 256, 0, stream>>>(x, g1W1, g1b1, U, S);
  k_edge<<<NE / 32, 256, 0, stream>>>(ei, U, S);
  k_mlp2_stats<<<2048, 256, 0, stream>>>(S, g1W2, g1b2, Y, ST + 0);
  for (int l = 1; l <= 4; ++l) {
    k_mlp1_mid<<<2048, 256, 0, stream>>>(Y, ST + (l - 1) * 64, bng + (l - 1) * 32,
                                         bnb + (l - 1) * 32, gsW1 + (l - 1) * 1024,
                                         gsb1 + (l - 1) * 32, U, S);
    k_edge<<<NE / 32, 256, 0, stream>>>(ei, U, S);
    k_mlp2_stats<<<2048, 256, 0, stream>>>(S, gsW2 + (l - 1) * 1024, gsb2 + (l - 1) * 32,
                                           Y, ST + l * 64);
  }
  k_pool_xd<<<NG, 64, 0, stream>>>(Y, batch, ST, bng, bnb, Wxd, bxd, XC);
  // WK region (340e6) overlaps Y during GNN -> prep only after pool consumed Y
  k_prep<<<256, 256, 0, stream>>>(c2W, c3W, W2K, W3K);
  k_cnn<<<NG, 256, 0, stream>>>(xo, c1W, c1b, W2K, c2b, W3K, c3b, T3);
  {
    dim3 grid((NG + 63) / 64, 128 / 64);
    k_gemm<<<grid, 256, 0, stream>>>(T3, 2944, Wxt, bxt, XC, 256, 128, NG, 128, 2944, 0);
  }
  {
    dim3 grid((NG + 63) / 64, 1024 / 64);
    k_gemm<<<grid, 256, 0, stream>>>(XC, 256, W1f, b1f, H1, 1024, 0, NG, 1024, 256, 1);
  }
  {
    dim3 grid((NG + 63) / 64, 128 / 64);
    k_gemm<<<grid, 256, 0, stream>>>(H1, 1024, W2f, b2f, H2, 128, 0, NG, 128, 1024, 1);
  }
  k_out<<<(NG + 31) / 32, 256, 0, stream>>>(H2, Wo, bo, OUT);
}

// Round 3
// 7441.296 us; speedup vs baseline: 2.3432x; 1.6039x over previous
//
#include <hip/hip_runtime.h>

#define NN 1000000
#define NE 4000000
#define NG 25000
#define BN_EPS 1e-5f

typedef unsigned short u16t;
typedef unsigned int u32t;
typedef __attribute__((ext_vector_type(8))) short bf16x8;
typedef __attribute__((ext_vector_type(4))) float f32x4;

__device__ inline u16t f2bf(float f) {
  u32t u = __float_as_uint(f);
  u32t r = (u + 0x7FFFu + ((u >> 16) & 1u)) >> 16;
  return (u16t)r;
}

// ---- workspace layout (bytes) ----
// GNN phase : U @0 (128e6), Y @256e6 (128e6), stats @384e6,
//             CSR in XC slot: RS @384,004,096 (4MB), CURSOR @388,198,400 (4MB),
//             BSUM @392,392,704 (4KB), SSRC @392,396,800 (16MB)  [dead once pool runs]
// head phase: XC @384,004,096 (25.6MB), T3 @0, WK @340e6, H1 @0, H2 @320e6
static const size_t OFF_U = 0;
static const size_t OFF_Y = 256000000;
static const size_t OFF_STATS = 384000000;
static const size_t OFF_XC = 384004096;
static const size_t OFF_RS = 384004096;
static const size_t OFF_CUR = 388198400;
static const size_t OFF_BSUM = 392392704;
static const size_t OFF_SSRC = 392396800;
static const size_t OFF_T3 = 0;
static const size_t OFF_WK = 340000000;
static const size_t OFF_H1 = 0;
static const size_t OFF_H2 = 320000000;

// ---------------- CSR build ----------------
__global__ __launch_bounds__(256) void k_hist(const int* __restrict__ ei, u32t* __restrict__ cnt) {
  const int i = blockIdx.x * 256 + threadIdx.x;
  if (i < NE) atomicAdd(&cnt[ei[NE + i]], 1u);
}

// block sums over 1024-elem tiles
__global__ __launch_bounds__(256) void k_scan1(const u32t* __restrict__ deg, u32t* __restrict__ bsum) {
  __shared__ u32t red[4];
  const int b = blockIdx.x, t = threadIdx.x;
  u32t s = 0;
#pragma unroll
  for (int j = 0; j < 4; ++j) {
    const int i = b * 1024 + j * 256 + t;
    if (i < NN) s += deg[i];
  }
#pragma unroll
  for (int off = 32; off > 0; off >>= 1) s += __shfl_down(s, off);
  if ((t & 63) == 0) red[t >> 6] = s;
  __syncthreads();
  if (t == 0) bsum[b] = red[0] + red[1] + red[2] + red[3];
}

// single-block exclusive scan of bsum[977]; also rs[NN]=NE
__global__ __launch_bounds__(256) void k_scan2(u32t* __restrict__ bsum, u32t* __restrict__ rs, int nblk) {
  __shared__ u32t sh[256];
  const int t = threadIdx.x;
  u32t v[4];
#pragma unroll
  for (int j = 0; j < 4; ++j) {
    const int i = t * 4 + j;
    v[j] = (i < nblk) ? bsum[i] : 0u;
  }
  const u32t tot = v[0] + v[1] + v[2] + v[3];
  sh[t] = tot;
  __syncthreads();
  for (int off = 1; off < 256; off <<= 1) {
    u32t add = (t >= off) ? sh[t - off] : 0u;
    __syncthreads();
    sh[t] += add;
    __syncthreads();
  }
  const u32t tb = (t == 0) ? 0u : sh[t - 1];
  u32t run = tb;
#pragma unroll
  for (int j = 0; j < 4; ++j) {
    const int i = t * 4 + j;
    if (i < nblk) bsum[i] = run;
    run += v[j];
  }
  if (t == 0) rs[NN] = NE;
}

// per-block exclusive scan: rs = scan(deg)+bsum[b]; cursor = rs copy
__global__ __launch_bounds__(256) void k_scan3(u32t* __restrict__ cur, u32t* __restrict__ rs,
                                               const u32t* __restrict__ bsum) {
  __shared__ u32t sh[256];
  const int b = blockIdx.x, t = threadIdx.x;
  const int i0 = b * 1024 + t * 4;
  u32t v[4];
#pragma unroll
  for (int j = 0; j < 4; ++j) v[j] = (i0 + j < NN) ? cur[i0 + j] : 0u;
  sh[t] = v[0] + v[1] + v[2] + v[3];
  __syncthreads();
  for (int off = 1; off < 256; off <<= 1) {
    u32t add = (t >= off) ? sh[t - off] : 0u;
    __syncthreads();
    sh[t] += add;
    __syncthreads();
  }
  u32t run = bsum[b] + ((t == 0) ? 0u : sh[t - 1]);
#pragma unroll
  for (int j = 0; j < 4; ++j) {
    const int i = i0 + j;
    if (i < NN) { rs[i] = run; cur[i] = run; }
    run += v[j];
  }
}

__global__ __launch_bounds__(256) void k_scatter(const int* __restrict__ ei,
                                                 u32t* __restrict__ cur, int* __restrict__ ssrc) {
  const int i = blockIdx.x * 256 + threadIdx.x;
  if (i < NE) {
    const int src = ei[i], dst = ei[NE + i];
    const u32t pos = atomicAdd(&cur[dst], 1u);
    ssrc[pos] = src;
  }
}

// ---------------- GNN kernels ----------------

// layer0: u = x @ W1 (78->32)
__global__ __launch_bounds__(256) void k_mlp1_first(
    const float* __restrict__ x, const float* __restrict__ W1, float* __restrict__ u)
{
  __shared__ float Wt[78 * 33];
  __shared__ float xt_[8 * 79];
  const int t = threadIdx.x;
  for (int id = t; id < 78 * 32; id += 256) {
    int k = id >> 5, c = id & 31;
    Wt[k * 33 + c] = W1[id];
  }
  const int c = t & 31, nl = t >> 5;
  const int ntiles = NN / 8;
  for (int tile = blockIdx.x; tile < ntiles; tile += gridDim.x) {
    const int n0 = tile * 8;
    __syncthreads();
    for (int id = t; id < 8 * 78; id += 256) {
      int r = id / 78, k = id - r * 78;
      xt_[r * 79 + k] = x[(size_t)n0 * 78 + id];
    }
    __syncthreads();
    float acc = 0.f;
    const float* xr = xt_ + nl * 79;
#pragma unroll
    for (int k = 0; k < 78; ++k) acc = fmaf(xr[k], Wt[k * 33 + c], acc);
    u[(size_t)(n0 + nl) * 32 + c] = acc;
  }
}

// layers 1..4: h = BN(y_prev); u = h @ W1
__global__ __launch_bounds__(256) void k_mlp1_mid(
    const float* __restrict__ y, const float* __restrict__ stats,
    const float* __restrict__ gamma, const float* __restrict__ beta,
    const float* __restrict__ W1, float* __restrict__ u)
{
  __shared__ float Wt[32 * 33];
  __shared__ float ht[8 * 33];
  const int t = threadIdx.x;
  for (int id = t; id < 1024; id += 256) {
    int k = id >> 5, c = id & 31;
    Wt[k * 33 + c] = W1[id];
  }
  const int c = t & 31, nl = t >> 5;
  const float mu = stats[c] * (1.f / NN);
  float var = fmaxf(stats[32 + c] * (1.f / NN) - mu * mu, 0.f);
  const float sc = gamma[c] * rsqrtf(var + BN_EPS);
  const float sh = beta[c] - mu * sc;
  const int ntiles = NN / 8;
  for (int tile = blockIdx.x; tile < ntiles; tile += gridDim.x) {
    const int n0 = tile * 8;
    __syncthreads();
    {
      float raw = y[(size_t)n0 * 32 + t];
      ht[nl * 33 + c] = raw * sc + sh;
    }
    __syncthreads();
    float acc = 0.f;
    const float* hr = ht + nl * 33;
#pragma unroll
    for (int k = 0; k < 32; ++k) acc = fmaf(hr[k], Wt[k * 33 + c], acc);
    u[(size_t)(n0 + nl) * 32 + c] = acc;
  }
}

// fused: s = u[n] + b1 + sum_{src in CSR[n]} u[src]; y = relu(relu(s)@W2+b2); stats
__global__ __launch_bounds__(256) void k_agg(
    const float* __restrict__ u, const u32t* __restrict__ rs, const int* __restrict__ ssrc,
    const float* __restrict__ b1, const float* __restrict__ W2, const float* __restrict__ b2,
    float* __restrict__ y, float* __restrict__ stats)
{
  __shared__ float W2s[32 * 33];
  __shared__ float ht[32 * 33];
  __shared__ float red[256];
  const int t = threadIdx.x;
  for (int id = t; id < 1024; id += 256) {
    int k = id >> 5, c = id & 31;
    W2s[k * 33 + c] = W2[id];
  }
  const int nl = t >> 3, l3 = t & 7, c0 = l3 * 4;
  const int n = blockIdx.x * 32 + nl;
  const float4 b1v = *(const float4*)(b1 + c0);
  float4 s4 = *(const float4*)(u + (size_t)n * 32 + c0);
  s4.x += b1v.x; s4.y += b1v.y; s4.z += b1v.z; s4.w += b1v.w;
  const u32t e0 = rs[n], e1 = rs[n + 1];
  for (u32t e = e0; e < e1; ++e) {
    const int sn = ssrc[e];
    const float4 v = *(const float4*)(u + (size_t)sn * 32 + c0);
    s4.x += v.x; s4.y += v.y; s4.z += v.z; s4.w += v.w;
  }
  float* hp = ht + nl * 33 + c0;
  hp[0] = fmaxf(s4.x, 0.f);
  hp[1] = fmaxf(s4.y, 0.f);
  hp[2] = fmaxf(s4.z, 0.f);
  hp[3] = fmaxf(s4.w, 0.f);
  __syncthreads();
  const int c = t & 31;
  const float b2v = b2[c];
  float rsum = 0.f, rq = 0.f;
#pragma unroll
  for (int rep = 0; rep < 4; ++rep) {
    const int row = (t >> 5) + rep * 8;
    const float* hr = ht + row * 33;
    float acc = b2v;
#pragma unroll
    for (int k = 0; k < 32; ++k) acc = fmaf(hr[k], W2s[k * 33 + c], acc);
    acc = fmaxf(acc, 0.f);
    y[(size_t)(blockIdx.x * 32 + row) * 32 + c] = acc;
    rsum += acc;
    rq += acc * acc;
  }
  rsum += __shfl_down(rsum, 32);
  rq += __shfl_down(rq, 32);
  __syncthreads();
  const int wv_ = t >> 6, lane = t & 63;
  if (lane < 32) {
    red[wv_ * 32 + lane] = rsum;
    red[128 + wv_ * 32 + lane] = rq;
  }
  __syncthreads();
  if (t < 32) {
    float a = red[t] + red[32 + t] + red[64 + t] + red[96 + t];
    float b = red[128 + t] + red[160 + t] + red[192 + t] + red[224 + t];
    unsafeAtomicAdd(&stats[t], a);
    unsafeAtomicAdd(&stats[32 + t], b);
  }
}

__global__ __launch_bounds__(64) void k_pool_xd(
    const float* __restrict__ y, const int* __restrict__ batch,
    const float* __restrict__ stats, const float* __restrict__ gamma,
    const float* __restrict__ beta, const float* __restrict__ Wxd,
    const float* __restrict__ bxd, float* __restrict__ xc)
{
  const int g = blockIdx.x, t = threadIdx.x;
  int lo = 0, n = NN;
  while (n > 0) {
    int h = n >> 1, m = lo + h;
    if (batch[m] < g) { lo = m + 1; n -= h + 1; } else n = h;
  }
  int hi = lo;
  n = NN - lo;
  while (n > 0) {
    int h = n >> 1, m = hi + h;
    if (batch[m] < g + 1) { hi = m + 1; n -= h + 1; } else n = h;
  }
  const int c = t & 31;
  const float mu = stats[4 * 64 + c] * (1.f / NN);
  float var = fmaxf(stats[4 * 64 + 32 + c] * (1.f / NN) - mu * mu, 0.f);
  const float sc = gamma[4 * 32 + c] * rsqrtf(var + BN_EPS);
  const float sh = beta[4 * 32 + c] - mu * sc;
  float acc = 0.f;
  for (int i = lo + (t >> 5); i < hi; i += 2) acc += y[(size_t)i * 32 + c];
  acc += __shfl_down(acc, 32);
  __shared__ float pl[32];
  if (t < 32) pl[t] = acc * sc + (float)(hi - lo) * sh;
  __syncthreads();
#pragma unroll
  for (int rep = 0; rep < 2; ++rep) {
    const int o = t + rep * 64;
    float a = bxd[o];
#pragma unroll
    for (int cc = 0; cc < 32; ++cc) a = fmaf(pl[cc], Wxd[cc * 128 + o], a);
    xc[(size_t)g * 256 + o] = fmaxf(a, 0.f);
  }
}

// ---------------- CNN weight prep ----------------
__global__ __launch_bounds__(256) void k_prep(
    const float* __restrict__ w2, const float* __restrict__ w3,
    u16t* __restrict__ W2k, u16t* __restrict__ W3k)
{
  int i = blockIdx.x * 256 + threadIdx.x;
  if (i < 64 * 256) {
    int c2 = i >> 8, kk = i & 255, tt = kk >> 5, ci = kk & 31;
    W2k[i] = f2bf(w2[c2 * 256 + ci * 8 + tt]);
  }
  if (i < 128 * 512) {
    int c3 = i >> 9, kk = i & 511, tt = kk >> 6, ci = kk & 63;
    W3k[i] = f2bf(w3[c3 * 512 + ci * 8 + tt]);
  }
}

// ---------------- fused per-graph CNN (MFMA conv2/conv3) ----------------
__global__ __launch_bounds__(256) void k_cnn(
    const float* __restrict__ xo,
    const float* __restrict__ w1, const float* __restrict__ b1,
    const u16t* __restrict__ W2k, const float* __restrict__ b2,
    const u16t* __restrict__ W3k, const float* __restrict__ b3,
    float* __restrict__ t3)
{
  __shared__ __align__(16) char smem[59264];
  float* xot = (float*)(smem);
  float* w1s = (float*)(smem + 3072);
  float* b2s = (float*)(smem + 4096);
  float* b3s = (float*)(smem + 4352);
  short* T1T = (short*)(smem + 4864);
  short* T2T = (short*)(smem + 4864);
  short* S2  = (short*)(smem + 24704);
  short* S3  = (short*)(smem + 24704);

  const int g = blockIdx.x, t = threadIdx.x;
  const int w = t >> 6, l = t & 63, col = l & 15, kg = l >> 4;

  for (int i = t; i < 768; i += 256) xot[i] = (i < 735) ? xo[(size_t)g * 735 + i] : 0.f;
  w1s[t] = w1[t];
  if (t < 64) b2s[t] = b2[t];
  if (t < 128) b3s[t] = b3[t];
  if (t < 192) {
    int r = 242 + (t >> 5), c = t & 31;
    T1T[r * 40 + c] = 0;
  }
  __syncthreads();

  // conv1 fp32 + relu + pool3 -> T1T bf16 [pos][ch]
  {
    const int c = t >> 3, qg = t & 7;
    float wv[8];
#pragma unroll
    for (int j = 0; j < 8; ++j) wv[j] = w1s[c * 8 + j];
    const float bias = b1[c];
    const int q0 = qg * 31, qe = (q0 + 31 < 242) ? q0 + 31 : 242;
#pragma unroll 1
    for (int qc = q0; qc < qe; qc += 10) {
      const int cnt = (qe - qc < 10) ? qe - qc : 10;
      float xv[37];
#pragma unroll
      for (int j = 0; j < 37; ++j) xv[j] = xot[3 * qc + j];
#pragma unroll
      for (int j0 = 0; j0 < 10; ++j0) {
        if (j0 < cnt) {
          float a0 = bias, a1 = bias, a2 = bias;
#pragma unroll
          for (int tt = 0; tt < 8; ++tt) {
            a0 = fmaf(wv[tt], xv[3 * j0 + tt], a0);
            a1 = fmaf(wv[tt], xv[3 * j0 + 1 + tt], a1);
            a2 = fmaf(wv[tt], xv[3 * j0 + 2 + tt], a2);
          }
          float m = fmaxf(fmaxf(a0, a1), fmaxf(a2, 0.f));
          T1T[(qc + j0) * 40 + c] = (short)f2bf(m);
        }
      }
    }
  }
  __syncthreads();

  // conv2 MFMA: M=64 x N=240 x K=256
  {
    f32x4 acc[4][4];
#pragma unroll
    for (int m = 0; m < 4; ++m)
#pragma unroll
      for (int i = 0; i < 4; ++i) acc[m][i] = (f32x4){0.f, 0.f, 0.f, 0.f};
    const int nt0 = w * 4;
#pragma unroll 1
    for (int kk = 0; kk < 8; ++kk) {
      bf16x8 am[4];
#pragma unroll
      for (int m = 0; m < 4; ++m)
        am[m] = *(const bf16x8*)(W2k + ((m * 16 + col) << 8) + kk * 32 + kg * 8);
#pragma unroll
      for (int i = 0; i < 4; ++i) {
        const int nt = nt0 + i;
        if (nt < 15) {
          const int row = nt * 16 + col + kk;
          bf16x8 bv = *(const bf16x8*)(T1T + row * 40 + kg * 8);
#pragma unroll
          for (int m = 0; m < 4; ++m)
            acc[m][i] = __builtin_amdgcn_mfma_f32_16x16x32_bf16(am[m], bv, acc[m][i], 0, 0, 0);
        }
      }
    }
#pragma unroll
    for (int m = 0; m < 4; ++m) {
      float bb[4];
#pragma unroll
      for (int r = 0; r < 4; ++r) bb[r] = b2s[m * 16 + kg * 4 + r];
#pragma unroll
      for (int i = 0; i < 4; ++i) {
        const int nt = nt0 + i;
        if (nt < 15) {
          const int pos = nt * 16 + col;
          union { u16t u[4]; uint2 v; } pk;
#pragma unroll
          for (int r = 0; r < 4; ++r) pk.u[r] = f2bf(fmaxf(acc[m][i][r] + bb[r], 0.f));
          *(uint2*)(S2 + pos * 72 + m * 16 + kg * 4) = pk.v;
        }
      }
    }
  }
  __syncthreads();

  // pool3 conv2 -> T2T [q][ch]
  for (int id = t; id < 1408; id += 256) {
    if (id < 1248) {
      const int q = id >> 4, cq = id & 15;
      union { u16t u[4]; uint2 v; } a, b, c, o;
      a.v = *(const uint2*)(S2 + (3 * q) * 72 + cq * 4);
      b.v = *(const uint2*)(S2 + (3 * q + 1) * 72 + cq * 4);
      c.v = *(const uint2*)(S2 + (3 * q + 2) * 72 + cq * 4);
#pragma unroll
      for (int r = 0; r < 4; ++r) {
        u16t m = a.u[r] > b.u[r] ? a.u[r] : b.u[r];
        o.u[r] = m > c.u[r] ? m : c.u[r];
      }
      *(uint2*)(T2T + q * 72 + cq * 4) = o.v;
    } else {
      const int id2 = id - 1248;
      const int r = 78 + (id2 >> 4), cq = id2 & 15;
      *(uint2*)(T2T + r * 72 + cq * 4) = make_uint2(0u, 0u);
    }
  }
  __syncthreads();

  // conv3 MFMA: M=128 x N=80 x K=512
  {
    const int wm = w & 1, wn = w >> 1;
    const int nt0 = wn * 3, ncnt = wn ? 2 : 3;
    f32x4 acc[4][3];
#pragma unroll
    for (int m = 0; m < 4; ++m)
#pragma unroll
      for (int i = 0; i < 3; ++i) acc[m][i] = (f32x4){0.f, 0.f, 0.f, 0.f};
#pragma unroll 1
    for (int kk = 0; kk < 16; ++kk) {
      bf16x8 am[4];
#pragma unroll
      for (int m = 0; m < 4; ++m)
        am[m] = *(const bf16x8*)(W3k + ((wm * 64 + m * 16 + col) << 9) + kk * 32 + kg * 8);
      const int tt = kk >> 1, c0 = ((kk & 1) << 5) + kg * 8;
#pragma unroll
      for (int i = 0; i < 3; ++i) {
        if (i < ncnt) {
          const int row = (nt0 + i) * 16 + col + tt;
          bf16x8 bv = *(const bf16x8*)(T2T + row * 72 + c0);
#pragma unroll
          for (int m = 0; m < 4; ++m)
            acc[m][i] = __builtin_amdgcn_mfma_f32_16x16x32_bf16(am[m], bv, acc[m][i], 0, 0, 0);
        }
      }
    }
#pragma unroll
    for (int m = 0; m < 4; ++m) {
      float bb[4];
#pragma unroll
      for (int r = 0; r < 4; ++r) bb[r] = b3s[wm * 64 + m * 16 + kg * 4 + r];
#pragma unroll
      for (int i = 0; i < 3; ++i) {
        if (i < ncnt) {
          const int pos = (nt0 + i) * 16 + col;
          union { u16t u[4]; uint2 v; } pk;
#pragma unroll
          for (int r = 0; r < 4; ++r) pk.u[r] = f2bf(fmaxf(acc[m][i][r] + bb[r], 0.f));
          *(uint2*)(S3 + pos * 136 + wm * 64 + m * 16 + kg * 4) = pk.v;
        }
      }
    }
  }
  __syncthreads();

  for (int id = t; id < 2944; id += 256) {
    const int c = id / 23, q = id - c * 23;
    u16t a = (u16t)S3[(3 * q) * 136 + c];
    u16t b = (u16t)S3[(3 * q + 1) * 136 + c];
    u16t d = (u16t)S3[(3 * q + 2) * 136 + c];
    u16t m = a > b ? a : b;
    m = m > d ? m : d;
    t3[(size_t)g * 2944 + id] = __uint_as_float((u32t)m << 16);
  }
}

// ---------------- generic tiled GEMM ----------------
__global__ __launch_bounds__(256) void k_gemm(
    const float* __restrict__ A, int lda,
    const float* __restrict__ W, const float* __restrict__ bias,
    float* __restrict__ C, int ldc, int c_off,
    int M, int N, int K, int do_relu)
{
  __shared__ float As[64 * 17];
  __shared__ float Ws[16 * 64];
  const int t = threadIdx.x;
  const int m0 = blockIdx.x * 64, n0 = blockIdx.y * 64;
  const int tm = t >> 4, tn = t & 15;
  float acc[4][4] = {};
  const int lrow = t >> 2, lkq = (t & 3) * 4;
  const int wkr = t >> 4, wnc = (t & 15) * 4;
  for (int k0 = 0; k0 < K; k0 += 16) {
    float4 av = make_float4(0.f, 0.f, 0.f, 0.f);
    if (m0 + lrow < M) av = *(const float4*)(A + (size_t)(m0 + lrow) * lda + k0 + lkq);
    const float4 wv = *(const float4*)(W + (size_t)(k0 + wkr) * N + n0 + wnc);
    __syncthreads();
    As[lrow * 17 + lkq + 0] = av.x;
    As[lrow * 17 + lkq + 1] = av.y;
    As[lrow * 17 + lkq + 2] = av.z;
    As[lrow * 17 + lkq + 3] = av.w;
    *(float4*)(Ws + wkr * 64 + wnc) = wv;
    __syncthreads();
#pragma unroll
    for (int kk = 0; kk < 16; ++kk) {
      float a[4];
#pragma unroll
      for (int i_ = 0; i_ < 4; ++i_) a[i_] = As[(tm * 4 + i_) * 17 + kk];
      const float4 w = *(const float4*)(Ws + kk * 64 + tn * 4);
#pragma unroll
      for (int i_ = 0; i_ < 4; ++i_) {
        acc[i_][0] = fmaf(a[i_], w.x, acc[i_][0]);
        acc[i_][1] = fmaf(a[i_], w.y, acc[i_][1]);
        acc[i_][2] = fmaf(a[i_], w.z, acc[i_][2]);
        acc[i_][3] = fmaf(a[i_], w.w, acc[i_][3]);
      }
    }
  }
  const float4 bv = *(const float4*)(bias + n0 + tn * 4);
#pragma unroll
  for (int i_ = 0; i_ < 4; ++i_) {
    const int m = m0 + tm * 4 + i_;
    if (m < M) {
      float4 o;
      o.x = acc[i_][0] + bv.x;
      o.y = acc[i_][1] + bv.y;
      o.z = acc[i_][2] + bv.z;
      o.w = acc[i_][3] + bv.w;
      if (do_relu) {
        o.x = fmaxf(o.x, 0.f); o.y = fmaxf(o.y, 0.f);
        o.z = fmaxf(o.z, 0.f); o.w = fmaxf(o.w, 0.f);
      }
      *(float4*)(C + (size_t)m * ldc + c_off + n0 + tn * 4) = o;
    }
  }
}

__global__ __launch_bounds__(256) void k_out(
    const float* __restrict__ h2, const float* __restrict__ Wo,
    const float* __restrict__ bo, float* __restrict__ out)
{
  __shared__ float Ws_[128];
  const int t = threadIdx.x;
  if (t < 128) Ws_[t] = Wo[t];
  __syncthreads();
  const int g = blockIdx.x * 32 + (t >> 3), l = t & 7;
  float acc = 0.f;
  if (g < NG) {
    const float* hr = h2 + (size_t)g * 128 + l * 16;
    const float* wr = Ws_ + l * 16;
#pragma unroll
    for (int j = 0; j < 16; ++j) acc = fmaf(hr[j], wr[j], acc);
  }
  acc += __shfl_down(acc, 4, 8);
  acc += __shfl_down(acc, 2, 8);
  acc += __shfl_down(acc, 1, 8);
  if (l == 0 && g < NG) out[g] = acc + bo[0];
}

extern "C" void kernel_launch(void* const* d_in, const int* in_sizes, int n_in,
                              void* d_out, int out_size, void* d_ws, size_t ws_size,
                              hipStream_t stream) {
  const float* x    = (const float*)d_in[0];
  const int*   ei   = (const int*)d_in[1];
  const int*   batch= (const int*)d_in[2];
  const float* xo   = (const float*)d_in[3];
  const float* g1W1 = (const float*)d_in[4];
  const float* g1b1 = (const float*)d_in[5];
  const float* g1W2 = (const float*)d_in[6];
  const float* g1b2 = (const float*)d_in[7];
  const float* gsW1 = (const float*)d_in[8];
  const float* gsb1 = (const float*)d_in[9];
  const float* gsW2 = (const float*)d_in[10];
  const float* gsb2 = (const float*)d_in[11];
  const float* bng  = (const float*)d_in[12];
  const float* bnb  = (const float*)d_in[13];
  const float* Wxd  = (const float*)d_in[14];
  const float* bxd  = (const float*)d_in[15];
  const float* c1W  = (const float*)d_in[16];
  const float* c1b  = (const float*)d_in[17];
  const float* c2W  = (const float*)d_in[18];
  const float* c2b  = (const float*)d_in[19];
  const float* c3W  = (const float*)d_in[20];
  const float* c3b  = (const float*)d_in[21];
  const float* Wxt  = (const float*)d_in[22];
  const float* bxt  = (const float*)d_in[23];
  const float* W1f  = (const float*)d_in[24];
  const float* b1f  = (const float*)d_in[25];
  const float* W2f  = (const float*)d_in[26];
  const float* b2f  = (const float*)d_in[27];
  const float* Wo   = (const float*)d_in[28];
  const float* bo   = (const float*)d_in[29];

  char* ws = (char*)d_ws;
  float* U   = (float*)(ws + OFF_U);
  float* Y   = (float*)(ws + OFF_Y);
  float* ST  = (float*)(ws + OFF_STATS);
  float* XC  = (float*)(ws + OFF_XC);
  u32t*  RS  = (u32t*)(ws + OFF_RS);
  u32t*  CUR = (u32t*)(ws + OFF_CUR);
  u32t*  BS  = (u32t*)(ws + OFF_BSUM);
  int*   SSRC= (int*)(ws + OFF_SSRC);
  float* T3  = (float*)(ws + OFF_T3);
  u16t*  W2K = (u16t*)(ws + OFF_WK);
  u16t*  W3K = W2K + 64 * 256;
  float* H1  = (float*)(ws + OFF_H1);
  float* H2  = (float*)(ws + OFF_H2);
  float* OUT = (float*)d_out;

  const int NBLK = (NN + 1023) / 1024;  // 977

  hipMemsetAsync(ST, 0, 5 * 64 * sizeof(float), stream);
  hipMemsetAsync(CUR, 0, NN * sizeof(u32t), stream);

  // CSR build (reused by all 5 layers)
  k_hist<<<(NE + 255) / 256, 256, 0, stream>>>(ei, CUR);
  k_scan1<<<NBLK, 256, 0, stream>>>(CUR, BS);
  k_scan2<<<1, 256, 0, stream>>>(BS, RS, NBLK);
  k_scan3<<<NBLK, 256, 0, stream>>>(CUR, RS, BS);
  k_scatter<<<(NE + 255) / 256, 256, 0, stream>>>(ei, CUR, SSRC);

  // layer 0
  k_mlp1_first<<<2048, 256, 0, stream>>>(x, g1W1, U);
  k_agg<<<NN / 32, 256, 0, stream>>>(U, RS, SSRC, g1b1, g1W2, g1b2, Y, ST + 0);
  // layers 1..4
  for (int l = 1; l <= 4; ++l) {
    k_mlp1_mid<<<2048, 256, 0, stream>>>(Y, ST + (l - 1) * 64, bng + (l - 1) * 32,
                                         bnb + (l - 1) * 32, gsW1 + (l - 1) * 1024, U);
    k_agg<<<NN / 32, 256, 0, stream>>>(U, RS, SSRC, gsb1 + (l - 1) * 32,
                                       gsW2 + (l - 1) * 1024, gsb2 + (l - 1) * 32,
                                       Y, ST + l * 64);
  }
  k_pool_xd<<<NG, 64, 0, stream>>>(Y, batch, ST, bng, bnb, Wxd, bxd, XC);
  k_prep<<<256, 256, 0, stream>>>(c2W, c3W, W2K, W3K);
  k_cnn<<<NG, 256, 0, stream>>>(xo, c1W, c1b, W2K, c2b, W3K, c3b, T3);
  {
    dim3 grid((NG + 63) / 64, 128 / 64);
    k_gemm<<<grid, 256, 0, stream>>>(T3, 2944, Wxt, bxt, XC, 256, 128, NG, 128, 2944, 0);
  }
  {
    dim3 grid((NG + 63) / 64, 1024 / 64);
    k_gemm<<<grid, 256, 0, stream>>>(XC, 256, W1f, b1f, H1, 1024, 0, NG, 1024, 256, 1);
  }
  {
    dim3 grid((NG + 63) / 64, 128 / 64);
    k_gemm<<<grid, 256, 0, stream>>>(H1, 1024, W2f, b2f, H2, 128, 0, NG, 128, 1024, 1);
  }
  k_out<<<(NG + 31) / 32, 256, 0, stream>>>(H2, Wo, bo, OUT);
}

// Round 5
// 4556.598 us; speedup vs baseline: 3.8266x; 1.6331x over previous
//
#include <hip/hip_runtime.h>

#define NN 1000000
#define NE 4000000
#define NG 25000
#define BN_EPS 1e-5f

typedef unsigned short u16t;
typedef unsigned int u32t;
typedef __attribute__((ext_vector_type(8))) short bf16x8;
typedef __attribute__((ext_vector_type(4))) float f32x4;

__device__ inline u16t f2bf(float f) {
  u32t u = __float_as_uint(f);
  u32t r = (u + 0x7FFFu + ((u >> 16) & 1u)) >> 16;
  return (u16t)r;
}
__device__ inline float bf2f(u16t h) { return __uint_as_float((u32t)h << 16); }
// fp16 helpers (GNN state: 11-bit mantissa, half the bytes of fp32)
__device__ inline u16t f2h(float f) {
  _Float16 h = (_Float16)f;
  return *(u16t*)&h;
}
__device__ inline float h2f(u16t v) {
  _Float16 h = *(_Float16*)&v;
  return (float)h;
}
__device__ inline void add4h(float* a, uint2 v) {
  union { uint2 u; _Float16 h[4]; } cv;
  cv.u = v;
  a[0] += (float)cv.h[0];
  a[1] += (float)cv.h[1];
  a[2] += (float)cv.h[2];
  a[3] += (float)cv.h[3];
}

// ---- workspace layout (bytes) ----
// GNN: U/YB fp16 @0 (64e6), YA fp16 @130e6 (64e6), ST @258e6, RS @259e6,
//      CUR @263.2e6, BSUM @267.3e6, SSRC @268e6 (16e6)
// always-free: WK @285e6 (bf16 weights), XC @287e6 (bf16 25000x256)
// head: T3 bf16 @0 (147.2e6, after pool), H1 bf16 @150e6, H2 f32 @210e6
static const size_t OFF_U    = 0;           // also YB
static const size_t OFF_YA   = 130000000;
static const size_t OFF_ST   = 258000000;
static const size_t OFF_RS   = 259000000;
static const size_t OFF_CUR  = 263200000;
static const size_t OFF_BSUM = 267300000;
static const size_t OFF_SSRC = 268000000;
static const size_t OFF_WK   = 285000000;
static const size_t OFF_XC   = 287000000;
static const size_t OFF_T3   = 0;
static const size_t OFF_H1   = 150000000;
static const size_t OFF_H2   = 210000000;

// ---------------- CSR build ----------------
__global__ __launch_bounds__(256) void k_hist(const int* __restrict__ ei, u32t* __restrict__ cnt) {
  const int i = blockIdx.x * 256 + threadIdx.x;
  if (i < NE) atomicAdd(&cnt[ei[NE + i]], 1u);
}

__global__ __launch_bounds__(256) void k_scan1(const u32t* __restrict__ deg, u32t* __restrict__ bsum) {
  __shared__ u32t red[4];
  const int b = blockIdx.x, t = threadIdx.x;
  u32t s = 0;
#pragma unroll
  for (int j = 0; j < 4; ++j) {
    const int i = b * 1024 + j * 256 + t;
    if (i < NN) s += deg[i];
  }
#pragma unroll
  for (int off = 32; off > 0; off >>= 1) s += __shfl_down(s, off);
  if ((t & 63) == 0) red[t >> 6] = s;
  __syncthreads();
  if (t == 0) bsum[b] = red[0] + red[1] + red[2] + red[3];
}

__global__ __launch_bounds__(256) void k_scan2(u32t* __restrict__ bsum, u32t* __restrict__ rs, int nblk) {
  __shared__ u32t sh[256];
  const int t = threadIdx.x;
  u32t v[4];
#pragma unroll
  for (int j = 0; j < 4; ++j) {
    const int i = t * 4 + j;
    v[j] = (i < nblk) ? bsum[i] : 0u;
  }
  const u32t tot = v[0] + v[1] + v[2] + v[3];
  sh[t] = tot;
  __syncthreads();
  for (int off = 1; off < 256; off <<= 1) {
    u32t add = (t >= off) ? sh[t - off] : 0u;
    __syncthreads();
    sh[t] += add;
    __syncthreads();
  }
  const u32t tb = (t == 0) ? 0u : sh[t - 1];
  u32t run = tb;
#pragma unroll
  for (int j = 0; j < 4; ++j) {
    const int i = t * 4 + j;
    if (i < nblk) bsum[i] = run;
    run += v[j];
  }
  if (t == 0) rs[NN] = NE;
}

__global__ __launch_bounds__(256) void k_scan3(u32t* __restrict__ cur, u32t* __restrict__ rs,
                                               const u32t* __restrict__ bsum) {
  __shared__ u32t sh[256];
  const int b = blockIdx.x, t = threadIdx.x;
  const int i0 = b * 1024 + t * 4;
  u32t v[4];
#pragma unroll
  for (int j = 0; j < 4; ++j) v[j] = (i0 + j < NN) ? cur[i0 + j] : 0u;
  sh[t] = v[0] + v[1] + v[2] + v[3];
  __syncthreads();
  for (int off = 1; off < 256; off <<= 1) {
    u32t add = (t >= off) ? sh[t - off] : 0u;
    __syncthreads();
    sh[t] += add;
    __syncthreads();
  }
  u32t run = bsum[b] + ((t == 0) ? 0u : sh[t - 1]);
#pragma unroll
  for (int j = 0; j < 4; ++j) {
    const int i = i0 + j;
    if (i < NN) { rs[i] = run; cur[i] = run; }
    run += v[j];
  }
}

__global__ __launch_bounds__(256) void k_scatter(const int* __restrict__ ei,
                                                 u32t* __restrict__ cur, int* __restrict__ ssrc) {
  const int i = blockIdx.x * 256 + threadIdx.x;
  if (i < NE) {
    const int src = ei[i], dst = ei[NE + i];
    const u32t pos = atomicAdd(&cur[dst], 1u);
    ssrc[pos] = src;
  }
}

// ---------------- GNN kernels ----------------

// layer0 part A: u = x @ W1 (78->32), fp16 out
__global__ __launch_bounds__(256) void k_mlp1_first(
    const float* __restrict__ x, const float* __restrict__ W1, u16t* __restrict__ u)
{
  __shared__ float Wt[78 * 33];
  __shared__ float xt_[8 * 79];
  const int t = threadIdx.x;
  for (int id = t; id < 78 * 32; id += 256) {
    int k = id >> 5, c = id & 31;
    Wt[k * 33 + c] = W1[id];
  }
  const int c = t & 31, nl = t >> 5;
  const int ntiles = NN / 8;
  for (int tile = blockIdx.x; tile < ntiles; tile += gridDim.x) {
    const int n0 = tile * 8;
    __syncthreads();
    for (int id = t; id < 8 * 78; id += 256) {
      int r = id / 78, k = id - r * 78;
      xt_[r * 79 + k] = x[(size_t)n0 * 78 + id];
    }
    __syncthreads();
    float acc = 0.f;
    const float* xr = xt_ + nl * 79;
#pragma unroll
    for (int k = 0; k < 78; ++k) acc = fmaf(xr[k], Wt[k * 33 + c], acc);
    u[(size_t)(n0 + nl) * 32 + c] = f2h(acc);
  }
}

// layer0 part B: gather u, +b1, relu, @W2+b2, relu -> y + stats
__global__ __launch_bounds__(256) void k_agg0(
    const u16t* __restrict__ u, const u32t* __restrict__ rs, const int* __restrict__ ssrc,
    const float* __restrict__ b1, const float* __restrict__ W2, const float* __restrict__ b2,
    u16t* __restrict__ yout, float* __restrict__ stats_out)
{
  __shared__ float W2s[32 * 33];
  __shared__ float A1[32 * 33];
  __shared__ float red[256];
  const int t = threadIdx.x;
  for (int id = t; id < 1024; id += 256) {
    int k = id >> 5, c = id & 31;
    W2s[k * 33 + c] = W2[id];
  }
  const int nl = t >> 3, c0 = (t & 7) * 4;
  const int n = blockIdx.x * 32 + nl;
  float a[4] = {0.f, 0.f, 0.f, 0.f};
  add4h(a, *(const uint2*)(u + (size_t)n * 32 + c0));
  const u32t e0 = rs[n], e1 = rs[n + 1];
  for (u32t e = e0; e < e1; ++e) {
    const int sn = ssrc[e];
    add4h(a, *(const uint2*)(u + (size_t)sn * 32 + c0));
  }
  const float4 b1v = *(const float4*)(b1 + c0);
  float* hp = A1 + nl * 33 + c0;
  hp[0] = fmaxf(a[0] + b1v.x, 0.f);
  hp[1] = fmaxf(a[1] + b1v.y, 0.f);
  hp[2] = fmaxf(a[2] + b1v.z, 0.f);
  hp[3] = fmaxf(a[3] + b1v.w, 0.f);
  __syncthreads();
  const int c = t & 31;
  const float b2v = b2[c];
  float rsum = 0.f, rq = 0.f;
#pragma unroll
  for (int rep = 0; rep < 4; ++rep) {
    const int row = (t >> 5) + rep * 8;
    const float* hr = A1 + row * 33;
    float acc = b2v;
#pragma unroll
    for (int k = 0; k < 32; ++k) acc = fmaf(hr[k], W2s[k * 33 + c], acc);
    acc = fmaxf(acc, 0.f);
    yout[(size_t)(blockIdx.x * 32 + row) * 32 + c] = f2h(acc);
    rsum += acc;
    rq += acc * acc;
  }
  rsum += __shfl_down(rsum, 32);
  rq += __shfl_down(rq, 32);
  __syncthreads();
  const int wv_ = t >> 6, lane = t & 63;
  if (lane < 32) {
    red[wv_ * 32 + lane] = rsum;
    red[128 + wv_ * 32 + lane] = rq;
  }
  __syncthreads();
  if (t < 32) {
    float aa = red[t] + red[32 + t] + red[64 + t] + red[96 + t];
    float bb = red[128 + t] + red[160 + t] + red[192 + t] + red[224 + t];
    unsafeAtomicAdd(&stats_out[t], aa);
    unsafeAtomicAdd(&stats_out[32 + t], bb);
  }
}

// layers 1..4 fully fused: gather y(fp16), BN-affine (count trick), @W1+b1 relu, @W2+b2 relu
__global__ __launch_bounds__(256) void k_layer(
    const u16t* __restrict__ yin, const u32t* __restrict__ rs, const int* __restrict__ ssrc,
    const float* __restrict__ stats, const float* __restrict__ gamma, const float* __restrict__ beta,
    const float* __restrict__ W1, const float* __restrict__ b1,
    const float* __restrict__ W2, const float* __restrict__ b2,
    u16t* __restrict__ yout, float* __restrict__ stats_out)
{
  __shared__ float W1s[32 * 33];
  __shared__ float W2s[32 * 33];
  __shared__ float A1[32 * 33];
  __shared__ float A2[32 * 33];
  __shared__ float red[256];
  const int t = threadIdx.x;
  for (int id = t; id < 1024; id += 256) {
    int k = id >> 5, c = id & 31;
    W1s[k * 33 + c] = W1[id];
    W2s[k * 33 + c] = W2[id];
  }
  const int nl = t >> 3, c0 = (t & 7) * 4;
  const int n = blockIdx.x * 32 + nl;
  float sc[4], sh[4];
  {
    const float4 s1 = *(const float4*)(stats + c0);
    const float4 s2 = *(const float4*)(stats + 32 + c0);
    const float4 gm = *(const float4*)(gamma + c0);
    const float4 bt = *(const float4*)(beta + c0);
    const float m0 = s1.x * (1.f / NN), m1 = s1.y * (1.f / NN),
                m2 = s1.z * (1.f / NN), m3 = s1.w * (1.f / NN);
    sc[0] = gm.x * rsqrtf(fmaxf(s2.x * (1.f / NN) - m0 * m0, 0.f) + BN_EPS);
    sc[1] = gm.y * rsqrtf(fmaxf(s2.y * (1.f / NN) - m1 * m1, 0.f) + BN_EPS);
    sc[2] = gm.z * rsqrtf(fmaxf(s2.z * (1.f / NN) - m2 * m2, 0.f) + BN_EPS);
    sc[3] = gm.w * rsqrtf(fmaxf(s2.w * (1.f / NN) - m3 * m3, 0.f) + BN_EPS);
    sh[0] = bt.x - m0 * sc[0];
    sh[1] = bt.y - m1 * sc[1];
    sh[2] = bt.z - m2 * sc[2];
    sh[3] = bt.w - m3 * sc[3];
  }
  float a[4] = {0.f, 0.f, 0.f, 0.f};
  add4h(a, *(const uint2*)(yin + (size_t)n * 32 + c0));
  const u32t e0 = rs[n], e1 = rs[n + 1];
  for (u32t e = e0; e < e1; ++e) {
    const int sn = ssrc[e];
    add4h(a, *(const uint2*)(yin + (size_t)sn * 32 + c0));
  }
  const float cnt = (float)(e1 - e0 + 1u);
  float* hp = A1 + nl * 33 + c0;
#pragma unroll
  for (int j = 0; j < 4; ++j) hp[j] = sc[j] * a[j] + cnt * sh[j];
  __syncthreads();
  const int c = t & 31;
  const float b1v = b1[c];
#pragma unroll
  for (int rep = 0; rep < 4; ++rep) {
    const int row = (t >> 5) + rep * 8;
    const float* hr = A1 + row * 33;
    float acc = b1v;
#pragma unroll
    for (int k = 0; k < 32; ++k) acc = fmaf(hr[k], W1s[k * 33 + c], acc);
    A2[row * 33 + c] = fmaxf(acc, 0.f);
  }
  __syncthreads();
  const float b2v = b2[c];
  float rsum = 0.f, rq = 0.f;
#pragma unroll
  for (int rep = 0; rep < 4; ++rep) {
    const int row = (t >> 5) + rep * 8;
    const float* hr = A2 + row * 33;
    float acc = b2v;
#pragma unroll
    for (int k = 0; k < 32; ++k) acc = fmaf(hr[k], W2s[k * 33 + c], acc);
    acc = fmaxf(acc, 0.f);
    yout[(size_t)(blockIdx.x * 32 + row) * 32 + c] = f2h(acc);
    rsum += acc;
    rq += acc * acc;
  }
  rsum += __shfl_down(rsum, 32);
  rq += __shfl_down(rq, 32);
  __syncthreads();
  const int wv_ = t >> 6, lane = t & 63;
  if (lane < 32) {
    red[wv_ * 32 + lane] = rsum;
    red[128 + wv_ * 32 + lane] = rq;
  }
  __syncthreads();
  if (t < 32) {
    float aa = red[t] + red[32 + t] + red[64 + t] + red[96 + t];
    float bb = red[128 + t] + red[160 + t] + red[192 + t] + red[224 + t];
    unsafeAtomicAdd(&stats_out[t], aa);
    unsafeAtomicAdd(&stats_out[32 + t], bb);
  }
}

// pool + xd head; y fp16 in, XC bf16 out (cols 0..127)
__global__ __launch_bounds__(64) void k_pool_xd(
    const u16t* __restrict__ y, const int* __restrict__ batch,
    const float* __restrict__ stats, const float* __restrict__ gamma,
    const float* __restrict__ beta, const float* __restrict__ Wxd,
    const float* __restrict__ bxd, u16t* __restrict__ xc)
{
  const int g = blockIdx.x, t = threadIdx.x;
  int lo = 0, n = NN;
  while (n > 0) {
    int h = n >> 1, m = lo + h;
    if (batch[m] < g) { lo = m + 1; n -= h + 1; } else n = h;
  }
  int hi = lo;
  n = NN - lo;
  while (n > 0) {
    int h = n >> 1, m = hi + h;
    if (batch[m] < g + 1) { hi = m + 1; n -= h + 1; } else n = h;
  }
  const int c = t & 31;
  const float mu = stats[4 * 64 + c] * (1.f / NN);
  float var = fmaxf(stats[4 * 64 + 32 + c] * (1.f / NN) - mu * mu, 0.f);
  const float sc = gamma[4 * 32 + c] * rsqrtf(var + BN_EPS);
  const float sh = beta[4 * 32 + c] - mu * sc;
  float acc = 0.f;
  for (int i = lo + (t >> 5); i < hi; i += 2) acc += h2f(y[(size_t)i * 32 + c]);
  acc += __shfl_down(acc, 32);
  __shared__ float pl[32];
  if (t < 32) pl[t] = acc * sc + (float)(hi - lo) * sh;
  __syncthreads();
#pragma unroll
  for (int rep = 0; rep < 2; ++rep) {
    const int o = t + rep * 64;
    float a = bxd[o];
#pragma unroll
    for (int cc = 0; cc < 32; ++cc) a = fmaf(pl[cc], Wxd[cc * 128 + o], a);
    xc[(size_t)g * 256 + o] = f2bf(fmaxf(a, 0.f));
  }
}

// ---------------- weight prep: CNN K-reorder + head W transposes, all bf16 ----------------
__global__ __launch_bounds__(256) void k_prep(
    const float* __restrict__ w2, const float* __restrict__ w3,
    const float* __restrict__ wxt, const float* __restrict__ wf1, const float* __restrict__ wf2,
    u16t* __restrict__ W2k, u16t* __restrict__ W3k,
    u16t* __restrict__ WXT, u16t* __restrict__ WF1, u16t* __restrict__ WF2)
{
  const int i = blockIdx.x * 256 + threadIdx.x;
  if (i < 64 * 256) {
    int c2 = i >> 8, kk = i & 255, tt = kk >> 5, ci = kk & 31;
    W2k[i] = f2bf(w2[c2 * 256 + ci * 8 + tt]);
  }
  if (i < 128 * 512) {
    int c3 = i >> 9, kk = i & 511, tt = kk >> 6, ci = kk & 63;
    W3k[i] = f2bf(w3[c3 * 512 + ci * 8 + tt]);
  }
  if (i < 128 * 2944) {
    int nn = i / 2944, kk = i - nn * 2944;
    WXT[i] = f2bf(wxt[kk * 128 + nn]);
  }
  if (i < 1024 * 256) {
    int nn = i >> 8, kk = i & 255;
    WF1[i] = f2bf(wf1[kk * 1024 + nn]);
  }
  if (i < 128 * 1024) {
    int nn = i >> 10, kk = i & 1023;
    WF2[i] = f2bf(wf2[kk * 128 + nn]);
  }
}

// ---------------- fused per-graph CNN: m-split waves + pool-in-register ----------------
__global__ __launch_bounds__(256, 4) void k_cnn(
    const float* __restrict__ xo,
    const float* __restrict__ w1, const float* __restrict__ b1,
    const u16t* __restrict__ W2k, const float* __restrict__ b2,
    const u16t* __restrict__ W3k, const float* __restrict__ b3,
    u16t* __restrict__ t3)
{
  __shared__ __align__(16) char smem[35936];
  float* xot = (float*)(smem);
  float* w1s = (float*)(smem + 3072);
  float* b2s = (float*)(smem + 4096);
  float* b3s = (float*)(smem + 4352);
  short* T1T = (short*)(smem + 4864);
  short* T2T = (short*)(smem + 24704);

  const int g = blockIdx.x, t = threadIdx.x;
  const int w = t >> 6, l = t & 63, col = l & 15, kg = l >> 4;

  for (int i = t; i < 768; i += 256) xot[i] = (i < 735) ? xo[(size_t)g * 735 + i] : 0.f;
  w1s[t] = w1[t];
  if (t < 64) b2s[t] = b2[t];
  if (t < 128) b3s[t] = b3[t];
  if (t < 192) {  // zero T1T pad rows 242..247
    int r = 242 + (t >> 5), c = t & 31;
    T1T[r * 40 + c] = 0;
  }
  __syncthreads();

  // conv1 (1->32,k8) fp32 + relu + pool3 -> T1T bf16 [pos][ch]
  {
    const int c = t >> 3, qg = t & 7;
    float wv[8];
#pragma unroll
    for (int j = 0; j < 8; ++j) wv[j] = w1s[c * 8 + j];
    const float bias = b1[c];
    const int q0 = qg * 31, qe = (q0 + 31 < 242) ? q0 + 31 : 242;
#pragma unroll 1
    for (int qc = q0; qc < qe; qc += 10) {
      const int cnt = (qe - qc < 10) ? qe - qc : 10;
      float xv[37];
#pragma unroll
      for (int j = 0; j < 37; ++j) xv[j] = xot[3 * qc + j];
#pragma unroll
      for (int j0 = 0; j0 < 10; ++j0) {
        if (j0 < cnt) {
          float a0 = bias, a1 = bias, a2 = bias;
#pragma unroll
          for (int tt = 0; tt < 8; ++tt) {
            a0 = fmaf(wv[tt], xv[3 * j0 + tt], a0);
            a1 = fmaf(wv[tt], xv[3 * j0 + 1 + tt], a1);
            a2 = fmaf(wv[tt], xv[3 * j0 + 2 + tt], a2);
          }
          float m = fmaxf(fmaxf(a0, a1), fmaxf(a2, 0.f));
          T1T[(qc + j0) * 40 + c] = (short)f2bf(m);
        }
      }
    }
  }
  __syncthreads();

  // conv2 (32->64,k8): wave w owns out-ch [w*16,w*16+16). pool3 in-register.
  {
    bf16x8 am[8];
#pragma unroll
    for (int kk = 0; kk < 8; ++kk)
      am[kk] = *(const bf16x8*)(W2k + (w * 16 + col) * 256 + kk * 32 + kg * 8);
#pragma unroll 1
    for (int qt = 0; qt < 5; ++qt) {
      const int rbase = qt * 48 + col * 3;
      bf16x8 rv[10];
#pragma unroll
      for (int s = 0; s < 10; ++s)
        rv[s] = *(const bf16x8*)(T1T + (rbase + s) * 40 + kg * 8);
      f32x4 a0 = {0.f, 0.f, 0.f, 0.f}, a1 = a0, a2 = a0;
#pragma unroll
      for (int kk = 0; kk < 8; ++kk) {
        a0 = __builtin_amdgcn_mfma_f32_16x16x32_bf16(am[kk], rv[kk], a0, 0, 0, 0);
        a1 = __builtin_amdgcn_mfma_f32_16x16x32_bf16(am[kk], rv[kk + 1], a1, 0, 0, 0);
        a2 = __builtin_amdgcn_mfma_f32_16x16x32_bf16(am[kk], rv[kk + 2], a2, 0, 0, 0);
      }
      const int q = qt * 16 + col;
      if (q < 78) {
        union { u16t u[4]; uint2 v; } pk;
#pragma unroll
        for (int r = 0; r < 4; ++r) {
          const float bb = b2s[w * 16 + kg * 4 + r];
          float m = fmaxf(fmaxf(a0[r], a1[r]), a2[r]);
          pk.u[r] = f2bf(fmaxf(m + bb, 0.f));
        }
        *(uint2*)(T2T + q * 72 + w * 16 + kg * 4) = pk.v;
      }
    }
  }
  __syncthreads();

  // conv3 (64->128,k8): wave w owns out-ch blocks {2w,2w+1}. pool3 in-register.
  {
#pragma unroll 1
    for (int mi = 0; mi < 2; ++mi) {
      const int m3 = w * 2 + mi;
      f32x4 acc[2][3];
#pragma unroll
      for (int qt = 0; qt < 2; ++qt)
#pragma unroll
        for (int r = 0; r < 3; ++r) acc[qt][r] = (f32x4){0.f, 0.f, 0.f, 0.f};
#pragma unroll 1
      for (int kh = 0; kh < 2; ++kh) {
        bf16x8 amh[8];
#pragma unroll
        for (int tt = 0; tt < 8; ++tt)
          amh[tt] = *(const bf16x8*)(W3k + (m3 * 16 + col) * 512 + (tt * 2 + kh) * 32 + kg * 8);
#pragma unroll 1
        for (int qt = 0; qt < 2; ++qt) {
          const int rbase = qt * 48 + col * 3;
          bf16x8 rv[10];
#pragma unroll
          for (int s = 0; s < 10; ++s) {
            int row = rbase + s;
            row = (row < 78) ? row : 77;  // clamp: garbage only feeds discarded cols
            rv[s] = *(const bf16x8*)(T2T + row * 72 + kh * 32 + kg * 8);
          }
#pragma unroll
          for (int tt = 0; tt < 8; ++tt) {
            acc[qt][0] = __builtin_amdgcn_mfma_f32_16x16x32_bf16(amh[tt], rv[tt], acc[qt][0], 0, 0, 0);
            acc[qt][1] = __builtin_amdgcn_mfma_f32_16x16x32_bf16(amh[tt], rv[tt + 1], acc[qt][1], 0, 0, 0);
            acc[qt][2] = __builtin_amdgcn_mfma_f32_16x16x32_bf16(amh[tt], rv[tt + 2], acc[qt][2], 0, 0, 0);
          }
        }
      }
#pragma unroll
      for (int qt = 0; qt < 2; ++qt) {
        const int q = qt * 16 + col;
        if (q < 23) {
#pragma unroll
          for (int r = 0; r < 4; ++r) {
            const int c = m3 * 16 + kg * 4 + r;
            float m = fmaxf(fmaxf(acc[qt][0][r], acc[qt][1][r]), acc[qt][2][r]);
            t3[(size_t)g * 2944 + c * 23 + q] = f2bf(fmaxf(m + b3s[c], 0.f));
          }
        }
      }
    }
  }
}

// ---------------- bf16 MFMA GEMM: C = [relu](A[M,K] @ WT[N,K]^T + bias) ----------------
__global__ __launch_bounds__(256) void k_mgemm(
    const u16t* __restrict__ A, int lda,
    const u16t* __restrict__ WT, const float* __restrict__ bias,
    void* __restrict__ Cv, int ldc, int c_off, int M, int Kd,
    int relu_f, int out32)
{
  __shared__ __align__(16) u16t As[128 * 4 * 8];
  __shared__ __align__(16) u16t Ws2[64 * 4 * 8];
  const int t = threadIdx.x;
  const int w = t >> 6, l = t & 63, col = l & 15, kg = l >> 4;
  const int wm = w & 1, wn = w >> 1;
  const int m0 = blockIdx.x * 128, n0 = blockIdx.y * 64;
  f32x4 acc[4][2];
#pragma unroll
  for (int i = 0; i < 4; ++i)
#pragma unroll
    for (int j = 0; j < 2; ++j) acc[i][j] = (f32x4){0.f, 0.f, 0.f, 0.f};
  const int ar = t >> 1, ac = (t & 1) * 2;
  const int wr = t >> 2, wc = t & 3;
  const bool aok = (m0 + ar) < M;
  const u16t* Ap = A + (size_t)(m0 + ar) * lda;
  const u16t* Wp = WT + (size_t)(n0 + wr) * Kd;
  for (int k0 = 0; k0 < Kd; k0 += 32) {
    bf16x8 av0 = {0, 0, 0, 0, 0, 0, 0, 0}, av1 = {0, 0, 0, 0, 0, 0, 0, 0};
    if (aok) {
      av0 = *(const bf16x8*)(Ap + k0 + ac * 8);
      av1 = *(const bf16x8*)(Ap + k0 + (ac + 1) * 8);
    }
    const bf16x8 wv = *(const bf16x8*)(Wp + k0 + wc * 8);
    __syncthreads();
    *(bf16x8*)(As + (ar * 4 + (ac ^ (ar & 3))) * 8) = av0;
    *(bf16x8*)(As + (ar * 4 + ((ac + 1) ^ (ar & 3))) * 8) = av1;
    *(bf16x8*)(Ws2 + (wr * 4 + (wc ^ (wr & 3))) * 8) = wv;
    __syncthreads();
    bf16x8 af[4], bf[2];
#pragma unroll
    for (int i = 0; i < 4; ++i) {
      const int R = wm * 64 + i * 16 + col;
      af[i] = *(const bf16x8*)(As + (R * 4 + (kg ^ (R & 3))) * 8);
    }
#pragma unroll
    for (int j = 0; j < 2; ++j) {
      const int R = wn * 32 + j * 16 + col;
      bf[j] = *(const bf16x8*)(Ws2 + (R * 4 + (kg ^ (R & 3))) * 8);
    }
#pragma unroll
    for (int i = 0; i < 4; ++i)
#pragma unroll
      for (int j = 0; j < 2; ++j)
        acc[i][j] = __builtin_amdgcn_mfma_f32_16x16x32_bf16(af[i], bf[j], acc[i][j], 0, 0, 0);
  }
#pragma unroll
  for (int j = 0; j < 2; ++j) {
    const int gn = n0 + wn * 32 + j * 16 + col;
    const float bb = bias[gn];
#pragma unroll
    for (int i = 0; i < 4; ++i) {
      const int gmb = m0 + wm * 64 + i * 16 + kg * 4;
#pragma unroll
      for (int r = 0; r < 4; ++r) {
        const int gm = gmb + r;
        if (gm < M) {
          float v = acc[i][j][r] + bb;
          if (relu_f) v = fmaxf(v, 0.f);
          if (out32) ((float*)Cv)[(size_t)gm * ldc + c_off + gn] = v;
          else ((u16t*)Cv)[(size_t)gm * ldc + c_off + gn] = f2bf(v);
        }
      }
    }
  }
}

// final 128 -> 1
__global__ __launch_bounds__(256) void k_out(
    const float* __restrict__ h2, const float* __restrict__ Wo,
    const float* __restrict__ bo, float* __restrict__ out)
{
  __shared__ float Ws_[128];
  const int t = threadIdx.x;
  if (t < 128) Ws_[t] = Wo[t];
  __syncthreads();
  const int g = blockIdx.x * 32 + (t >> 3), l = t & 7;
  float acc = 0.f;
  if (g < NG) {
    const float* hr = h2 + (size_t)g * 128 + l * 16;
    const float* wr = Ws_ + l * 16;
#pragma unroll
    for (int j = 0; j < 16; ++j) acc = fmaf(hr[j], wr[j], acc);
  }
  acc += __shfl_down(acc, 4, 8);
  acc += __shfl_down(acc, 2, 8);
  acc += __shfl_down(acc, 1, 8);
  if (l == 0 && g < NG) out[g] = acc + bo[0];
}

extern "C" void kernel_launch(void* const* d_in, const int* in_sizes, int n_in,
                              void* d_out, int out_size, void* d_ws, size_t ws_size,
                              hipStream_t stream) {
  const float* x    = (const float*)d_in[0];
  const int*   ei   = (const int*)d_in[1];
  const int*   batch= (const int*)d_in[2];
  const float* xo   = (const float*)d_in[3];
  const float* g1W1 = (const float*)d_in[4];
  const float* g1b1 = (const float*)d_in[5];
  const float* g1W2 = (const float*)d_in[6];
  const float* g1b2 = (const float*)d_in[7];
  const float* gsW1 = (const float*)d_in[8];
  const float* gsb1 = (const float*)d_in[9];
  const float* gsW2 = (const float*)d_in[10];
  const float* gsb2 = (const float*)d_in[11];
  const float* bng  = (const float*)d_in[12];
  const float* bnb  = (const float*)d_in[13];
  const float* Wxd  = (const float*)d_in[14];
  const float* bxd  = (const float*)d_in[15];
  const float* c1W  = (const float*)d_in[16];
  const float* c1b  = (const float*)d_in[17];
  const float* c2W  = (const float*)d_in[18];
  const float* c2b  = (const float*)d_in[19];
  const float* c3W  = (const float*)d_in[20];
  const float* c3b  = (const float*)d_in[21];
  const float* Wxt  = (const float*)d_in[22];
  const float* bxt  = (const float*)d_in[23];
  const float* W1f  = (const float*)d_in[24];
  const float* b1f  = (const float*)d_in[25];
  const float* W2f  = (const float*)d_in[26];
  const float* b2f  = (const float*)d_in[27];
  const float* Wo   = (const float*)d_in[28];
  const float* bo   = (const float*)d_in[29];

  char* ws = (char*)d_ws;
  u16t*  U   = (u16t*)(ws + OFF_U);    // fp16; also YB
  u16t*  YA  = (u16t*)(ws + OFF_YA);   // fp16
  u16t*  YB  = (u16t*)(ws + OFF_U);
  float* ST  = (float*)(ws + OFF_ST);
  u32t*  RS  = (u32t*)(ws + OFF_RS);
  u32t*  CUR = (u32t*)(ws + OFF_CUR);
  u32t*  BS  = (u32t*)(ws + OFF_BSUM);
  int*   SSRC= (int*)(ws + OFF_SSRC);
  u16t*  WK  = (u16t*)(ws + OFF_WK);
  u16t*  W2K = WK;
  u16t*  W3K = WK + 16384;
  u16t*  WXT = WK + 16384 + 65536;
  u16t*  WF1 = WK + 16384 + 65536 + 376832;
  u16t*  WF2 = WK + 16384 + 65536 + 376832 + 262144;
  u16t*  XC  = (u16t*)(ws + OFF_XC);
  u16t*  T3  = (u16t*)(ws + OFF_T3);
  u16t*  H1  = (u16t*)(ws + OFF_H1);
  float* H2  = (float*)(ws + OFF_H2);
  float* OUT = (float*)d_out;

  const int NBLK = (NN + 1023) / 1024;  // 977

  hipMemsetAsync(ST, 0, 5 * 64 * sizeof(float), stream);
  hipMemsetAsync(CUR, 0, NN * sizeof(u32t), stream);

  k_prep<<<(128 * 2944 + 255) / 256, 256, 0, stream>>>(c2W, c3W, Wxt, W1f, W2f,
                                                        W2K, W3K, WXT, WF1, WF2);

  // CSR build (reused by all 5 layers)
  k_hist<<<(NE + 255) / 256, 256, 0, stream>>>(ei, CUR);
  k_scan1<<<NBLK, 256, 0, stream>>>(CUR, BS);
  k_scan2<<<1, 256, 0, stream>>>(BS, RS, NBLK);
  k_scan3<<<NBLK, 256, 0, stream>>>(CUR, RS, BS);
  k_scatter<<<(NE + 255) / 256, 256, 0, stream>>>(ei, CUR, SSRC);

  // GNN (fp16 state, fp32 accumulate)
  k_mlp1_first<<<2048, 256, 0, stream>>>(x, g1W1, U);
  k_agg0<<<NN / 32, 256, 0, stream>>>(U, RS, SSRC, g1b1, g1W2, g1b2, YA, ST + 0);
  const u16t* yin = YA;
  u16t* yout = YB;  // overlays U (dead after k_agg0)
  for (int lyr = 1; lyr <= 4; ++lyr) {
    k_layer<<<NN / 32, 256, 0, stream>>>(yin, RS, SSRC, ST + (lyr - 1) * 64,
                                         bng + (lyr - 1) * 32, bnb + (lyr - 1) * 32,
                                         gsW1 + (lyr - 1) * 1024, gsb1 + (lyr - 1) * 32,
                                         gsW2 + (lyr - 1) * 1024, gsb2 + (lyr - 1) * 32,
                                         yout, ST + lyr * 64);
    const u16t* tmp = yin;
    yin = yout;
    yout = (u16t*)tmp;
  }
  // yin == YA after 4 layers
  k_pool_xd<<<NG, 64, 0, stream>>>(yin, batch, ST, bng, bnb, Wxd, bxd, XC);

  // CNN branch (T3 overlays U/YB + YA head, all dead after pool)
  k_cnn<<<NG, 256, 0, stream>>>(xo, c1W, c1b, W2K, c2b, W3K, c3b, T3);

  // heads
  {
    dim3 grid((NG + 127) / 128, 2);
    k_mgemm<<<grid, 256, 0, stream>>>(T3, 2944, WXT, bxt, XC, 256, 128, NG, 2944, 0, 0);
  }
  {
    dim3 grid((NG + 127) / 128, 16);
    k_mgemm<<<grid, 256, 0, stream>>>(XC, 256, WF1, b1f, H1, 1024, 0, NG, 256, 1, 0);
  }
  {
    dim3 grid((NG + 127) / 128, 2);
    k_mgemm<<<grid, 256, 0, stream>>>(H1, 1024, WF2, b2f, H2, 128, 0, NG, 1024, 1, 1);
  }
  k_out<<<(NG + 31) / 32, 256, 0, stream>>>(H2, Wo, bo, OUT);
}

// Round 7
// 4450.209 us; speedup vs baseline: 3.9181x; 1.0239x over previous
//
#include <hip/hip_runtime.h>

#define NN 1000000
#define NE 4000000
#define NG 25000
#define BN_EPS 1e-5f

typedef unsigned short u16t;
typedef unsigned int u32t;
typedef __attribute__((ext_vector_type(8))) short bf16x8;
typedef __attribute__((ext_vector_type(4))) float f32x4;

__device__ inline u16t f2bf(float f) {
  u32t u = __float_as_uint(f);
  u32t r = (u + 0x7FFFu + ((u >> 16) & 1u)) >> 16;
  return (u16t)r;
}
__device__ inline float bf2f(u16t h) { return __uint_as_float((u32t)h << 16); }
__device__ inline u16t f2h(float f) {
  _Float16 h = (_Float16)f;
  return *(u16t*)&h;
}
__device__ inline float h2f(u16t v) {
  _Float16 h = *(_Float16*)&v;
  return (float)h;
}
__device__ inline void add4h(float* a, uint2 v) {
  union { uint2 u; _Float16 h[4]; } cv;
  cv.u = v;
  a[0] += (float)cv.h[0];
  a[1] += (float)cv.h[1];
  a[2] += (float)cv.h[2];
  a[3] += (float)cv.h[3];
}

// ---- workspace layout (bytes) ----
static const size_t OFF_U    = 0;           // fp16 64MB; also YB
static const size_t OFF_YA   = 130000000;
static const size_t OFF_ST   = 258000000;
static const size_t OFF_RS   = 259000000;
static const size_t OFF_CUR  = 263200000;
static const size_t OFF_BSUM = 267300000;
static const size_t OFF_SSRC = 268000000;
static const size_t OFF_WK   = 285000000;
static const size_t OFF_XC   = 287000000;
static const size_t OFF_T3   = 0;
static const size_t OFF_H1   = 150000000;
static const size_t OFF_H2   = 210000000;

// ---------------- CSR build ----------------
__global__ __launch_bounds__(256) void k_hist(const int* __restrict__ ei, u32t* __restrict__ cnt) {
  const int i = blockIdx.x * 256 + threadIdx.x;
  if (i < NE) atomicAdd(&cnt[ei[NE + i]], 1u);
}

__global__ __launch_bounds__(256) void k_scan1(const u32t* __restrict__ deg, u32t* __restrict__ bsum) {
  __shared__ u32t red[4];
  const int b = blockIdx.x, t = threadIdx.x;
  u32t s = 0;
#pragma unroll
  for (int j = 0; j < 4; ++j) {
    const int i = b * 1024 + j * 256 + t;
    if (i < NN) s += deg[i];
  }
#pragma unroll
  for (int off = 32; off > 0; off >>= 1) s += __shfl_down(s, off);
  if ((t & 63) == 0) red[t >> 6] = s;
  __syncthreads();
  if (t == 0) bsum[b] = red[0] + red[1] + red[2] + red[3];
}

__global__ __launch_bounds__(256) void k_scan2(u32t* __restrict__ bsum, u32t* __restrict__ rs, int nblk) {
  __shared__ u32t sh[256];
  const int t = threadIdx.x;
  u32t v[4];
#pragma unroll
  for (int j = 0; j < 4; ++j) {
    const int i = t * 4 + j;
    v[j] = (i < nblk) ? bsum[i] : 0u;
  }
  const u32t tot = v[0] + v[1] + v[2] + v[3];
  sh[t] = tot;
  __syncthreads();
  for (int off = 1; off < 256; off <<= 1) {
    u32t add = (t >= off) ? sh[t - off] : 0u;
    __syncthreads();
    sh[t] += add;
    __syncthreads();
  }
  const u32t tb = (t == 0) ? 0u : sh[t - 1];
  u32t run = tb;
#pragma unroll
  for (int j = 0; j < 4; ++j) {
    const int i = t * 4 + j;
    if (i < nblk) bsum[i] = run;
    run += v[j];
  }
  if (t == 0) rs[NN] = NE;
}

__global__ __launch_bounds__(256) void k_scan3(u32t* __restrict__ cur, u32t* __restrict__ rs,
                                               const u32t* __restrict__ bsum) {
  __shared__ u32t sh[256];
  const int b = blockIdx.x, t = threadIdx.x;
  const int i0 = b * 1024 + t * 4;
  u32t v[4];
#pragma unroll
  for (int j = 0; j < 4; ++j) v[j] = (i0 + j < NN) ? cur[i0 + j] : 0u;
  sh[t] = v[0] + v[1] + v[2] + v[3];
  __syncthreads();
  for (int off = 1; off < 256; off <<= 1) {
    u32t add = (t >= off) ? sh[t - off] : 0u;
    __syncthreads();
    sh[t] += add;
    __syncthreads();
  }
  u32t run = bsum[b] + ((t == 0) ? 0u : sh[t - 1]);
#pragma unroll
  for (int j = 0; j < 4; ++j) {
    const int i = i0 + j;
    if (i < NN) { rs[i] = run; cur[i] = run; }
    run += v[j];
  }
}

__global__ __launch_bounds__(256) void k_scatter(const int* __restrict__ ei,
                                                 u32t* __restrict__ cur, int* __restrict__ ssrc) {
  const int i = blockIdx.x * 256 + threadIdx.x;
  if (i < NE) {
    const int src = ei[i], dst = ei[NE + i];
    const u32t pos = atomicAdd(&cur[dst], 1u);
    ssrc[pos] = src;
  }
}

// ---------------- GNN kernels ----------------

__global__ __launch_bounds__(256) void k_mlp1_first(
    const float* __restrict__ x, const float* __restrict__ W1, u16t* __restrict__ u)
{
  __shared__ float Wt[78 * 33];
  __shared__ float xt_[8 * 79];
  const int t = threadIdx.x;
  for (int id = t; id < 78 * 32; id += 256) {
    int k = id >> 5, c = id & 31;
    Wt[k * 33 + c] = W1[id];
  }
  const int c = t & 31, nl = t >> 5;
  const int ntiles = NN / 8;
  for (int tile = blockIdx.x; tile < ntiles; tile += gridDim.x) {
    const int n0 = tile * 8;
    __syncthreads();
    for (int id = t; id < 8 * 78; id += 256) {
      int r = id / 78, k = id - r * 78;
      xt_[r * 79 + k] = x[(size_t)n0 * 78 + id];
    }
    __syncthreads();
    float acc = 0.f;
    const float* xr = xt_ + nl * 79;
#pragma unroll
    for (int k = 0; k < 78; ++k) acc = fmaf(xr[k], Wt[k * 33 + c], acc);
    u[(size_t)(n0 + nl) * 32 + c] = f2h(acc);
  }
}

__global__ __launch_bounds__(256) void k_agg0(
    const u16t* __restrict__ u, const u32t* __restrict__ rs, const int* __restrict__ ssrc,
    const float* __restrict__ b1, const float* __restrict__ W2, const float* __restrict__ b2,
    u16t* __restrict__ yout, float* __restrict__ stats_out)
{
  __shared__ float W2s[32 * 33];
  __shared__ float A1[32 * 33];
  __shared__ float red[256];
  const int t = threadIdx.x;
  for (int id = t; id < 1024; id += 256) {
    int k = id >> 5, c = id & 31;
    W2s[k * 33 + c] = W2[id];
  }
  const int nl = t >> 3, c0 = (t & 7) * 4;
  const int n = blockIdx.x * 32 + nl;
  float a[4] = {0.f, 0.f, 0.f, 0.f};
  add4h(a, *(const uint2*)(u + (size_t)n * 32 + c0));
  const u32t e0 = rs[n], e1 = rs[n + 1];
  u32t e = e0;
  for (; e + 4 <= e1; e += 4) {
    const int s0v = ssrc[e], s1v = ssrc[e + 1], s2v = ssrc[e + 2], s3v = ssrc[e + 3];
    const uint2 v0 = *(const uint2*)(u + (size_t)s0v * 32 + c0);
    const uint2 v1 = *(const uint2*)(u + (size_t)s1v * 32 + c0);
    const uint2 v2 = *(const uint2*)(u + (size_t)s2v * 32 + c0);
    const uint2 v3 = *(const uint2*)(u + (size_t)s3v * 32 + c0);
    add4h(a, v0); add4h(a, v1); add4h(a, v2); add4h(a, v3);
  }
  for (; e < e1; ++e)
    add4h(a, *(const uint2*)(u + (size_t)ssrc[e] * 32 + c0));
  const float4 b1v = *(const float4*)(b1 + c0);
  float* hp = A1 + nl * 33 + c0;
  hp[0] = fmaxf(a[0] + b1v.x, 0.f);
  hp[1] = fmaxf(a[1] + b1v.y, 0.f);
  hp[2] = fmaxf(a[2] + b1v.z, 0.f);
  hp[3] = fmaxf(a[3] + b1v.w, 0.f);
  __syncthreads();
  const int c = t & 31;
  const float b2v = b2[c];
  float rsum = 0.f, rq = 0.f;
#pragma unroll
  for (int rep = 0; rep < 4; ++rep) {
    const int row = (t >> 5) + rep * 8;
    const float* hr = A1 + row * 33;
    float acc = b2v;
#pragma unroll
    for (int k = 0; k < 32; ++k) acc = fmaf(hr[k], W2s[k * 33 + c], acc);
    acc = fmaxf(acc, 0.f);
    yout[(size_t)(blockIdx.x * 32 + row) * 32 + c] = f2h(acc);
    rsum += acc;
    rq += acc * acc;
  }
  rsum += __shfl_down(rsum, 32);
  rq += __shfl_down(rq, 32);
  __syncthreads();
  const int wv_ = t >> 6, lane = t & 63;
  if (lane < 32) {
    red[wv_ * 32 + lane] = rsum;
    red[128 + wv_ * 32 + lane] = rq;
  }
  __syncthreads();
  if (t < 32) {
    float aa = red[t] + red[32 + t] + red[64 + t] + red[96 + t];
    float bb = red[128 + t] + red[160 + t] + red[192 + t] + red[224 + t];
    unsafeAtomicAdd(&stats_out[t], aa);
    unsafeAtomicAdd(&stats_out[32 + t], bb);
  }
}

__global__ __launch_bounds__(256) void k_layer(
    const u16t* __restrict__ yin, const u32t* __restrict__ rs, const int* __restrict__ ssrc,
    const float* __restrict__ stats, const float* __restrict__ gamma, const float* __restrict__ beta,
    const float* __restrict__ W1, const float* __restrict__ b1,
    const float* __restrict__ W2, const float* __restrict__ b2,
    u16t* __restrict__ yout, float* __restrict__ stats_out)
{
  __shared__ float W1s[32 * 33];
  __shared__ float W2s[32 * 33];
  __shared__ float A1[32 * 33];
  __shared__ float A2[32 * 33];
  __shared__ float red[256];
  const int t = threadIdx.x;
  for (int id = t; id < 1024; id += 256) {
    int k = id >> 5, c = id & 31;
    W1s[k * 33 + c] = W1[id];
    W2s[k * 33 + c] = W2[id];
  }
  const int nl = t >> 3, c0 = (t & 7) * 4;
  const int n = blockIdx.x * 32 + nl;
  float sc[4], sh[4];
  {
    const float4 s1 = *(const float4*)(stats + c0);
    const float4 s2 = *(const float4*)(stats + 32 + c0);
    const float4 gm = *(const float4*)(gamma + c0);
    const float4 bt = *(const float4*)(beta + c0);
    const float m0 = s1.x * (1.f / NN), m1 = s1.y * (1.f / NN),
                m2 = s1.z * (1.f / NN), m3 = s1.w * (1.f / NN);
    sc[0] = gm.x * rsqrtf(fmaxf(s2.x * (1.f / NN) - m0 * m0, 0.f) + BN_EPS);
    sc[1] = gm.y * rsqrtf(fmaxf(s2.y * (1.f / NN) - m1 * m1, 0.f) + BN_EPS);
    sc[2] = gm.z * rsqrtf(fmaxf(s2.z * (1.f / NN) - m2 * m2, 0.f) + BN_EPS);
    sc[3] = gm.w * rsqrtf(fmaxf(s2.w * (1.f / NN) - m3 * m3, 0.f) + BN_EPS);
    sh[0] = bt.x - m0 * sc[0];
    sh[1] = bt.y - m1 * sc[1];
    sh[2] = bt.z - m2 * sc[2];
    sh[3] = bt.w - m3 * sc[3];
  }
  float a[4] = {0.f, 0.f, 0.f, 0.f};
  add4h(a, *(const uint2*)(yin + (size_t)n * 32 + c0));
  const u32t e0 = rs[n], e1 = rs[n + 1];
  u32t e = e0;
  for (; e + 4 <= e1; e += 4) {
    const int s0v = ssrc[e], s1v = ssrc[e + 1], s2v = ssrc[e + 2], s3v = ssrc[e + 3];
    const uint2 v0 = *(const uint2*)(yin + (size_t)s0v * 32 + c0);
    const uint2 v1 = *(const uint2*)(yin + (size_t)s1v * 32 + c0);
    const uint2 v2 = *(const uint2*)(yin + (size_t)s2v * 32 + c0);
    const uint2 v3 = *(const uint2*)(yin + (size_t)s3v * 32 + c0);
    add4h(a, v0); add4h(a, v1); add4h(a, v2); add4h(a, v3);
  }
  for (; e < e1; ++e)
    add4h(a, *(const uint2*)(yin + (size_t)ssrc[e] * 32 + c0));
  const float cnt = (float)(e1 - e0 + 1u);
  float* hp = A1 + nl * 33 + c0;
#pragma unroll
  for (int j = 0; j < 4; ++j) hp[j] = sc[j] * a[j] + cnt * sh[j];
  __syncthreads();
  const int c = t & 31;
  const float b1v = b1[c];
#pragma unroll
  for (int rep = 0; rep < 4; ++rep) {
    const int row = (t >> 5) + rep * 8;
    const float* hr = A1 + row * 33;
    float acc = b1v;
#pragma unroll
    for (int k = 0; k < 32; ++k) acc = fmaf(hr[k], W1s[k * 33 + c], acc);
    A2[row * 33 + c] = fmaxf(acc, 0.f);
  }
  __syncthreads();
  const float b2v = b2[c];
  float rsum = 0.f, rq = 0.f;
#pragma unroll
  for (int rep = 0; rep < 4; ++rep) {
    const int row = (t >> 5) + rep * 8;
    const float* hr = A2 + row * 33;
    float acc = b2v;
#pragma unroll
    for (int k = 0; k < 32; ++k) acc = fmaf(hr[k], W2s[k * 33 + c], acc);
    acc = fmaxf(acc, 0.f);
    yout[(size_t)(blockIdx.x * 32 + row) * 32 + c] = f2h(acc);
    rsum += acc;
    rq += acc * acc;
  }
  rsum += __shfl_down(rsum, 32);
  rq += __shfl_down(rq, 32);
  __syncthreads();
  const int wv_ = t >> 6, lane = t & 63;
  if (lane < 32) {
    red[wv_ * 32 + lane] = rsum;
    red[128 + wv_ * 32 + lane] = rq;
  }
  __syncthreads();
  if (t < 32) {
    float aa = red[t] + red[32 + t] + red[64 + t] + red[96 + t];
    float bb = red[128 + t] + red[160 + t] + red[192 + t] + red[224 + t];
    unsafeAtomicAdd(&stats_out[t], aa);
    unsafeAtomicAdd(&stats_out[32 + t], bb);
  }
}

__global__ __launch_bounds__(64) void k_pool_xd(
    const u16t* __restrict__ y, const int* __restrict__ batch,
    const float* __restrict__ stats, const float* __restrict__ gamma,
    const float* __restrict__ beta, const float* __restrict__ Wxd,
    const float* __restrict__ bxd, u16t* __restrict__ xc)
{
  const int g = blockIdx.x, t = threadIdx.x;
  int lo = 0, n = NN;
  while (n > 0) {
    int h = n >> 1, m = lo + h;
    if (batch[m] < g) { lo = m + 1; n -= h + 1; } else n = h;
  }
  int hi = lo;
  n = NN - lo;
  while (n > 0) {
    int h = n >> 1, m = hi + h;
    if (batch[m] < g + 1) { hi = m + 1; n -= h + 1; } else n = h;
  }
  const int c = t & 31;
  const float mu = stats[4 * 64 + c] * (1.f / NN);
  float var = fmaxf(stats[4 * 64 + 32 + c] * (1.f / NN) - mu * mu, 0.f);
  const float sc = gamma[4 * 32 + c] * rsqrtf(var + BN_EPS);
  const float sh = beta[4 * 32 + c] - mu * sc;
  float acc = 0.f;
  for (int i = lo + (t >> 5); i < hi; i += 2) acc += h2f(y[(size_t)i * 32 + c]);
  acc += __shfl_down(acc, 32);
  __shared__ float pl[32];
  if (t < 32) pl[t] = acc * sc + (float)(hi - lo) * sh;
  __syncthreads();
#pragma unroll
  for (int rep = 0; rep < 2; ++rep) {
    const int o = t + rep * 64;
    float a = bxd[o];
#pragma unroll
    for (int cc = 0; cc < 32; ++cc) a = fmaf(pl[cc], Wxd[cc * 128 + o], a);
    xc[(size_t)g * 256 + o] = f2bf(fmaxf(a, 0.f));
  }
}

// ---------------- weight prep ----------------
__global__ __launch_bounds__(256) void k_prep(
    const float* __restrict__ w2, const float* __restrict__ w3,
    const float* __restrict__ wxt, const float* __restrict__ wf1, const float* __restrict__ wf2,
    u16t* __restrict__ W2k, u16t* __restrict__ W3k,
    u16t* __restrict__ WXT, u16t* __restrict__ WF1, u16t* __restrict__ WF2)
{
  const int i = blockIdx.x * 256 + threadIdx.x;
  if (i < 64 * 256) {
    int c2 = i >> 8, kk = i & 255, tt = kk >> 5, ci = kk & 31;
    W2k[i] = f2bf(w2[c2 * 256 + ci * 8 + tt]);
  }
  if (i < 128 * 512) {
    int c3 = i >> 9, kk = i & 511, tt = kk >> 6, ci = kk & 63;
    W3k[i] = f2bf(w3[c3 * 512 + ci * 8 + tt]);
  }
  if (i < 128 * 2944) {
    int nn = i / 2944, kk = i - nn * 2944;
    WXT[i] = f2bf(wxt[kk * 128 + nn]);
  }
  if (i < 1024 * 256) {
    int nn = i >> 8, kk = i & 255;
    WF1[i] = f2bf(wf1[kk * 1024 + nn]);
  }
  if (i < 128 * 1024) {
    int nn = i >> 10, kk = i & 1023;
    WF2[i] = f2bf(wf2[kk * 128 + nn]);   // FIXED: was OOB wf2[kk*1024+nn]*0.f + ...
  }
}

// ---------------- fused per-graph CNN ----------------
// LDS (30720 B -> 5 blocks/CU):
//  xot f32[768] @0 | w1s f32[256] @3072 | b2s[64] @4096 | b3s[128] @4352
//  T1T u16 [248 rows x 32] swizzled @4864 (15872B)   [stg overlays @4864 in conv3]
//  T2B bytes [78 rows x 128B] swizzled @20736 (9984B)
__global__ __launch_bounds__(256, 5) void k_cnn(
    const float* __restrict__ xo,
    const float* __restrict__ w1, const float* __restrict__ b1,
    const u16t* __restrict__ W2k, const float* __restrict__ b2,
    const u16t* __restrict__ W3k, const float* __restrict__ b3,
    u16t* __restrict__ t3)
{
  __shared__ __align__(16) char smem[30720];
  float* xot = (float*)(smem);
  float* w1s = (float*)(smem + 3072);
  float* b2s = (float*)(smem + 4096);
  float* b3s = (float*)(smem + 4352);
  short* T1T = (short*)(smem + 4864);
  char*  T2B = smem + 20736;
  u16t*  stg = (u16t*)(smem + 4864);

  const int g = blockIdx.x, t = threadIdx.x;
  const int w = t >> 6, l = t & 63, col = l & 15, kg = l >> 4;

  for (int i = t; i < 768; i += 256) xot[i] = (i < 735) ? xo[(size_t)g * 735 + i] : 0.f;
  w1s[t] = w1[t];
  if (t < 64) b2s[t] = b2[t];
  if (t < 128) b3s[t] = b3[t];
  if (t < 192) {  // zero pad rows 242..247 (full rows -> swizzle-safe)
    int r = 242 + (t >> 5), c = t & 31;
    T1T[r * 32 + c] = 0;
  }
  __syncthreads();

  // conv1 fp32 + relu + pool3 -> T1T [pos][32ch] swizzled (slot ^= pos&3)
  {
    const int c = t >> 3, qg = t & 7;
    float wv[8];
#pragma unroll
    for (int j = 0; j < 8; ++j) wv[j] = w1s[c * 8 + j];
    const float bias = b1[c];
    const int q0 = qg * 31, qe = (q0 + 31 < 242) ? q0 + 31 : 242;
#pragma unroll 1
    for (int qc = q0; qc < qe; qc += 10) {
      const int cnt = (qe - qc < 10) ? qe - qc : 10;
      float xv[37];
#pragma unroll
      for (int j = 0; j < 37; ++j) xv[j] = xot[3 * qc + j];
#pragma unroll
      for (int j0 = 0; j0 < 10; ++j0) {
        if (j0 < cnt) {
          float a0 = bias, a1 = bias, a2 = bias;
#pragma unroll
          for (int tt = 0; tt < 8; ++tt) {
            a0 = fmaf(wv[tt], xv[3 * j0 + tt], a0);
            a1 = fmaf(wv[tt], xv[3 * j0 + 1 + tt], a1);
            a2 = fmaf(wv[tt], xv[3 * j0 + 2 + tt], a2);
          }
          float m = fmaxf(fmaxf(a0, a1), fmaxf(a2, 0.f));
          const int pos = qc + j0;
          T1T[pos * 32 + (c ^ ((pos & 3) << 3))] = (short)f2bf(m);
        }
      }
    }
  }
  __syncthreads();

  // conv2 (32->64,k8): wave w owns out-ch [w*16,w*16+16). pool3 in-register.
  {
    bf16x8 am[8];
#pragma unroll
    for (int kk = 0; kk < 8; ++kk)
      am[kk] = *(const bf16x8*)(W2k + (w * 16 + col) * 256 + kk * 32 + kg * 8);
#pragma unroll 1
    for (int qt = 0; qt < 5; ++qt) {
      const int rbase = qt * 48 + col * 3;
      bf16x8 rv[10];
#pragma unroll
      for (int s = 0; s < 10; ++s) {
        const int row = rbase + s;
        rv[s] = *(const bf16x8*)(T1T + row * 32 + ((kg ^ (row & 3)) << 3));
      }
      f32x4 a0 = {0.f, 0.f, 0.f, 0.f}, a1 = a0, a2 = a0;
#pragma unroll
      for (int kk = 0; kk < 8; ++kk) {
        a0 = __builtin_amdgcn_mfma_f32_16x16x32_bf16(am[kk], rv[kk], a0, 0, 0, 0);
        a1 = __builtin_amdgcn_mfma_f32_16x16x32_bf16(am[kk], rv[kk + 1], a1, 0, 0, 0);
        a2 = __builtin_amdgcn_mfma_f32_16x16x32_bf16(am[kk], rv[kk + 2], a2, 0, 0, 0);
      }
      const int q = qt * 16 + col;
      if (q < 78) {
        union { u16t u[4]; uint2 v; } pk;
#pragma unroll
        for (int r = 0; r < 4; ++r) {
          const float bb = b2s[w * 16 + kg * 4 + r];
          float m = fmaxf(fmaxf(a0[r], a1[r]), a2[r]);
          pk.u[r] = f2bf(fmaxf(m + bb, 0.f));
        }
        const int boff = (q * 128 + (w * 16 + kg * 4) * 2) ^ ((q & 7) << 4);
        *(uint2*)(T2B + boff) = pk.v;
      }
    }
  }
  __syncthreads();

  // conv3 (64->128,k8): wave w owns out-ch blocks {2w,2w+1}. pool3 in-register.
  {
#pragma unroll 1
    for (int mi = 0; mi < 2; ++mi) {
      const int m3 = w * 2 + mi;
      f32x4 acc[2][3];
#pragma unroll
      for (int qt = 0; qt < 2; ++qt)
#pragma unroll
        for (int r = 0; r < 3; ++r) acc[qt][r] = (f32x4){0.f, 0.f, 0.f, 0.f};
#pragma unroll 1
      for (int kh = 0; kh < 2; ++kh) {
        bf16x8 amh[8];
#pragma unroll
        for (int tt = 0; tt < 8; ++tt)
          amh[tt] = *(const bf16x8*)(W3k + (m3 * 16 + col) * 512 + (tt * 2 + kh) * 32 + kg * 8);
#pragma unroll 1
        for (int qt = 0; qt < 2; ++qt) {
          const int rbase = qt * 48 + col * 3;
          bf16x8 rv[10];
#pragma unroll
          for (int s = 0; s < 10; ++s) {
            int row = rbase + s;
            row = (row < 78) ? row : 77;  // clamp: garbage only feeds discarded cols
            const int boff = (row * 128 + kh * 64 + kg * 16) ^ ((row & 7) << 4);
            rv[s] = *(const bf16x8*)(T2B + boff);
          }
#pragma unroll
          for (int tt = 0; tt < 8; ++tt) {
            acc[qt][0] = __builtin_amdgcn_mfma_f32_16x16x32_bf16(amh[tt], rv[tt], acc[qt][0], 0, 0, 0);
            acc[qt][1] = __builtin_amdgcn_mfma_f32_16x16x32_bf16(amh[tt], rv[tt + 1], acc[qt][1], 0, 0, 0);
            acc[qt][2] = __builtin_amdgcn_mfma_f32_16x16x32_bf16(amh[tt], rv[tt + 2], acc[qt][2], 0, 0, 0);
          }
        }
      }
#pragma unroll
      for (int qt = 0; qt < 2; ++qt) {
        const int q = qt * 16 + col;
        if (q < 23) {
#pragma unroll
          for (int r = 0; r < 4; ++r) {
            const int c = m3 * 16 + kg * 4 + r;
            float m = fmaxf(fmaxf(acc[qt][0][r], acc[qt][1][r]), acc[qt][2][r]);
            stg[c * 23 + q] = f2bf(fmaxf(m + b3s[c], 0.f));
          }
        }
      }
    }
  }
  __syncthreads();

  // coalesced t3 store: 2944 u16 = 368 uint4
  {
    const uint4* s4 = (const uint4*)stg;
    uint4* d4 = (uint4*)(t3 + (size_t)g * 2944);
    for (int id = t; id < 368; id += 256) d4[id] = s4[id];
  }
}

// ---------------- bf16 MFMA GEMM ----------------
__global__ __launch_bounds__(256) void k_mgemm(
    const u16t* __restrict__ A, int lda,
    const u16t* __restrict__ WT, const float* __restrict__ bias,
    void* __restrict__ Cv, int ldc, int c_off, int M, int Kd,
    int relu_f, int out32)
{
  __shared__ __align__(16) u16t As[128 * 4 * 8];
  __shared__ __align__(16) u16t Ws2[64 * 4 * 8];
  const int t = threadIdx.x;
  const int w = t >> 6, l = t & 63, col = l & 15, kg = l >> 4;
  const int wm = w & 1, wn = w >> 1;
  const int m0 = blockIdx.x * 128, n0 = blockIdx.y * 64;
  f32x4 acc[4][2];
#pragma unroll
  for (int i = 0; i < 4; ++i)
#pragma unroll
    for (int j = 0; j < 2; ++j) acc[i][j] = (f32x4){0.f, 0.f, 0.f, 0.f};
  const int ar = t >> 1, ac = (t & 1) * 2;
  const int wr = t >> 2, wc = t & 3;
  const bool aok = (m0 + ar) < M;
  const u16t* Ap = A + (size_t)(m0 + ar) * lda;
  const u16t* Wp = WT + (size_t)(n0 + wr) * Kd;
  for (int k0 = 0; k0 < Kd; k0 += 32) {
    bf16x8 av0 = {0, 0, 0, 0, 0, 0, 0, 0}, av1 = {0, 0, 0, 0, 0, 0, 0, 0};
    if (aok) {
      av0 = *(const bf16x8*)(Ap + k0 + ac * 8);
      av1 = *(const bf16x8*)(Ap + k0 + (ac + 1) * 8);
    }
    const bf16x8 wv = *(const bf16x8*)(Wp + k0 + wc * 8);
    __syncthreads();
    *(bf16x8*)(As + (ar * 4 + (ac ^ (ar & 3))) * 8) = av0;
    *(bf16x8*)(As + (ar * 4 + ((ac + 1) ^ (ar & 3))) * 8) = av1;
    *(bf16x8*)(Ws2 + (wr * 4 + (wc ^ (wr & 3))) * 8) = wv;
    __syncthreads();
    bf16x8 af[4], bf[2];
#pragma unroll
    for (int i = 0; i < 4; ++i) {
      const int R = wm * 64 + i * 16 + col;
      af[i] = *(const bf16x8*)(As + (R * 4 + (kg ^ (R & 3))) * 8);
    }
#pragma unroll
    for (int j = 0; j < 2; ++j) {
      const int R = wn * 32 + j * 16 + col;
      bf[j] = *(const bf16x8*)(Ws2 + (R * 4 + (kg ^ (R & 3))) * 8);
    }
#pragma unroll
    for (int i = 0; i < 4; ++i)
#pragma unroll
      for (int j = 0; j < 2; ++j)
        acc[i][j] = __builtin_amdgcn_mfma_f32_16x16x32_bf16(af[i], bf[j], acc[i][j], 0, 0, 0);
  }
#pragma unroll
  for (int j = 0; j < 2; ++j) {
    const int gn = n0 + wn * 32 + j * 16 + col;
    const float bb = bias[gn];
#pragma unroll
    for (int i = 0; i < 4; ++i) {
      const int gmb = m0 + wm * 64 + i * 16 + kg * 4;
#pragma unroll
      for (int r = 0; r < 4; ++r) {
        const int gm = gmb + r;
        if (gm < M) {
          float v = acc[i][j][r] + bb;
          if (relu_f) v = fmaxf(v, 0.f);
          if (out32) ((float*)Cv)[(size_t)gm * ldc + c_off + gn] = v;
          else ((u16t*)Cv)[(size_t)gm * ldc + c_off + gn] = f2bf(v);
        }
      }
    }
  }
}

__global__ __launch_bounds__(256) void k_out(
    const float* __restrict__ h2, const float* __restrict__ Wo,
    const float* __restrict__ bo, float* __restrict__ out)
{
  __shared__ float Ws_[128];
  const int t = threadIdx.x;
  if (t < 128) Ws_[t] = Wo[t];
  __syncthreads();
  const int g = blockIdx.x * 32 + (t >> 3), l = t & 7;
  float acc = 0.f;
  if (g < NG) {
    const float* hr = h2 + (size_t)g * 128 + l * 16;
    const float* wr = Ws_ + l * 16;
#pragma unroll
    for (int j = 0; j < 16; ++j) acc = fmaf(hr[j], wr[j], acc);
  }
  acc += __shfl_down(acc, 4, 8);
  acc += __shfl_down(acc, 2, 8);
  acc += __shfl_down(acc, 1, 8);
  if (l == 0 && g < NG) out[g] = acc + bo[0];
}

extern "C" void kernel_launch(void* const* d_in, const int* in_sizes, int n_in,
                              void* d_out, int out_size, void* d_ws, size_t ws_size,
                              hipStream_t stream) {
  const float* x    = (const float*)d_in[0];
  const int*   ei   = (const int*)d_in[1];
  const int*   batch= (const int*)d_in[2];
  const float* xo   = (const float*)d_in[3];
  const float* g1W1 = (const float*)d_in[4];
  const float* g1b1 = (const float*)d_in[5];
  const float* g1W2 = (const float*)d_in[6];
  const float* g1b2 = (const float*)d_in[7];
  const float* gsW1 = (const float*)d_in[8];
  const float* gsb1 = (const float*)d_in[9];
  const float* gsW2 = (const float*)d_in[10];
  const float* gsb2 = (const float*)d_in[11];
  const float* bng  = (const float*)d_in[12];
  const float* bnb  = (const float*)d_in[13];
  const float* Wxd  = (const float*)d_in[14];
  const float* bxd  = (const float*)d_in[15];
  const float* c1W  = (const float*)d_in[16];
  const float* c1b  = (const float*)d_in[17];
  const float* c2W  = (const float*)d_in[18];
  const float* c2b  = (const float*)d_in[19];
  const float* c3W  = (const float*)d_in[20];
  const float* c3b  = (const float*)d_in[21];
  const float* Wxt  = (const float*)d_in[22];
  const float* bxt  = (const float*)d_in[23];
  const float* W1f  = (const float*)d_in[24];
  const float* b1f  = (const float*)d_in[25];
  const float* W2f  = (const float*)d_in[26];
  const float* b2f  = (const float*)d_in[27];
  const float* Wo   = (const float*)d_in[28];
  const float* bo   = (const float*)d_in[29];

  char* ws = (char*)d_ws;
  u16t*  U   = (u16t*)(ws + OFF_U);
  u16t*  YA  = (u16t*)(ws + OFF_YA);
  u16t*  YB  = (u16t*)(ws + OFF_U);
  float* ST  = (float*)(ws + OFF_ST);
  u32t*  RS  = (u32t*)(ws + OFF_RS);
  u32t*  CUR = (u32t*)(ws + OFF_CUR);
  u32t*  BS  = (u32t*)(ws + OFF_BSUM);
  int*   SSRC= (int*)(ws + OFF_SSRC);
  u16t*  WK  = (u16t*)(ws + OFF_WK);
  u16t*  W2K = WK;
  u16t*  W3K = WK + 16384;
  u16t*  WXT = WK + 16384 + 65536;
  u16t*  WF1 = WK + 16384 + 65536 + 376832;
  u16t*  WF2 = WK + 16384 + 65536 + 376832 + 262144;
  u16t*  XC  = (u16t*)(ws + OFF_XC);
  u16t*  T3  = (u16t*)(ws + OFF_T3);
  u16t*  H1  = (u16t*)(ws + OFF_H1);
  float* H2  = (float*)(ws + OFF_H2);
  float* OUT = (float*)d_out;

  const int NBLK = (NN + 1023) / 1024;

  hipMemsetAsync(ST, 0, 5 * 64 * sizeof(float), stream);
  hipMemsetAsync(CUR, 0, NN * sizeof(u32t), stream);

  k_prep<<<(128 * 2944 + 255) / 256, 256, 0, stream>>>(c2W, c3W, Wxt, W1f, W2f,
                                                        W2K, W3K, WXT, WF1, WF2);

  k_hist<<<(NE + 255) / 256, 256, 0, stream>>>(ei, CUR);
  k_scan1<<<NBLK, 256, 0, stream>>>(CUR, BS);
  k_scan2<<<1, 256, 0, stream>>>(BS, RS, NBLK);
  k_scan3<<<NBLK, 256, 0, stream>>>(CUR, RS, BS);
  k_scatter<<<(NE + 255) / 256, 256, 0, stream>>>(ei, CUR, SSRC);

  k_mlp1_first<<<2048, 256, 0, stream>>>(x, g1W1, U);
  k_agg0<<<NN / 32, 256, 0, stream>>>(U, RS, SSRC, g1b1, g1W2, g1b2, YA, ST + 0);
  const u16t* yin = YA;
  u16t* yout = YB;
  for (int lyr = 1; lyr <= 4; ++lyr) {
    k_layer<<<NN / 32, 256, 0, stream>>>(yin, RS, SSRC, ST + (lyr - 1) * 64,
                                         bng + (lyr - 1) * 32, bnb + (lyr - 1) * 32,
                                         gsW1 + (lyr - 1) * 1024, gsb1 + (lyr - 1) * 32,
                                         gsW2 + (lyr - 1) * 1024, gsb2 + (lyr - 1) * 32,
                                         yout, ST + lyr * 64);
    const u16t* tmp = yin;
    yin = yout;
    yout = (u16t*)tmp;
  }
  k_pool_xd<<<NG, 64, 0, stream>>>(yin, batch, ST, bng, bnb, Wxd, bxd, XC);

  k_cnn<<<NG, 256, 0, stream>>>(xo, c1W, c1b, W2K, c2b, W3K, c3b, T3);

  {
    dim3 grid((NG + 127) / 128, 2);
    k_mgemm<<<grid, 256, 0, stream>>>(T3, 2944, WXT, bxt, XC, 256, 128, NG, 2944, 0, 0);
  }
  {
    dim3 grid((NG + 127) / 128, 16);
    k_mgemm<<<grid, 256, 0, stream>>>(XC, 256, WF1, b1f, H1, 1024, 0, NG, 256, 1, 0);
  }
  {
    dim3 grid((NG + 127) / 128, 2);
    k_mgemm<<<grid, 256, 0, stream>>>(H1, 1024, WF2, b2f, H2, 128, 0, NG, 1024, 1, 1);
  }
  k_out<<<(NG + 31) / 32, 256, 0, stream>>>(H2, Wo, bo, OUT);
}

// Round 8
// 4021.131 us; speedup vs baseline: 4.3361x; 1.1067x over previous
//
#include <hip/hip_runtime.h>

#define NN 1000000
#define NE 4000000
#define NG 25000
#define BN_EPS 1e-5f

typedef unsigned short u16t;
typedef unsigned int u32t;
typedef __attribute__((ext_vector_type(8))) short bf16x8;
typedef __attribute__((ext_vector_type(4))) float f32x4;

__device__ inline u16t f2bf(float f) {
  u32t u = __float_as_uint(f);
  u32t r = (u + 0x7FFFu + ((u >> 16) & 1u)) >> 16;
  return (u16t)r;
}
__device__ inline float bf2f(u16t h) { return __uint_as_float((u32t)h << 16); }
__device__ inline u16t f2h(float f) {
  _Float16 h = (_Float16)f;
  return *(u16t*)&h;
}
__device__ inline float h2f(u16t v) {
  _Float16 h = *(_Float16*)&v;
  return (float)h;
}
__device__ inline void add4h(float* a, uint2 v) {
  union { uint2 u; _Float16 h[4]; } cv;
  cv.u = v;
  a[0] += (float)cv.h[0];
  a[1] += (float)cv.h[1];
  a[2] += (float)cv.h[2];
  a[3] += (float)cv.h[3];
}

// ---- workspace layout (bytes) ----
static const size_t OFF_U    = 0;           // fp16 64MB; also YB
static const size_t OFF_YA   = 130000000;
static const size_t OFF_ST   = 258000000;
static const size_t OFF_RS   = 259000000;
static const size_t OFF_CUR  = 263200000;
static const size_t OFF_BSUM = 267300000;
static const size_t OFF_SSRC = 268000000;
static const size_t OFF_WK   = 285000000;
static const size_t OFF_XC   = 287000000;
static const size_t OFF_T3   = 0;
static const size_t OFF_H1   = 150000000;
static const size_t OFF_H2   = 210000000;

// ---------------- CSR build ----------------
__global__ __launch_bounds__(256) void k_hist(const int* __restrict__ ei, u32t* __restrict__ cnt) {
  const int i = blockIdx.x * 256 + threadIdx.x;
  if (i < NE) atomicAdd(&cnt[ei[NE + i]], 1u);
}

__global__ __launch_bounds__(256) void k_scan1(const u32t* __restrict__ deg, u32t* __restrict__ bsum) {
  __shared__ u32t red[4];
  const int b = blockIdx.x, t = threadIdx.x;
  u32t s = 0;
#pragma unroll
  for (int j = 0; j < 4; ++j) {
    const int i = b * 1024 + j * 256 + t;
    if (i < NN) s += deg[i];
  }
#pragma unroll
  for (int off = 32; off > 0; off >>= 1) s += __shfl_down(s, off);
  if ((t & 63) == 0) red[t >> 6] = s;
  __syncthreads();
  if (t == 0) bsum[b] = red[0] + red[1] + red[2] + red[3];
}

__global__ __launch_bounds__(256) void k_scan2(u32t* __restrict__ bsum, u32t* __restrict__ rs, int nblk) {
  __shared__ u32t sh[256];
  const int t = threadIdx.x;
  u32t v[4];
#pragma unroll
  for (int j = 0; j < 4; ++j) {
    const int i = t * 4 + j;
    v[j] = (i < nblk) ? bsum[i] : 0u;
  }
  const u32t tot = v[0] + v[1] + v[2] + v[3];
  sh[t] = tot;
  __syncthreads();
  for (int off = 1; off < 256; off <<= 1) {
    u32t add = (t >= off) ? sh[t - off] : 0u;
    __syncthreads();
    sh[t] += add;
    __syncthreads();
  }
  const u32t tb = (t == 0) ? 0u : sh[t - 1];
  u32t run = tb;
#pragma unroll
  for (int j = 0; j < 4; ++j) {
    const int i = t * 4 + j;
    if (i < nblk) bsum[i] = run;
    run += v[j];
  }
  if (t == 0) rs[NN] = NE;
}

__global__ __launch_bounds__(256) void k_scan3(u32t* __restrict__ cur, u32t* __restrict__ rs,
                                               const u32t* __restrict__ bsum) {
  __shared__ u32t sh[256];
  const int b = blockIdx.x, t = threadIdx.x;
  const int i0 = b * 1024 + t * 4;
  u32t v[4];
#pragma unroll
  for (int j = 0; j < 4; ++j) v[j] = (i0 + j < NN) ? cur[i0 + j] : 0u;
  sh[t] = v[0] + v[1] + v[2] + v[3];
  __syncthreads();
  for (int off = 1; off < 256; off <<= 1) {
    u32t add = (t >= off) ? sh[t - off] : 0u;
    __syncthreads();
    sh[t] += add;
    __syncthreads();
  }
  u32t run = bsum[b] + ((t == 0) ? 0u : sh[t - 1]);
#pragma unroll
  for (int j = 0; j < 4; ++j) {
    const int i = i0 + j;
    if (i < NN) { rs[i] = run; cur[i] = run; }
    run += v[j];
  }
}

__global__ __launch_bounds__(256) void k_scatter(const int* __restrict__ ei,
                                                 u32t* __restrict__ cur, int* __restrict__ ssrc) {
  const int i = blockIdx.x * 256 + threadIdx.x;
  if (i < NE) {
    const int src = ei[i], dst = ei[NE + i];
    const u32t pos = atomicAdd(&cur[dst], 1u);
    ssrc[pos] = src;
  }
}

// ---------------- GNN kernels ----------------

__global__ __launch_bounds__(256) void k_mlp1_first(
    const float* __restrict__ x, const float* __restrict__ W1, u16t* __restrict__ u)
{
  __shared__ float Wt[78 * 33];
  __shared__ float xt_[8 * 79];
  const int t = threadIdx.x;
  for (int id = t; id < 78 * 32; id += 256) {
    int k = id >> 5, c = id & 31;
    Wt[k * 33 + c] = W1[id];
  }
  const int c = t & 31, nl = t >> 5;
  const int ntiles = NN / 8;
  for (int tile = blockIdx.x; tile < ntiles; tile += gridDim.x) {
    const int n0 = tile * 8;
    __syncthreads();
    for (int id = t; id < 8 * 78; id += 256) {
      int r = id / 78, k = id - r * 78;
      xt_[r * 79 + k] = x[(size_t)n0 * 78 + id];
    }
    __syncthreads();
    float acc = 0.f;
    const float* xr = xt_ + nl * 79;
#pragma unroll
    for (int k = 0; k < 78; ++k) acc = fmaf(xr[k], Wt[k * 33 + c], acc);
    u[(size_t)(n0 + nl) * 32 + c] = f2h(acc);
  }
}

__global__ __launch_bounds__(256) void k_agg0(
    const u16t* __restrict__ u, const u32t* __restrict__ rs, const int* __restrict__ ssrc,
    const float* __restrict__ b1, const float* __restrict__ W2, const float* __restrict__ b2,
    u16t* __restrict__ yout, float* __restrict__ stats_out)
{
  __shared__ float W2s[32 * 33];
  __shared__ float A1[32 * 33];
  __shared__ float red[256];
  const int t = threadIdx.x;
  for (int id = t; id < 1024; id += 256) {
    int k = id >> 5, c = id & 31;
    W2s[k * 33 + c] = W2[id];
  }
  const int nl = t >> 3, c0 = (t & 7) * 4;
  const int n = blockIdx.x * 32 + nl;
  float a[4] = {0.f, 0.f, 0.f, 0.f};
  add4h(a, *(const uint2*)(u + (size_t)n * 32 + c0));
  const u32t e0 = rs[n], e1 = rs[n + 1];
  u32t e = e0;
  for (; e + 4 <= e1; e += 4) {
    const int s0v = ssrc[e], s1v = ssrc[e + 1], s2v = ssrc[e + 2], s3v = ssrc[e + 3];
    const uint2 v0 = *(const uint2*)(u + (size_t)s0v * 32 + c0);
    const uint2 v1 = *(const uint2*)(u + (size_t)s1v * 32 + c0);
    const uint2 v2 = *(const uint2*)(u + (size_t)s2v * 32 + c0);
    const uint2 v3 = *(const uint2*)(u + (size_t)s3v * 32 + c0);
    add4h(a, v0); add4h(a, v1); add4h(a, v2); add4h(a, v3);
  }
  for (; e < e1; ++e)
    add4h(a, *(const uint2*)(u + (size_t)ssrc[e] * 32 + c0));
  const float4 b1v = *(const float4*)(b1 + c0);
  float* hp = A1 + nl * 33 + c0;
  hp[0] = fmaxf(a[0] + b1v.x, 0.f);
  hp[1] = fmaxf(a[1] + b1v.y, 0.f);
  hp[2] = fmaxf(a[2] + b1v.z, 0.f);
  hp[3] = fmaxf(a[3] + b1v.w, 0.f);
  __syncthreads();
  const int c = t & 31;
  const float b2v = b2[c];
  float rsum = 0.f, rq = 0.f;
#pragma unroll
  for (int rep = 0; rep < 4; ++rep) {
    const int row = (t >> 5) + rep * 8;
    const float* hr = A1 + row * 33;
    float acc = b2v;
#pragma unroll
    for (int k = 0; k < 32; ++k) acc = fmaf(hr[k], W2s[k * 33 + c], acc);
    acc = fmaxf(acc, 0.f);
    yout[(size_t)(blockIdx.x * 32 + row) * 32 + c] = f2h(acc);
    rsum += acc;
    rq += acc * acc;
  }
  rsum += __shfl_down(rsum, 32);
  rq += __shfl_down(rq, 32);
  __syncthreads();
  const int wv_ = t >> 6, lane = t & 63;
  if (lane < 32) {
    red[wv_ * 32 + lane] = rsum;
    red[128 + wv_ * 32 + lane] = rq;
  }
  __syncthreads();
  if (t < 32) {
    float aa = red[t] + red[32 + t] + red[64 + t] + red[96 + t];
    float bb = red[128 + t] + red[160 + t] + red[192 + t] + red[224 + t];
    unsafeAtomicAdd(&stats_out[t], aa);
    unsafeAtomicAdd(&stats_out[32 + t], bb);
  }
}

__global__ __launch_bounds__(256) void k_layer(
    const u16t* __restrict__ yin, const u32t* __restrict__ rs, const int* __restrict__ ssrc,
    const float* __restrict__ stats, const float* __restrict__ gamma, const float* __restrict__ beta,
    const float* __restrict__ W1, const float* __restrict__ b1,
    const float* __restrict__ W2, const float* __restrict__ b2,
    u16t* __restrict__ yout, float* __restrict__ stats_out)
{
  __shared__ float W1s[32 * 33];
  __shared__ float W2s[32 * 33];
  __shared__ float A1[32 * 33];
  __shared__ float A2[32 * 33];
  __shared__ float red[256];
  const int t = threadIdx.x;
  for (int id = t; id < 1024; id += 256) {
    int k = id >> 5, c = id & 31;
    W1s[k * 33 + c] = W1[id];
    W2s[k * 33 + c] = W2[id];
  }
  const int nl = t >> 3, c0 = (t & 7) * 4;
  const int n = blockIdx.x * 32 + nl;
  float sc[4], sh[4];
  {
    const float4 s1 = *(const float4*)(stats + c0);
    const float4 s2 = *(const float4*)(stats + 32 + c0);
    const float4 gm = *(const float4*)(gamma + c0);
    const float4 bt = *(const float4*)(beta + c0);
    const float m0 = s1.x * (1.f / NN), m1 = s1.y * (1.f / NN),
                m2 = s1.z * (1.f / NN), m3 = s1.w * (1.f / NN);
    sc[0] = gm.x * rsqrtf(fmaxf(s2.x * (1.f / NN) - m0 * m0, 0.f) + BN_EPS);
    sc[1] = gm.y * rsqrtf(fmaxf(s2.y * (1.f / NN) - m1 * m1, 0.f) + BN_EPS);
    sc[2] = gm.z * rsqrtf(fmaxf(s2.z * (1.f / NN) - m2 * m2, 0.f) + BN_EPS);
    sc[3] = gm.w * rsqrtf(fmaxf(s2.w * (1.f / NN) - m3 * m3, 0.f) + BN_EPS);
    sh[0] = bt.x - m0 * sc[0];
    sh[1] = bt.y - m1 * sc[1];
    sh[2] = bt.z - m2 * sc[2];
    sh[3] = bt.w - m3 * sc[3];
  }
  float a[4] = {0.f, 0.f, 0.f, 0.f};
  add4h(a, *(const uint2*)(yin + (size_t)n * 32 + c0));
  const u32t e0 = rs[n], e1 = rs[n + 1];
  u32t e = e0;
  for (; e + 4 <= e1; e += 4) {
    const int s0v = ssrc[e], s1v = ssrc[e + 1], s2v = ssrc[e + 2], s3v = ssrc[e + 3];
    const uint2 v0 = *(const uint2*)(yin + (size_t)s0v * 32 + c0);
    const uint2 v1 = *(const uint2*)(yin + (size_t)s1v * 32 + c0);
    const uint2 v2 = *(const uint2*)(yin + (size_t)s2v * 32 + c0);
    const uint2 v3 = *(const uint2*)(yin + (size_t)s3v * 32 + c0);
    add4h(a, v0); add4h(a, v1); add4h(a, v2); add4h(a, v3);
  }
  for (; e < e1; ++e)
    add4h(a, *(const uint2*)(yin + (size_t)ssrc[e] * 32 + c0));
  const float cnt = (float)(e1 - e0 + 1u);
  float* hp = A1 + nl * 33 + c0;
#pragma unroll
  for (int j = 0; j < 4; ++j) hp[j] = sc[j] * a[j] + cnt * sh[j];
  __syncthreads();
  const int c = t & 31;
  const float b1v = b1[c];
#pragma unroll
  for (int rep = 0; rep < 4; ++rep) {
    const int row = (t >> 5) + rep * 8;
    const float* hr = A1 + row * 33;
    float acc = b1v;
#pragma unroll
    for (int k = 0; k < 32; ++k) acc = fmaf(hr[k], W1s[k * 33 + c], acc);
    A2[row * 33 + c] = fmaxf(acc, 0.f);
  }
  __syncthreads();
  const float b2v = b2[c];
  float rsum = 0.f, rq = 0.f;
#pragma unroll
  for (int rep = 0; rep < 4; ++rep) {
    const int row = (t >> 5) + rep * 8;
    const float* hr = A2 + row * 33;
    float acc = b2v;
#pragma unroll
    for (int k = 0; k < 32; ++k) acc = fmaf(hr[k], W2s[k * 33 + c], acc);
    acc = fmaxf(acc, 0.f);
    yout[(size_t)(blockIdx.x * 32 + row) * 32 + c] = f2h(acc);
    rsum += acc;
    rq += acc * acc;
  }
  rsum += __shfl_down(rsum, 32);
  rq += __shfl_down(rq, 32);
  __syncthreads();
  const int wv_ = t >> 6, lane = t & 63;
  if (lane < 32) {
    red[wv_ * 32 + lane] = rsum;
    red[128 + wv_ * 32 + lane] = rq;
  }
  __syncthreads();
  if (t < 32) {
    float aa = red[t] + red[32 + t] + red[64 + t] + red[96 + t];
    float bb = red[128 + t] + red[160 + t] + red[192 + t] + red[224 + t];
    unsafeAtomicAdd(&stats_out[t], aa);
    unsafeAtomicAdd(&stats_out[32 + t], bb);
  }
}

__global__ __launch_bounds__(64) void k_pool_xd(
    const u16t* __restrict__ y, const int* __restrict__ batch,
    const float* __restrict__ stats, const float* __restrict__ gamma,
    const float* __restrict__ beta, const float* __restrict__ Wxd,
    const float* __restrict__ bxd, u16t* __restrict__ xc)
{
  const int g = blockIdx.x, t = threadIdx.x;
  int lo = 0, n = NN;
  while (n > 0) {
    int h = n >> 1, m = lo + h;
    if (batch[m] < g) { lo = m + 1; n -= h + 1; } else n = h;
  }
  int hi = lo;
  n = NN - lo;
  while (n > 0) {
    int h = n >> 1, m = hi + h;
    if (batch[m] < g + 1) { hi = m + 1; n -= h + 1; } else n = h;
  }
  const int c = t & 31;
  const float mu = stats[4 * 64 + c] * (1.f / NN);
  float var = fmaxf(stats[4 * 64 + 32 + c] * (1.f / NN) - mu * mu, 0.f);
  const float sc = gamma[4 * 32 + c] * rsqrtf(var + BN_EPS);
  const float sh = beta[4 * 32 + c] - mu * sc;
  float acc = 0.f;
  for (int i = lo + (t >> 5); i < hi; i += 2) acc += h2f(y[(size_t)i * 32 + c]);
  acc += __shfl_down(acc, 32);
  __shared__ float pl[32];
  if (t < 32) pl[t] = acc * sc + (float)(hi - lo) * sh;
  __syncthreads();
#pragma unroll
  for (int rep = 0; rep < 2; ++rep) {
    const int o = t + rep * 64;
    float a = bxd[o];
#pragma unroll
    for (int cc = 0; cc < 32; ++cc) a = fmaf(pl[cc], Wxd[cc * 128 + o], a);
    xc[(size_t)g * 256 + o] = f2bf(fmaxf(a, 0.f));
  }
}

// ---------------- weight prep ----------------
__global__ __launch_bounds__(256) void k_prep(
    const float* __restrict__ w2, const float* __restrict__ w3,
    const float* __restrict__ wxt, const float* __restrict__ wf1, const float* __restrict__ wf2,
    u16t* __restrict__ W2k, u16t* __restrict__ W3k,
    u16t* __restrict__ WXT, u16t* __restrict__ WF1, u16t* __restrict__ WF2)
{
  const int i = blockIdx.x * 256 + threadIdx.x;
  if (i < 64 * 256) {
    int c2 = i >> 8, kk = i & 255, tt = kk >> 5, ci = kk & 31;
    W2k[i] = f2bf(w2[c2 * 256 + ci * 8 + tt]);
  }
  if (i < 128 * 512) {
    int c3 = i >> 9, kk = i & 511, tt = kk >> 6, ci = kk & 63;
    W3k[i] = f2bf(w3[c3 * 512 + ci * 8 + tt]);
  }
  if (i < 128 * 2944) {
    int nn = i / 2944, kk = i - nn * 2944;
    WXT[i] = f2bf(wxt[kk * 128 + nn]);
  }
  if (i < 1024 * 256) {
    int nn = i >> 8, kk = i & 255;
    WF1[i] = f2bf(wf1[kk * 1024 + nn]);
  }
  if (i < 128 * 1024) {
    int nn = i >> 10, kk = i & 1023;
    WF2[i] = f2bf(wf2[kk * 128 + nn]);
  }
}

// ---------------- fused per-graph CNN ----------------
// LDS (30720 B -> 5 blocks/CU):
//  xot f32[768] @0 | w1s f32[256] @3072 | b2s[64] @4096 | b3s[128] @4352
//  T1T u16 [248 rows x 32] swizzled @4864 (15872B)   [stg overlays @4864 in conv3]
//  T2B bytes [78 rows x 128B] swizzled @20736 (9984B)
__global__ __launch_bounds__(256, 5) void k_cnn(
    const float* __restrict__ xo,
    const float* __restrict__ w1, const float* __restrict__ b1,
    const u16t* __restrict__ W2k, const float* __restrict__ b2,
    const u16t* __restrict__ W3k, const float* __restrict__ b3,
    u16t* __restrict__ t3)
{
  __shared__ __align__(16) char smem[30720];
  float* xot = (float*)(smem);
  float* w1s = (float*)(smem + 3072);
  float* b2s = (float*)(smem + 4096);
  float* b3s = (float*)(smem + 4352);
  short* T1T = (short*)(smem + 4864);
  char*  T2B = smem + 20736;
  u16t*  stg = (u16t*)(smem + 4864);

  const int g = blockIdx.x, t = threadIdx.x;
  const int w = t >> 6, l = t & 63, col = l & 15, kg = l >> 4;

  for (int i = t; i < 768; i += 256) xot[i] = (i < 735) ? xo[(size_t)g * 735 + i] : 0.f;
  w1s[t] = w1[t];
  if (t < 64) b2s[t] = b2[t];
  if (t < 128) b3s[t] = b3[t];
  if (t < 192) {  // zero pad rows 242..247 (full rows -> swizzle-safe)
    int r = 242 + (t >> 5), c = t & 31;
    T1T[r * 32 + c] = 0;
  }
  __syncthreads();

  // conv1 fp32 + relu + pool3 -> T1T [pos][32ch] swizzled (slot ^= pos&3)
  {
    const int c = t >> 3, qg = t & 7;
    float wv[8];
#pragma unroll
    for (int j = 0; j < 8; ++j) wv[j] = w1s[c * 8 + j];
    const float bias = b1[c];
    const int q0 = qg * 31, qe = (q0 + 31 < 242) ? q0 + 31 : 242;
#pragma unroll 1
    for (int qc = q0; qc < qe; qc += 10) {
      const int cnt = (qe - qc < 10) ? qe - qc : 10;
      float xv[37];
#pragma unroll
      for (int j = 0; j < 37; ++j) xv[j] = xot[3 * qc + j];
#pragma unroll
      for (int j0 = 0; j0 < 10; ++j0) {
        if (j0 < cnt) {
          float a0 = bias, a1 = bias, a2 = bias;
#pragma unroll
          for (int tt = 0; tt < 8; ++tt) {
            a0 = fmaf(wv[tt], xv[3 * j0 + tt], a0);
            a1 = fmaf(wv[tt], xv[3 * j0 + 1 + tt], a1);
            a2 = fmaf(wv[tt], xv[3 * j0 + 2 + tt], a2);
          }
          float m = fmaxf(fmaxf(a0, a1), fmaxf(a2, 0.f));
          const int pos = qc + j0;
          T1T[pos * 32 + (c ^ ((pos & 3) << 3))] = (short)f2bf(m);
        }
      }
    }
  }
  __syncthreads();

  // conv2 (32->64,k8): wave w owns out-ch [w*16,w*16+16). pool3 in-register.
  {
    bf16x8 am[8];
#pragma unroll
    for (int kk = 0; kk < 8; ++kk)
      am[kk] = *(const bf16x8*)(W2k + (w * 16 + col) * 256 + kk * 32 + kg * 8);
#pragma unroll 1
    for (int qt = 0; qt < 5; ++qt) {
      const int rbase = qt * 48 + col * 3;
      bf16x8 rv[10];
#pragma unroll
      for (int s = 0; s < 10; ++s) {
        const int row = rbase + s;
        rv[s] = *(const bf16x8*)(T1T + row * 32 + ((kg ^ (row & 3)) << 3));
      }
      f32x4 a0 = {0.f, 0.f, 0.f, 0.f}, a1 = a0, a2 = a0;
#pragma unroll
      for (int kk = 0; kk < 8; ++kk) {
        a0 = __builtin_amdgcn_mfma_f32_16x16x32_bf16(am[kk], rv[kk], a0, 0, 0, 0);
        a1 = __builtin_amdgcn_mfma_f32_16x16x32_bf16(am[kk], rv[kk + 1], a1, 0, 0, 0);
        a2 = __builtin_amdgcn_mfma_f32_16x16x32_bf16(am[kk], rv[kk + 2], a2, 0, 0, 0);
      }
      const int q = qt * 16 + col;
      if (q < 78) {
        union { u16t u[4]; uint2 v; } pk;
#pragma unroll
        for (int r = 0; r < 4; ++r) {
          const float bb = b2s[w * 16 + kg * 4 + r];
          float m = fmaxf(fmaxf(a0[r], a1[r]), a2[r]);
          pk.u[r] = f2bf(fmaxf(m + bb, 0.f));
        }
        const int boff = (q * 128 + (w * 16 + kg * 4) * 2) ^ ((q & 7) << 4);
        *(uint2*)(T2B + boff) = pk.v;
      }
    }
  }
  __syncthreads();

  // conv3 (64->128,k8): wave w owns out-ch blocks {2w,2w+1}. pool3 in-register.
  // NOTE: qt loop is FULLY UNROLLED so acc[qt][r] is compile-time-indexed
  // (rule #20: runtime-indexed ext_vector arrays go to scratch -> 1.1GB HBM spill traffic)
  {
#pragma unroll 1
    for (int mi = 0; mi < 2; ++mi) {
      const int m3 = w * 2 + mi;
      f32x4 acc[2][3];
#pragma unroll
      for (int qt = 0; qt < 2; ++qt)
#pragma unroll
        for (int r = 0; r < 3; ++r) acc[qt][r] = (f32x4){0.f, 0.f, 0.f, 0.f};
#pragma unroll 1
      for (int kh = 0; kh < 2; ++kh) {
        bf16x8 amh[8];
#pragma unroll
        for (int tt = 0; tt < 8; ++tt)
          amh[tt] = *(const bf16x8*)(W3k + (m3 * 16 + col) * 512 + (tt * 2 + kh) * 32 + kg * 8);
#pragma unroll
        for (int qt = 0; qt < 2; ++qt) {
          const int rbase = qt * 48 + col * 3;
          bf16x8 rv[10];
#pragma unroll
          for (int s = 0; s < 10; ++s) {
            int row = rbase + s;
            row = (row < 78) ? row : 77;  // clamp: garbage only feeds discarded cols
            const int boff = (row * 128 + kh * 64 + kg * 16) ^ ((row & 7) << 4);
            rv[s] = *(const bf16x8*)(T2B + boff);
          }
#pragma unroll
          for (int tt = 0; tt < 8; ++tt) {
            acc[qt][0] = __builtin_amdgcn_mfma_f32_16x16x32_bf16(amh[tt], rv[tt], acc[qt][0], 0, 0, 0);
            acc[qt][1] = __builtin_amdgcn_mfma_f32_16x16x32_bf16(amh[tt], rv[tt + 1], acc[qt][1], 0, 0, 0);
            acc[qt][2] = __builtin_amdgcn_mfma_f32_16x16x32_bf16(amh[tt], rv[tt + 2], acc[qt][2], 0, 0, 0);
          }
        }
      }
#pragma unroll
      for (int qt = 0; qt < 2; ++qt) {
        const int q = qt * 16 + col;
        if (q < 23) {
#pragma unroll
          for (int r = 0; r < 4; ++r) {
            const int c = m3 * 16 + kg * 4 + r;
            float m = fmaxf(fmaxf(acc[qt][0][r], acc[qt][1][r]), acc[qt][2][r]);
            stg[c * 23 + q] = f2bf(fmaxf(m + b3s[c], 0.f));
          }
        }
      }
    }
  }
  __syncthreads();

  // coalesced t3 store: 2944 u16 = 368 uint4
  {
    const uint4* s4 = (const uint4*)stg;
    uint4* d4 = (uint4*)(t3 + (size_t)g * 2944);
    for (int id = t; id < 368; id += 256) d4[id] = s4[id];
  }
}

// ---------------- bf16 MFMA GEMM ----------------
__global__ __launch_bounds__(256) void k_mgemm(
    const u16t* __restrict__ A, int lda,
    const u16t* __restrict__ WT, const float* __restrict__ bias,
    void* __restrict__ Cv, int ldc, int c_off, int M, int Kd,
    int relu_f, int out32)
{
  __shared__ __align__(16) u16t As[128 * 4 * 8];
  __shared__ __align__(16) u16t Ws2[64 * 4 * 8];
  const int t = threadIdx.x;
  const int w = t >> 6, l = t & 63, col = l & 15, kg = l >> 4;
  const int wm = w & 1, wn = w >> 1;
  const int m0 = blockIdx.x * 128, n0 = blockIdx.y * 64;
  f32x4 acc[4][2];
#pragma unroll
  for (int i = 0; i < 4; ++i)
#pragma unroll
    for (int j = 0; j < 2; ++j) acc[i][j] = (f32x4){0.f, 0.f, 0.f, 0.f};
  const int ar = t >> 1, ac = (t & 1) * 2;
  const int wr = t >> 2, wc = t & 3;
  const bool aok = (m0 + ar) < M;
  const u16t* Ap = A + (size_t)(m0 + ar) * lda;
  const u16t* Wp = WT + (size_t)(n0 + wr) * Kd;
  for (int k0 = 0; k0 < Kd; k0 += 32) {
    bf16x8 av0 = {0, 0, 0, 0, 0, 0, 0, 0}, av1 = {0, 0, 0, 0, 0, 0, 0, 0};
    if (aok) {
      av0 = *(const bf16x8*)(Ap + k0 + ac * 8);
      av1 = *(const bf16x8*)(Ap + k0 + (ac + 1) * 8);
    }
    const bf16x8 wv = *(const bf16x8*)(Wp + k0 + wc * 8);
    __syncthreads();
    *(bf16x8*)(As + (ar * 4 + (ac ^ (ar & 3))) * 8) = av0;
    *(bf16x8*)(As + (ar * 4 + ((ac + 1) ^ (ar & 3))) * 8) = av1;
    *(bf16x8*)(Ws2 + (wr * 4 + (wc ^ (wr & 3))) * 8) = wv;
    __syncthreads();
    bf16x8 af[4], bf[2];
#pragma unroll
    for (int i = 0; i < 4; ++i) {
      const int R = wm * 64 + i * 16 + col;
      af[i] = *(const bf16x8*)(As + (R * 4 + (kg ^ (R & 3))) * 8);
    }
#pragma unroll
    for (int j = 0; j < 2; ++j) {
      const int R = wn * 32 + j * 16 + col;
      bf[j] = *(const bf16x8*)(Ws2 + (R * 4 + (kg ^ (R & 3))) * 8);
    }
#pragma unroll
    for (int i = 0; i < 4; ++i)
#pragma unroll
      for (int j = 0; j < 2; ++j)
        acc[i][j] = __builtin_amdgcn_mfma_f32_16x16x32_bf16(af[i], bf[j], acc[i][j], 0, 0, 0);
  }
#pragma unroll
  for (int j = 0; j < 2; ++j) {
    const int gn = n0 + wn * 32 + j * 16 + col;
    const float bb = bias[gn];
#pragma unroll
    for (int i = 0; i < 4; ++i) {
      const int gmb = m0 + wm * 64 + i * 16 + kg * 4;
#pragma unroll
      for (int r = 0; r < 4; ++r) {
        const int gm = gmb + r;
        if (gm < M) {
          float v = acc[i][j][r] + bb;
          if (relu_f) v = fmaxf(v, 0.f);
          if (out32) ((float*)Cv)[(size_t)gm * ldc + c_off + gn] = v;
          else ((u16t*)Cv)[(size_t)gm * ldc + c_off + gn] = f2bf(v);
        }
      }
    }
  }
}

__global__ __launch_bounds__(256) void k_out(
    const float* __restrict__ h2, const float* __restrict__ Wo,
    const float* __restrict__ bo, float* __restrict__ out)
{
  __shared__ float Ws_[128];
  const int t = threadIdx.x;
  if (t < 128) Ws_[t] = Wo[t];
  __syncthreads();
  const int g = blockIdx.x * 32 + (t >> 3), l = t & 7;
  float acc = 0.f;
  if (g < NG) {
    const float* hr = h2 + (size_t)g * 128 + l * 16;
    const float* wr = Ws_ + l * 16;
#pragma unroll
    for (int j = 0; j < 16; ++j) acc = fmaf(hr[j], wr[j], acc);
  }
  acc += __shfl_down(acc, 4, 8);
  acc += __shfl_down(acc, 2, 8);
  acc += __shfl_down(acc, 1, 8);
  if (l == 0 && g < NG) out[g] = acc + bo[0];
}

extern "C" void kernel_launch(void* const* d_in, const int* in_sizes, int n_in,
                              void* d_out, int out_size, void* d_ws, size_t ws_size,
                              hipStream_t stream) {
  const float* x    = (const float*)d_in[0];
  const int*   ei   = (const int*)d_in[1];
  const int*   batch= (const int*)d_in[2];
  const float* xo   = (const float*)d_in[3];
  const float* g1W1 = (const float*)d_in[4];
  const float* g1b1 = (const float*)d_in[5];
  const float* g1W2 = (const float*)d_in[6];
  const float* g1b2 = (const float*)d_in[7];
  const float* gsW1 = (const float*)d_in[8];
  const float* gsb1 = (const float*)d_in[9];
  const float* gsW2 = (const float*)d_in[10];
  const float* gsb2 = (const float*)d_in[11];
  const float* bng  = (const float*)d_in[12];
  const float* bnb  = (const float*)d_in[13];
  const float* Wxd  = (const float*)d_in[14];
  const float* bxd  = (const float*)d_in[15];
  const float* c1W  = (const float*)d_in[16];
  const float* c1b  = (const float*)d_in[17];
  const float* c2W  = (const float*)d_in[18];
  const float* c2b  = (const float*)d_in[19];
  const float* c3W  = (const float*)d_in[20];
  const float* c3b  = (const float*)d_in[21];
  const float* Wxt  = (const float*)d_in[22];
  const float* bxt  = (const float*)d_in[23];
  const float* W1f  = (const float*)d_in[24];
  const float* b1f  = (const float*)d_in[25];
  const float* W2f  = (const float*)d_in[26];
  const float* b2f  = (const float*)d_in[27];
  const float* Wo   = (const float*)d_in[28];
  const float* bo   = (const float*)d_in[29];

  char* ws = (char*)d_ws;
  u16t*  U   = (u16t*)(ws + OFF_U);
  u16t*  YA  = (u16t*)(ws + OFF_YA);
  u16t*  YB  = (u16t*)(ws + OFF_U);
  float* ST  = (float*)(ws + OFF_ST);
  u32t*  RS  = (u32t*)(ws + OFF_RS);
  u32t*  CUR = (u32t*)(ws + OFF_CUR);
  u32t*  BS  = (u32t*)(ws + OFF_BSUM);
  int*   SSRC= (int*)(ws + OFF_SSRC);
  u16t*  WK  = (u16t*)(ws + OFF_WK);
  u16t*  W2K = WK;
  u16t*  W3K = WK + 16384;
  u16t*  WXT = WK + 16384 + 65536;
  u16t*  WF1 = WK + 16384 + 65536 + 376832;
  u16t*  WF2 = WK + 16384 + 65536 + 376832 + 262144;
  u16t*  XC  = (u16t*)(ws + OFF_XC);
  u16t*  T3  = (u16t*)(ws + OFF_T3);
  u16t*  H1  = (u16t*)(ws + OFF_H1);
  float* H2  = (float*)(ws + OFF_H2);
  float* OUT = (float*)d_out;

  const int NBLK = (NN + 1023) / 1024;

  hipMemsetAsync(ST, 0, 5 * 64 * sizeof(float), stream);
  hipMemsetAsync(CUR, 0, NN * sizeof(u32t), stream);

  k_prep<<<(128 * 2944 + 255) / 256, 256, 0, stream>>>(c2W, c3W, Wxt, W1f, W2f,
                                                        W2K, W3K, WXT, WF1, WF2);

  k_hist<<<(NE + 255) / 256, 256, 0, stream>>>(ei, CUR);
  k_scan1<<<NBLK, 256, 0, stream>>>(CUR, BS);
  k_scan2<<<1, 256, 0, stream>>>(BS, RS, NBLK);
  k_scan3<<<NBLK, 256, 0, stream>>>(CUR, RS, BS);
  k_scatter<<<(NE + 255) / 256, 256, 0, stream>>>(ei, CUR, SSRC);

  k_mlp1_first<<<2048, 256, 0, stream>>>(x, g1W1, U);
  k_agg0<<<NN / 32, 256, 0, stream>>>(U, RS, SSRC, g1b1, g1W2, g1b2, YA, ST + 0);
  const u16t* yin = YA;
  u16t* yout = YB;
  for (int lyr = 1; lyr <= 4; ++lyr) {
    k_layer<<<NN / 32, 256, 0, stream>>>(yin, RS, SSRC, ST + (lyr - 1) * 64,
                                         bng + (lyr - 1) * 32, bnb + (lyr - 1) * 32,
                                         gsW1 + (lyr - 1) * 1024, gsb1 + (lyr - 1) * 32,
                                         gsW2 + (lyr - 1) * 1024, gsb2 + (lyr - 1) * 32,
                                         yout, ST + lyr * 64);
    const u16t* tmp = yin;
    yin = yout;
    yout = (u16t*)tmp;
  }
  k_pool_xd<<<NG, 64, 0, stream>>>(yin, batch, ST, bng, bnb, Wxd, bxd, XC);

  k_cnn<<<NG, 256, 0, stream>>>(xo, c1W, c1b, W2K, c2b, W3K, c3b, T3);

  {
    dim3 grid((NG + 127) / 128, 2);
    k_mgemm<<<grid, 256, 0, stream>>>(T3, 2944, WXT, bxt, XC, 256, 128, NG, 2944, 0, 0);
  }
  {
    dim3 grid((NG + 127) / 128, 16);
    k_mgemm<<<grid, 256, 0, stream>>>(XC, 256, WF1, b1f, H1, 1024, 0, NG, 256, 1, 0);
  }
  {
    dim3 grid((NG + 127) / 128, 2);
    k_mgemm<<<grid, 256, 0, stream>>>(H1, 1024, WF2, b2f, H2, 128, 0, NG, 1024, 1, 1);
  }
  k_out<<<(NG + 31) / 32, 256, 0, stream>>>(H2, Wo, bo, OUT);
}

// Round 9
// 3467.550 us; speedup vs baseline: 5.0284x; 1.1596x over previous
//
#include <hip/hip_runtime.h>

#define NN 1000000
#define NE 4000000
#define NG 25000
#define BN_EPS 1e-5f

typedef unsigned short u16t;
typedef unsigned int u32t;
typedef __attribute__((ext_vector_type(8))) short bf16x8;
typedef __attribute__((ext_vector_type(4))) float f32x4;

__device__ inline u16t f2bf(float f) {
  u32t u = __float_as_uint(f);
  u32t r = (u + 0x7FFFu + ((u >> 16) & 1u)) >> 16;
  return (u16t)r;
}
__device__ inline float bf2f(u16t h) { return __uint_as_float((u32t)h << 16); }
__device__ inline u16t f2h(float f) {
  _Float16 h = (_Float16)f;
  return *(u16t*)&h;
}
__device__ inline float h2f(u16t v) {
  _Float16 h = *(_Float16*)&v;
  return (float)h;
}
__device__ inline void add8h(float* a, uint4 v) {
  union { uint4 u; _Float16 h[8]; } cv;
  cv.u = v;
#pragma unroll
  for (int j = 0; j < 8; ++j) a[j] += (float)cv.h[j];
}

// ---- workspace layout (bytes) ----
static const size_t OFF_U    = 0;           // fp16 64MB; also YB
static const size_t OFF_YA   = 130000000;
static const size_t OFF_ST   = 258000000;
static const size_t OFF_RS   = 259000000;
static const size_t OFF_CUR  = 263200000;
static const size_t OFF_BSUM = 267300000;
static const size_t OFF_SSRC = 268000000;
static const size_t OFF_WK   = 285000000;
static const size_t OFF_XC   = 287000000;
static const size_t OFF_T3   = 0;
static const size_t OFF_H1   = 150000000;
static const size_t OFF_H2   = 210000000;

// ---------------- CSR build ----------------
__global__ __launch_bounds__(256) void k_hist(const int* __restrict__ ei, u32t* __restrict__ cnt) {
  const int i = blockIdx.x * 256 + threadIdx.x;
  if (i < NE) atomicAdd(&cnt[ei[NE + i]], 1u);
}

__global__ __launch_bounds__(256) void k_scan1(const u32t* __restrict__ deg, u32t* __restrict__ bsum) {
  __shared__ u32t red[4];
  const int b = blockIdx.x, t = threadIdx.x;
  u32t s = 0;
#pragma unroll
  for (int j = 0; j < 4; ++j) {
    const int i = b * 1024 + j * 256 + t;
    if (i < NN) s += deg[i];
  }
#pragma unroll
  for (int off = 32; off > 0; off >>= 1) s += __shfl_down(s, off);
  if ((t & 63) == 0) red[t >> 6] = s;
  __syncthreads();
  if (t == 0) bsum[b] = red[0] + red[1] + red[2] + red[3];
}

__global__ __launch_bounds__(256) void k_scan2(u32t* __restrict__ bsum, u32t* __restrict__ rs, int nblk) {
  __shared__ u32t sh[256];
  const int t = threadIdx.x;
  u32t v[4];
#pragma unroll
  for (int j = 0; j < 4; ++j) {
    const int i = t * 4 + j;
    v[j] = (i < nblk) ? bsum[i] : 0u;
  }
  const u32t tot = v[0] + v[1] + v[2] + v[3];
  sh[t] = tot;
  __syncthreads();
  for (int off = 1; off < 256; off <<= 1) {
    u32t add = (t >= off) ? sh[t - off] : 0u;
    __syncthreads();
    sh[t] += add;
    __syncthreads();
  }
  const u32t tb = (t == 0) ? 0u : sh[t - 1];
  u32t run = tb;
#pragma unroll
  for (int j = 0; j < 4; ++j) {
    const int i = t * 4 + j;
    if (i < nblk) bsum[i] = run;
    run += v[j];
  }
  if (t == 0) rs[NN] = NE;
}

__global__ __launch_bounds__(256) void k_scan3(u32t* __restrict__ cur, u32t* __restrict__ rs,
                                               const u32t* __restrict__ bsum) {
  __shared__ u32t sh[256];
  const int b = blockIdx.x, t = threadIdx.x;
  const int i0 = b * 1024 + t * 4;
  u32t v[4];
#pragma unroll
  for (int j = 0; j < 4; ++j) v[j] = (i0 + j < NN) ? cur[i0 + j] : 0u;
  sh[t] = v[0] + v[1] + v[2] + v[3];
  __syncthreads();
  for (int off = 1; off < 256; off <<= 1) {
    u32t add = (t >= off) ? sh[t - off] : 0u;
    __syncthreads();
    sh[t] += add;
    __syncthreads();
  }
  u32t run = bsum[b] + ((t == 0) ? 0u : sh[t - 1]);
#pragma unroll
  for (int j = 0; j < 4; ++j) {
    const int i = i0 + j;
    if (i < NN) { rs[i] = run; cur[i] = run; }
    run += v[j];
  }
}

__global__ __launch_bounds__(256) void k_scatter(const int* __restrict__ ei,
                                                 u32t* __restrict__ cur, int* __restrict__ ssrc) {
  const int i = blockIdx.x * 256 + threadIdx.x;
  if (i < NE) {
    const int src = ei[i], dst = ei[NE + i];
    const u32t pos = atomicAdd(&cur[dst], 1u);
    ssrc[pos] = src;
  }
}

// ---------------- GNN kernels ----------------

__global__ __launch_bounds__(256) void k_mlp1_first(
    const float* __restrict__ x, const float* __restrict__ W1, u16t* __restrict__ u)
{
  __shared__ float Wt[78 * 33];
  __shared__ float xt_[8 * 79];
  const int t = threadIdx.x;
  for (int id = t; id < 78 * 32; id += 256) {
    int k = id >> 5, c = id & 31;
    Wt[k * 33 + c] = W1[id];
  }
  const int c = t & 31, nl = t >> 5;
  const int ntiles = NN / 8;
  for (int tile = blockIdx.x; tile < ntiles; tile += gridDim.x) {
    const int n0 = tile * 8;
    __syncthreads();
    for (int id = t; id < 8 * 78; id += 256) {
      int r = id / 78, k = id - r * 78;
      xt_[r * 79 + k] = x[(size_t)n0 * 78 + id];
    }
    __syncthreads();
    float acc = 0.f;
    const float* xr = xt_ + nl * 79;
#pragma unroll
    for (int k = 0; k < 78; ++k) acc = fmaf(xr[k], Wt[k * 33 + c], acc);
    u[(size_t)(n0 + nl) * 32 + c] = f2h(acc);
  }
}

// layer0 part B: 64 nodes/block, 4 lanes x 16B per node row
__global__ __launch_bounds__(256) void k_agg0(
    const u16t* __restrict__ u, const u32t* __restrict__ rs, const int* __restrict__ ssrc,
    const float* __restrict__ b1, const float* __restrict__ W2, const float* __restrict__ b2,
    u16t* __restrict__ yout, float* __restrict__ stats_out)
{
  __shared__ float W2s[32 * 33];
  __shared__ float A1[64 * 33];
  __shared__ float red[256];
  const int t = threadIdx.x;
  for (int id = t; id < 1024; id += 256) {
    int k = id >> 5, c = id & 31;
    W2s[k * 33 + c] = W2[id];
  }
  const int nl = t >> 2, c0 = (t & 3) * 8;
  const int n = blockIdx.x * 64 + nl;
  float a[8] = {};
  add8h(a, *(const uint4*)(u + (size_t)n * 32 + c0));
  const u32t e0 = rs[n], e1 = rs[n + 1];
  u32t e = e0;
  for (; e + 4 <= e1; e += 4) {
    const int s0v = ssrc[e], s1v = ssrc[e + 1], s2v = ssrc[e + 2], s3v = ssrc[e + 3];
    const uint4 v0 = *(const uint4*)(u + (size_t)s0v * 32 + c0);
    const uint4 v1 = *(const uint4*)(u + (size_t)s1v * 32 + c0);
    const uint4 v2 = *(const uint4*)(u + (size_t)s2v * 32 + c0);
    const uint4 v3 = *(const uint4*)(u + (size_t)s3v * 32 + c0);
    add8h(a, v0); add8h(a, v1); add8h(a, v2); add8h(a, v3);
  }
  for (; e < e1; ++e)
    add8h(a, *(const uint4*)(u + (size_t)ssrc[e] * 32 + c0));
  float* hp = A1 + nl * 33 + c0;
#pragma unroll
  for (int j = 0; j < 8; ++j) hp[j] = fmaxf(a[j] + b1[c0 + j], 0.f);
  __syncthreads();
  const int c = t & 31;
  const float b2v = b2[c];
  float rsum = 0.f, rq = 0.f;
#pragma unroll
  for (int rep = 0; rep < 8; ++rep) {
    const int row = (t >> 5) + rep * 8;
    const float* hr = A1 + row * 33;
    float acc = b2v;
#pragma unroll
    for (int k = 0; k < 32; ++k) acc = fmaf(hr[k], W2s[k * 33 + c], acc);
    acc = fmaxf(acc, 0.f);
    yout[(size_t)(blockIdx.x * 64 + row) * 32 + c] = f2h(acc);
    rsum += acc;
    rq += acc * acc;
  }
  rsum += __shfl_down(rsum, 32);
  rq += __shfl_down(rq, 32);
  __syncthreads();
  const int wv_ = t >> 6, lane = t & 63;
  if (lane < 32) {
    red[wv_ * 32 + lane] = rsum;
    red[128 + wv_ * 32 + lane] = rq;
  }
  __syncthreads();
  if (t < 32) {
    float aa = red[t] + red[32 + t] + red[64 + t] + red[96 + t];
    float bb = red[128 + t] + red[160 + t] + red[192 + t] + red[224 + t];
    unsafeAtomicAdd(&stats_out[t], aa);
    unsafeAtomicAdd(&stats_out[32 + t], bb);
  }
}

// layers 1..4: 64 nodes/block, 4 lanes x 16B per node row
__global__ __launch_bounds__(256) void k_layer(
    const u16t* __restrict__ yin, const u32t* __restrict__ rs, const int* __restrict__ ssrc,
    const float* __restrict__ stats, const float* __restrict__ gamma, const float* __restrict__ beta,
    const float* __restrict__ W1, const float* __restrict__ b1,
    const float* __restrict__ W2, const float* __restrict__ b2,
    u16t* __restrict__ yout, float* __restrict__ stats_out)
{
  __shared__ float W1s[32 * 33];
  __shared__ float W2s[32 * 33];
  __shared__ float A1[64 * 33];
  __shared__ float A2[64 * 33];
  __shared__ float red[256];
  const int t = threadIdx.x;
  for (int id = t; id < 1024; id += 256) {
    int k = id >> 5, c = id & 31;
    W1s[k * 33 + c] = W1[id];
    W2s[k * 33 + c] = W2[id];
  }
  const int nl = t >> 2, c0 = (t & 3) * 8;
  const int n = blockIdx.x * 64 + nl;
  float sc[8], sh[8];
#pragma unroll
  for (int j = 0; j < 8; ++j) {
    const int c = c0 + j;
    const float mu = stats[c] * (1.f / NN);
    float var = fmaxf(stats[32 + c] * (1.f / NN) - mu * mu, 0.f);
    sc[j] = gamma[c] * rsqrtf(var + BN_EPS);
    sh[j] = beta[c] - mu * sc[j];
  }
  float a[8] = {};
  add8h(a, *(const uint4*)(yin + (size_t)n * 32 + c0));
  const u32t e0 = rs[n], e1 = rs[n + 1];
  u32t e = e0;
  for (; e + 4 <= e1; e += 4) {
    const int s0v = ssrc[e], s1v = ssrc[e + 1], s2v = ssrc[e + 2], s3v = ssrc[e + 3];
    const uint4 v0 = *(const uint4*)(yin + (size_t)s0v * 32 + c0);
    const uint4 v1 = *(const uint4*)(yin + (size_t)s1v * 32 + c0);
    const uint4 v2 = *(const uint4*)(yin + (size_t)s2v * 32 + c0);
    const uint4 v3 = *(const uint4*)(yin + (size_t)s3v * 32 + c0);
    add8h(a, v0); add8h(a, v1); add8h(a, v2); add8h(a, v3);
  }
  for (; e < e1; ++e)
    add8h(a, *(const uint4*)(yin + (size_t)ssrc[e] * 32 + c0));
  const float cnt = (float)(e1 - e0 + 1u);
  float* hp = A1 + nl * 33 + c0;
#pragma unroll
  for (int j = 0; j < 8; ++j) hp[j] = sc[j] * a[j] + cnt * sh[j];
  __syncthreads();
  const int c = t & 31;
  const float b1v = b1[c];
#pragma unroll
  for (int rep = 0; rep < 8; ++rep) {
    const int row = (t >> 5) + rep * 8;
    const float* hr = A1 + row * 33;
    float acc = b1v;
#pragma unroll
    for (int k = 0; k < 32; ++k) acc = fmaf(hr[k], W1s[k * 33 + c], acc);
    A2[row * 33 + c] = fmaxf(acc, 0.f);
  }
  __syncthreads();
  const float b2v = b2[c];
  float rsum = 0.f, rq = 0.f;
#pragma unroll
  for (int rep = 0; rep < 8; ++rep) {
    const int row = (t >> 5) + rep * 8;
    const float* hr = A2 + row * 33;
    float acc = b2v;
#pragma unroll
    for (int k = 0; k < 32; ++k) acc = fmaf(hr[k], W2s[k * 33 + c], acc);
    acc = fmaxf(acc, 0.f);
    yout[(size_t)(blockIdx.x * 64 + row) * 32 + c] = f2h(acc);
    rsum += acc;
    rq += acc * acc;
  }
  rsum += __shfl_down(rsum, 32);
  rq += __shfl_down(rq, 32);
  __syncthreads();
  const int wv_ = t >> 6, lane = t & 63;
  if (lane < 32) {
    red[wv_ * 32 + lane] = rsum;
    red[128 + wv_ * 32 + lane] = rq;
  }
  __syncthreads();
  if (t < 32) {
    float aa = red[t] + red[32 + t] + red[64 + t] + red[96 + t];
    float bb = red[128 + t] + red[160 + t] + red[192 + t] + red[224 + t];
    unsafeAtomicAdd(&stats_out[t], aa);
    unsafeAtomicAdd(&stats_out[32 + t], bb);
  }
}

__global__ __launch_bounds__(64) void k_pool_xd(
    const u16t* __restrict__ y, const int* __restrict__ batch,
    const float* __restrict__ stats, const float* __restrict__ gamma,
    const float* __restrict__ beta, const float* __restrict__ Wxd,
    const float* __restrict__ bxd, u16t* __restrict__ xc)
{
  const int g = blockIdx.x, t = threadIdx.x;
  int lo = 0, n = NN;
  while (n > 0) {
    int h = n >> 1, m = lo + h;
    if (batch[m] < g) { lo = m + 1; n -= h + 1; } else n = h;
  }
  int hi = lo;
  n = NN - lo;
  while (n > 0) {
    int h = n >> 1, m = hi + h;
    if (batch[m] < g + 1) { hi = m + 1; n -= h + 1; } else n = h;
  }
  const int c = t & 31;
  const float mu = stats[4 * 64 + c] * (1.f / NN);
  float var = fmaxf(stats[4 * 64 + 32 + c] * (1.f / NN) - mu * mu, 0.f);
  const float sc = gamma[4 * 32 + c] * rsqrtf(var + BN_EPS);
  const float sh = beta[4 * 32 + c] - mu * sc;
  float acc = 0.f;
  for (int i = lo + (t >> 5); i < hi; i += 2) acc += h2f(y[(size_t)i * 32 + c]);
  acc += __shfl_down(acc, 32);
  __shared__ float pl[32];
  if (t < 32) pl[t] = acc * sc + (float)(hi - lo) * sh;
  __syncthreads();
#pragma unroll
  for (int rep = 0; rep < 2; ++rep) {
    const int o = t + rep * 64;
    float a = bxd[o];
#pragma unroll
    for (int cc = 0; cc < 32; ++cc) a = fmaf(pl[cc], Wxd[cc * 128 + o], a);
    xc[(size_t)g * 256 + o] = f2bf(fmaxf(a, 0.f));
  }
}

// ---------------- weight prep ----------------
__global__ __launch_bounds__(256) void k_prep(
    const float* __restrict__ w2, const float* __restrict__ w3,
    const float* __restrict__ wxt, const float* __restrict__ wf1, const float* __restrict__ wf2,
    u16t* __restrict__ W2k, u16t* __restrict__ W3k,
    u16t* __restrict__ WXT, u16t* __restrict__ WF1, u16t* __restrict__ WF2)
{
  const int i = blockIdx.x * 256 + threadIdx.x;
  if (i < 64 * 256) {
    int c2 = i >> 8, kk = i & 255, tt = kk >> 5, ci = kk & 31;
    W2k[i] = f2bf(w2[c2 * 256 + ci * 8 + tt]);
  }
  if (i < 128 * 512) {
    int c3 = i >> 9, kk = i & 511, tt = kk >> 6, ci = kk & 63;
    W3k[i] = f2bf(w3[c3 * 512 + ci * 8 + tt]);
  }
  if (i < 128 * 2944) {
    int nn = i / 2944, kk = i - nn * 2944;
    WXT[i] = f2bf(wxt[kk * 128 + nn]);
  }
  if (i < 1024 * 256) {
    int nn = i >> 8, kk = i & 255;
    WF1[i] = f2bf(wf1[kk * 1024 + nn]);
  }
  if (i < 128 * 1024) {
    int nn = i >> 10, kk = i & 1023;
    WF2[i] = f2bf(wf2[kk * 128 + nn]);
  }
}

// ---------------- fused per-graph CNN ----------------
// LDS (30720 B); __launch_bounds__(256,4): 128-VGPR budget so conv2/conv3
// operand arrays stay in registers (5 waves/EU capped at ~96 -> 650MB scratch spill)
__global__ __launch_bounds__(256, 4) void k_cnn(
    const float* __restrict__ xo,
    const float* __restrict__ w1, const float* __restrict__ b1,
    const u16t* __restrict__ W2k, const float* __restrict__ b2,
    const u16t* __restrict__ W3k, const float* __restrict__ b3,
    u16t* __restrict__ t3)
{
  __shared__ __align__(16) char smem[30720];
  float* xot = (float*)(smem);
  float* w1s = (float*)(smem + 3072);
  float* b2s = (float*)(smem + 4096);
  float* b3s = (float*)(smem + 4352);
  short* T1T = (short*)(smem + 4864);
  char*  T2B = smem + 20736;
  u16t*  stg = (u16t*)(smem + 4864);

  const int g = blockIdx.x, t = threadIdx.x;
  const int w = t >> 6, l = t & 63, col = l & 15, kg = l >> 4;

  for (int i = t; i < 768; i += 256) xot[i] = (i < 735) ? xo[(size_t)g * 735 + i] : 0.f;
  w1s[t] = w1[t];
  if (t < 64) b2s[t] = b2[t];
  if (t < 128) b3s[t] = b3[t];
  if (t < 192) {
    int r = 242 + (t >> 5), c = t & 31;
    T1T[r * 32 + c] = 0;
  }
  __syncthreads();

  // conv1 fp32 + relu + pool3 -> T1T [pos][32ch] swizzled (slot ^= pos&3)
  {
    const int c = t >> 3, qg = t & 7;
    float wv[8];
#pragma unroll
    for (int j = 0; j < 8; ++j) wv[j] = w1s[c * 8 + j];
    const float bias = b1[c];
    const int q0 = qg * 31, qe = (q0 + 31 < 242) ? q0 + 31 : 242;
#pragma unroll 1
    for (int qc = q0; qc < qe; qc += 10) {
      const int cnt = (qe - qc < 10) ? qe - qc : 10;
      float xv[37];
#pragma unroll
      for (int j = 0; j < 37; ++j) xv[j] = xot[3 * qc + j];
#pragma unroll
      for (int j0 = 0; j0 < 10; ++j0) {
        if (j0 < cnt) {
          float a0 = bias, a1 = bias, a2 = bias;
#pragma unroll
          for (int tt = 0; tt < 8; ++tt) {
            a0 = fmaf(wv[tt], xv[3 * j0 + tt], a0);
            a1 = fmaf(wv[tt], xv[3 * j0 + 1 + tt], a1);
            a2 = fmaf(wv[tt], xv[3 * j0 + 2 + tt], a2);
          }
          float m = fmaxf(fmaxf(a0, a1), fmaxf(a2, 0.f));
          const int pos = qc + j0;
          T1T[pos * 32 + (c ^ ((pos & 3) << 3))] = (short)f2bf(m);
        }
      }
    }
  }
  __syncthreads();

  // conv2 (32->64,k8): wave w owns out-ch [w*16,w*16+16). pool3 in-register.
  {
    bf16x8 am[8];
#pragma unroll
    for (int kk = 0; kk < 8; ++kk)
      am[kk] = *(const bf16x8*)(W2k + (w * 16 + col) * 256 + kk * 32 + kg * 8);
#pragma unroll 1
    for (int qt = 0; qt < 5; ++qt) {
      const int rbase = qt * 48 + col * 3;
      bf16x8 rv[10];
#pragma unroll
      for (int s = 0; s < 10; ++s) {
        const int row = rbase + s;
        rv[s] = *(const bf16x8*)(T1T + row * 32 + ((kg ^ (row & 3)) << 3));
      }
      f32x4 a0 = {0.f, 0.f, 0.f, 0.f}, a1 = a0, a2 = a0;
#pragma unroll
      for (int kk = 0; kk < 8; ++kk) {
        a0 = __builtin_amdgcn_mfma_f32_16x16x32_bf16(am[kk], rv[kk], a0, 0, 0, 0);
        a1 = __builtin_amdgcn_mfma_f32_16x16x32_bf16(am[kk], rv[kk + 1], a1, 0, 0, 0);
        a2 = __builtin_amdgcn_mfma_f32_16x16x32_bf16(am[kk], rv[kk + 2], a2, 0, 0, 0);
      }
      const int q = qt * 16 + col;
      if (q < 78) {
        union { u16t u[4]; uint2 v; } pk;
#pragma unroll
        for (int r = 0; r < 4; ++r) {
          const float bb = b2s[w * 16 + kg * 4 + r];
          float m = fmaxf(fmaxf(a0[r], a1[r]), a2[r]);
          pk.u[r] = f2bf(fmaxf(m + bb, 0.f));
        }
        const int boff = (q * 128 + (w * 16 + kg * 4) * 2) ^ ((q & 7) << 4);
        *(uint2*)(T2B + boff) = pk.v;
      }
    }
  }
  __syncthreads();

  // conv3 (64->128,k8): wave w owns out-ch blocks {2w,2w+1}. pool3 in-register.
  {
#pragma unroll 1
    for (int mi = 0; mi < 2; ++mi) {
      const int m3 = w * 2 + mi;
      f32x4 acc[2][3];
#pragma unroll
      for (int qt = 0; qt < 2; ++qt)
#pragma unroll
        for (int r = 0; r < 3; ++r) acc[qt][r] = (f32x4){0.f, 0.f, 0.f, 0.f};
#pragma unroll 1
      for (int kh = 0; kh < 2; ++kh) {
        bf16x8 amh[8];
#pragma unroll
        for (int tt = 0; tt < 8; ++tt)
          amh[tt] = *(const bf16x8*)(W3k + (m3 * 16 + col) * 512 + (tt * 2 + kh) * 32 + kg * 8);
#pragma unroll
        for (int qt = 0; qt < 2; ++qt) {
          const int rbase = qt * 48 + col * 3;
          bf16x8 rv[10];
#pragma unroll
          for (int s = 0; s < 10; ++s) {
            int row = rbase + s;
            row = (row < 78) ? row : 77;
            const int boff = (row * 128 + kh * 64 + kg * 16) ^ ((row & 7) << 4);
            rv[s] = *(const bf16x8*)(T2B + boff);
          }
#pragma unroll
          for (int tt = 0; tt < 8; ++tt) {
            acc[qt][0] = __builtin_amdgcn_mfma_f32_16x16x32_bf16(amh[tt], rv[tt], acc[qt][0], 0, 0, 0);
            acc[qt][1] = __builtin_amdgcn_mfma_f32_16x16x32_bf16(amh[tt], rv[tt + 1], acc[qt][1], 0, 0, 0);
            acc[qt][2] = __builtin_amdgcn_mfma_f32_16x16x32_bf16(amh[tt], rv[tt + 2], acc[qt][2], 0, 0, 0);
          }
        }
      }
#pragma unroll
      for (int qt = 0; qt < 2; ++qt) {
        const int q = qt * 16 + col;
        if (q < 23) {
#pragma unroll
          for (int r = 0; r < 4; ++r) {
            const int c = m3 * 16 + kg * 4 + r;
            float m = fmaxf(fmaxf(acc[qt][0][r], acc[qt][1][r]), acc[qt][2][r]);
            stg[c * 23 + q] = f2bf(fmaxf(m + b3s[c], 0.f));
          }
        }
      }
    }
  }
  __syncthreads();

  {
    const uint4* s4 = (const uint4*)stg;
    uint4* d4 = (uint4*)(t3 + (size_t)g * 2944);
    for (int id = t; id < 368; id += 256) d4[id] = s4[id];
  }
}

// ---------------- bf16 MFMA GEMM ----------------
__global__ __launch_bounds__(256) void k_mgemm(
    const u16t* __restrict__ A, int lda,
    const u16t* __restrict__ WT, const float* __restrict__ bias,
    void* __restrict__ Cv, int ldc, int c_off, int M, int Kd,
    int relu_f, int out32)
{
  __shared__ __align__(16) u16t As[128 * 4 * 8];
  __shared__ __align__(16) u16t Ws2[64 * 4 * 8];
  const int t = threadIdx.x;
  const int w = t >> 6, l = t & 63, col = l & 15, kg = l >> 4;
  const int wm = w & 1, wn = w >> 1;
  const int m0 = blockIdx.x * 128, n0 = blockIdx.y * 64;
  f32x4 acc[4][2];
#pragma unroll
  for (int i = 0; i < 4; ++i)
#pragma unroll
    for (int j = 0; j < 2; ++j) acc[i][j] = (f32x4){0.f, 0.f, 0.f, 0.f};
  const int ar = t >> 1, ac = (t & 1) * 2;
  const int wr = t >> 2, wc = t & 3;
  const bool aok = (m0 + ar) < M;
  const u16t* Ap = A + (size_t)(m0 + ar) * lda;
  const u16t* Wp = WT + (size_t)(n0 + wr) * Kd;
  for (int k0 = 0; k0 < Kd; k0 += 32) {
    bf16x8 av0 = {0, 0, 0, 0, 0, 0, 0, 0}, av1 = {0, 0, 0, 0, 0, 0, 0, 0};
    if (aok) {
      av0 = *(const bf16x8*)(Ap + k0 + ac * 8);
      av1 = *(const bf16x8*)(Ap + k0 + (ac + 1) * 8);
    }
    const bf16x8 wv = *(const bf16x8*)(Wp + k0 + wc * 8);
    __syncthreads();
    *(bf16x8*)(As + (ar * 4 + (ac ^ (ar & 3))) * 8) = av0;
    *(bf16x8*)(As + (ar * 4 + ((ac + 1) ^ (ar & 3))) * 8) = av1;
    *(bf16x8*)(Ws2 + (wr * 4 + (wc ^ (wr & 3))) * 8) = wv;
    __syncthreads();
    bf16x8 af[4], bf[2];
#pragma unroll
    for (int i = 0; i < 4; ++i) {
      const int R = wm * 64 + i * 16 + col;
      af[i] = *(const bf16x8*)(As + (R * 4 + (kg ^ (R & 3))) * 8);
    }
#pragma unroll
    for (int j = 0; j < 2; ++j) {
      const int R = wn * 32 + j * 16 + col;
      bf[j] = *(const bf16x8*)(Ws2 + (R * 4 + (kg ^ (R & 3))) * 8);
    }
#pragma unroll
    for (int i = 0; i < 4; ++i)
#pragma unroll
      for (int j = 0; j < 2; ++j)
        acc[i][j] = __builtin_amdgcn_mfma_f32_16x16x32_bf16(af[i], bf[j], acc[i][j], 0, 0, 0);
  }
#pragma unroll
  for (int j = 0; j < 2; ++j) {
    const int gn = n0 + wn * 32 + j * 16 + col;
    const float bb = bias[gn];
#pragma unroll
    for (int i = 0; i < 4; ++i) {
      const int gmb = m0 + wm * 64 + i * 16 + kg * 4;
#pragma unroll
      for (int r = 0; r < 4; ++r) {
        const int gm = gmb + r;
        if (gm < M) {
          float v = acc[i][j][r] + bb;
          if (relu_f) v = fmaxf(v, 0.f);
          if (out32) ((float*)Cv)[(size_t)gm * ldc + c_off + gn] = v;
          else ((u16t*)Cv)[(size_t)gm * ldc + c_off + gn] = f2bf(v);
        }
      }
    }
  }
}

__global__ __launch_bounds__(256) void k_out(
    const float* __restrict__ h2, const float* __restrict__ Wo,
    const float* __restrict__ bo, float* __restrict__ out)
{
  __shared__ float Ws_[128];
  const int t = threadIdx.x;
  if (t < 128) Ws_[t] = Wo[t];
  __syncthreads();
  const int g = blockIdx.x * 32 + (t >> 3), l = t & 7;
  float acc = 0.f;
  if (g < NG) {
    const float* hr = h2 + (size_t)g * 128 + l * 16;
    const float* wr = Ws_ + l * 16;
#pragma unroll
    for (int j = 0; j < 16; ++j) acc = fmaf(hr[j], wr[j], acc);
  }
  acc += __shfl_down(acc, 4, 8);
  acc += __shfl_down(acc, 2, 8);
  acc += __shfl_down(acc, 1, 8);
  if (l == 0 && g < NG) out[g] = acc + bo[0];
}

extern "C" void kernel_launch(void* const* d_in, const int* in_sizes, int n_in,
                              void* d_out, int out_size, void* d_ws, size_t ws_size,
                              hipStream_t stream) {
  const float* x    = (const float*)d_in[0];
  const int*   ei   = (const int*)d_in[1];
  const int*   batch= (const int*)d_in[2];
  const float* xo   = (const float*)d_in[3];
  const float* g1W1 = (const float*)d_in[4];
  const float* g1b1 = (const float*)d_in[5];
  const float* g1W2 = (const float*)d_in[6];
  const float* g1b2 = (const float*)d_in[7];
  const float* gsW1 = (const float*)d_in[8];
  const float* gsb1 = (const float*)d_in[9];
  const float* gsW2 = (const float*)d_in[10];
  const float* gsb2 = (const float*)d_in[11];
  const float* bng  = (const float*)d_in[12];
  const float* bnb  = (const float*)d_in[13];
  const float* Wxd  = (const float*)d_in[14];
  const float* bxd  = (const float*)d_in[15];
  const float* c1W  = (const float*)d_in[16];
  const float* c1b  = (const float*)d_in[17];
  const float* c2W  = (const float*)d_in[18];
  const float* c2b  = (const float*)d_in[19];
  const float* c3W  = (const float*)d_in[20];
  const float* c3b  = (const float*)d_in[21];
  const float* Wxt  = (const float*)d_in[22];
  const float* bxt  = (const float*)d_in[23];
  const float* W1f  = (const float*)d_in[24];
  const float* b1f  = (const float*)d_in[25];
  const float* W2f  = (const float*)d_in[26];
  const float* b2f  = (const float*)d_in[27];
  const float* Wo   = (const float*)d_in[28];
  const float* bo   = (const float*)d_in[29];

  char* ws = (char*)d_ws;
  u16t*  U   = (u16t*)(ws + OFF_U);
  u16t*  YA  = (u16t*)(ws + OFF_YA);
  u16t*  YB  = (u16t*)(ws + OFF_U);
  float* ST  = (float*)(ws + OFF_ST);
  u32t*  RS  = (u32t*)(ws + OFF_RS);
  u32t*  CUR = (u32t*)(ws + OFF_CUR);
  u32t*  BS  = (u32t*)(ws + OFF_BSUM);
  int*   SSRC= (int*)(ws + OFF_SSRC);
  u16t*  WK  = (u16t*)(ws + OFF_WK);
  u16t*  W2K = WK;
  u16t*  W3K = WK + 16384;
  u16t*  WXT = WK + 16384 + 65536;
  u16t*  WF1 = WK + 16384 + 65536 + 376832;
  u16t*  WF2 = WK + 16384 + 65536 + 376832 + 262144;
  u16t*  XC  = (u16t*)(ws + OFF_XC);
  u16t*  T3  = (u16t*)(ws + OFF_T3);
  u16t*  H1  = (u16t*)(ws + OFF_H1);
  float* H2  = (float*)(ws + OFF_H2);
  float* OUT = (float*)d_out;

  const int NBLK = (NN + 1023) / 1024;

  hipMemsetAsync(ST, 0, 5 * 64 * sizeof(float), stream);
  hipMemsetAsync(CUR, 0, NN * sizeof(u32t), stream);

  k_prep<<<(128 * 2944 + 255) / 256, 256, 0, stream>>>(c2W, c3W, Wxt, W1f, W2f,
                                                        W2K, W3K, WXT, WF1, WF2);

  k_hist<<<(NE + 255) / 256, 256, 0, stream>>>(ei, CUR);
  k_scan1<<<NBLK, 256, 0, stream>>>(CUR, BS);
  k_scan2<<<1, 256, 0, stream>>>(BS, RS, NBLK);
  k_scan3<<<NBLK, 256, 0, stream>>>(CUR, RS, BS);
  k_scatter<<<(NE + 255) / 256, 256, 0, stream>>>(ei, CUR, SSRC);

  k_mlp1_first<<<2048, 256, 0, stream>>>(x, g1W1, U);
  k_agg0<<<NN / 64, 256, 0, stream>>>(U, RS, SSRC, g1b1, g1W2, g1b2, YA, ST + 0);
  const u16t* yin = YA;
  u16t* yout = YB;
  for (int lyr = 1; lyr <= 4; ++lyr) {
    k_layer<<<NN / 64, 256, 0, stream>>>(yin, RS, SSRC, ST + (lyr - 1) * 64,
                                         bng + (lyr - 1) * 32, bnb + (lyr - 1) * 32,
                                         gsW1 + (lyr - 1) * 1024, gsb1 + (lyr - 1) * 32,
                                         gsW2 + (lyr - 1) * 1024, gsb2 + (lyr - 1) * 32,
                                         yout, ST + lyr * 64);
    const u16t* tmp = yin;
    yin = yout;
    yout = (u16t*)tmp;
  }
  k_pool_xd<<<NG, 64, 0, stream>>>(yin, batch, ST, bng, bnb, Wxd, bxd, XC);

  k_cnn<<<NG, 256, 0, stream>>>(xo, c1W, c1b, W2K, c2b, W3K, c3b, T3);

  {
    dim3 grid((NG + 127) / 128, 2);
    k_mgemm<<<grid, 256, 0, stream>>>(T3, 2944, WXT, bxt, XC, 256, 128, NG, 2944, 0, 0);
  }
  {
    dim3 grid((NG + 127) / 128, 16);
    k_mgemm<<<grid, 256, 0, stream>>>(XC, 256, WF1, b1f, H1, 1024, 0, NG, 256, 1, 0);
  }
  {
    dim3 grid((NG + 127) / 128, 2);
    k_mgemm<<<grid, 256, 0, stream>>>(H1, 1024, WF2, b2f, H2, 128, 0, NG, 1024, 1, 1);
  }
  k_out<<<(NG + 31) / 32, 256, 0, stream>>>(H2, Wo, bo, OUT);
}

// Round 10
// 3424.908 us; speedup vs baseline: 5.0910x; 1.0125x over previous
//
#include <hip/hip_runtime.h>

#define NN 1000000
#define NE 4000000
#define NG 25000
#define BN_EPS 1e-5f

typedef unsigned short u16t;
typedef unsigned int u32t;
typedef __attribute__((ext_vector_type(8))) short bf16x8;
typedef __attribute__((ext_vector_type(4))) float f32x4;

__device__ inline u16t f2bf(float f) {
  u32t u = __float_as_uint(f);
  u32t r = (u + 0x7FFFu + ((u >> 16) & 1u)) >> 16;
  return (u16t)r;
}
__device__ inline float bf2f(u16t h) { return __uint_as_float((u32t)h << 16); }
__device__ inline u16t f2h(float f) {
  _Float16 h = (_Float16)f;
  return *(u16t*)&h;
}
__device__ inline float h2f(u16t v) {
  _Float16 h = *(_Float16*)&v;
  return (float)h;
}
__device__ inline void add8h(float* a, uint4 v) {
  union { uint4 u; _Float16 h[8]; } cv;
  cv.u = v;
#pragma unroll
  for (int j = 0; j < 8; ++j) a[j] += (float)cv.h[j];
}

// ---- workspace layout (bytes) ----
static const size_t OFF_U    = 0;           // fp16 64MB; also YB
static const size_t OFF_YA   = 130000000;
static const size_t OFF_ST   = 258000000;
static const size_t OFF_RS   = 259000000;
static const size_t OFF_CUR  = 263200000;   // CSR cursor; PERM overlays after k_scatter
static const size_t OFF_BSUM = 267300000;
static const size_t OFF_SSRC = 268000000;
static const size_t OFF_WK   = 285000000;
static const size_t OFF_XC   = 287000000;
static const size_t OFF_T3   = 0;
static const size_t OFF_H1   = 150000000;
static const size_t OFF_H2   = 210000000;

// ---------------- CSR build ----------------
__global__ __launch_bounds__(256) void k_hist(const int* __restrict__ ei, u32t* __restrict__ cnt) {
  const int i = blockIdx.x * 256 + threadIdx.x;
  if (i < NE) atomicAdd(&cnt[ei[NE + i]], 1u);
}

__global__ __launch_bounds__(256) void k_scan1(const u32t* __restrict__ deg, u32t* __restrict__ bsum) {
  __shared__ u32t red[4];
  const int b = blockIdx.x, t = threadIdx.x;
  u32t s = 0;
#pragma unroll
  for (int j = 0; j < 4; ++j) {
    const int i = b * 1024 + j * 256 + t;
    if (i < NN) s += deg[i];
  }
#pragma unroll
  for (int off = 32; off > 0; off >>= 1) s += __shfl_down(s, off);
  if ((t & 63) == 0) red[t >> 6] = s;
  __syncthreads();
  if (t == 0) bsum[b] = red[0] + red[1] + red[2] + red[3];
}

__global__ __launch_bounds__(256) void k_scan2(u32t* __restrict__ bsum, u32t* __restrict__ rs, int nblk) {
  __shared__ u32t sh[256];
  const int t = threadIdx.x;
  u32t v[4];
#pragma unroll
  for (int j = 0; j < 4; ++j) {
    const int i = t * 4 + j;
    v[j] = (i < nblk) ? bsum[i] : 0u;
  }
  const u32t tot = v[0] + v[1] + v[2] + v[3];
  sh[t] = tot;
  __syncthreads();
  for (int off = 1; off < 256; off <<= 1) {
    u32t add = (t >= off) ? sh[t - off] : 0u;
    __syncthreads();
    sh[t] += add;
    __syncthreads();
  }
  const u32t tb = (t == 0) ? 0u : sh[t - 1];
  u32t run = tb;
#pragma unroll
  for (int j = 0; j < 4; ++j) {
    const int i = t * 4 + j;
    if (i < nblk) bsum[i] = run;
    run += v[j];
  }
  if (t == 0) rs[NN] = NE;
}

__global__ __launch_bounds__(256) void k_scan3(u32t* __restrict__ cur, u32t* __restrict__ rs,
                                               const u32t* __restrict__ bsum) {
  __shared__ u32t sh[256];
  const int b = blockIdx.x, t = threadIdx.x;
  const int i0 = b * 1024 + t * 4;
  u32t v[4];
#pragma unroll
  for (int j = 0; j < 4; ++j) v[j] = (i0 + j < NN) ? cur[i0 + j] : 0u;
  sh[t] = v[0] + v[1] + v[2] + v[3];
  __syncthreads();
  for (int off = 1; off < 256; off <<= 1) {
    u32t add = (t >= off) ? sh[t - off] : 0u;
    __syncthreads();
    sh[t] += add;
    __syncthreads();
  }
  u32t run = bsum[b] + ((t == 0) ? 0u : sh[t - 1]);
#pragma unroll
  for (int j = 0; j < 4; ++j) {
    const int i = i0 + j;
    if (i < NN) { rs[i] = run; cur[i] = run; }
    run += v[j];
  }
}

__global__ __launch_bounds__(256) void k_scatter(const int* __restrict__ ei,
                                                 u32t* __restrict__ cur, int* __restrict__ ssrc) {
  const int i = blockIdx.x * 256 + threadIdx.x;
  if (i < NE) {
    const int src = ei[i], dst = ei[NE + i];
    const u32t pos = atomicAdd(&cur[dst], 1u);
    ssrc[pos] = src;
  }
}

// ---------------- degree-sort permutation (counting sort, 64 bins) ----------------
__global__ __launch_bounds__(256) void k_dhist(const u32t* __restrict__ rs, u32t* __restrict__ dh) {
  __shared__ u32t h[64];
  const int t = threadIdx.x;
  if (t < 64) h[t] = 0;
  __syncthreads();
#pragma unroll
  for (int j = 0; j < 4; ++j) {
    const int n = blockIdx.x * 1024 + j * 256 + t;
    if (n < NN) {
      u32t d = rs[n + 1] - rs[n];
      d = d > 63u ? 63u : d;
      atomicAdd(&h[d], 1u);
    }
  }
  __syncthreads();
  if (t < 64 && h[t]) atomicAdd(&dh[t], h[t]);
}

__global__ __launch_bounds__(64) void k_dscan(const u32t* __restrict__ dh, u32t* __restrict__ dc) {
  __shared__ u32t sh[64];
  const int t = threadIdx.x;
  sh[t] = dh[t];
  __syncthreads();
  for (int off = 1; off < 64; off <<= 1) {
    u32t v = (t >= off) ? sh[t - off] : 0u;
    __syncthreads();
    sh[t] += v;
    __syncthreads();
  }
  dc[t] = (t == 0) ? 0u : sh[t - 1];
}

__global__ __launch_bounds__(256) void k_dscatter(const u32t* __restrict__ rs, u32t* __restrict__ dc,
                                                  u32t* __restrict__ perm) {
  __shared__ u32t h[64], base[64];
  const int t = threadIdx.x;
  u32t d[4], loc[4];
  if (t < 64) h[t] = 0;
  __syncthreads();
#pragma unroll
  for (int j = 0; j < 4; ++j) {
    const int n = blockIdx.x * 1024 + j * 256 + t;
    if (n < NN) {
      u32t dd = rs[n + 1] - rs[n];
      dd = dd > 63u ? 63u : dd;
      d[j] = dd;
      loc[j] = atomicAdd(&h[dd], 1u);
    } else d[j] = 64u;
  }
  __syncthreads();
  if (t < 64) base[t] = h[t] ? atomicAdd(&dc[t], h[t]) : 0u;
  __syncthreads();
#pragma unroll
  for (int j = 0; j < 4; ++j) {
    const int n = blockIdx.x * 1024 + j * 256 + t;
    if (d[j] < 64u) perm[base[d[j]] + loc[j]] = (u32t)n;
  }
}

// ---------------- GNN kernels ----------------

__global__ __launch_bounds__(256) void k_mlp1_first(
    const float* __restrict__ x, const float* __restrict__ W1, u16t* __restrict__ u)
{
  __shared__ float Wt[78 * 33];
  __shared__ float xt_[8 * 79];
  const int t = threadIdx.x;
  for (int id = t; id < 78 * 32; id += 256) {
    int k = id >> 5, c = id & 31;
    Wt[k * 33 + c] = W1[id];
  }
  const int c = t & 31, nl = t >> 5;
  const int ntiles = NN / 8;
  for (int tile = blockIdx.x; tile < ntiles; tile += gridDim.x) {
    const int n0 = tile * 8;
    __syncthreads();
    for (int id = t; id < 8 * 78; id += 256) {
      int r = id / 78, k = id - r * 78;
      xt_[r * 79 + k] = x[(size_t)n0 * 78 + id];
    }
    __syncthreads();
    float acc = 0.f;
    const float* xr = xt_ + nl * 79;
#pragma unroll
    for (int k = 0; k < 78; ++k) acc = fmaf(xr[k], Wt[k * 33 + c], acc);
    u[(size_t)(n0 + nl) * 32 + c] = f2h(acc);
  }
}

// layer0 part B: 64 (degree-sorted) nodes/block, 4 lanes x 16B per node row
__global__ __launch_bounds__(256) void k_agg0(
    const u16t* __restrict__ u, const u32t* __restrict__ rs, const int* __restrict__ ssrc,
    const u32t* __restrict__ perm,
    const float* __restrict__ b1, const float* __restrict__ W2, const float* __restrict__ b2,
    u16t* __restrict__ yout, float* __restrict__ stats_out)
{
  __shared__ float W2s[32 * 33];
  __shared__ float A1[64 * 33];
  __shared__ float red[256];
  __shared__ u32t pm[64];
  const int t = threadIdx.x;
  for (int id = t; id < 1024; id += 256) {
    int k = id >> 5, c = id & 31;
    W2s[k * 33 + c] = W2[id];
  }
  if (t < 64) pm[t] = perm[blockIdx.x * 64 + t];
  __syncthreads();
  const int nl = t >> 2, c0 = (t & 3) * 8;
  const int pn = (int)pm[nl];
  float a[8] = {};
  add8h(a, *(const uint4*)(u + (size_t)pn * 32 + c0));
  const u32t e0 = rs[pn], e1 = rs[pn + 1];
  u32t e = e0;
  for (; e + 4 <= e1; e += 4) {
    const int s0v = ssrc[e], s1v = ssrc[e + 1], s2v = ssrc[e + 2], s3v = ssrc[e + 3];
    const uint4 v0 = *(const uint4*)(u + (size_t)s0v * 32 + c0);
    const uint4 v1 = *(const uint4*)(u + (size_t)s1v * 32 + c0);
    const uint4 v2 = *(const uint4*)(u + (size_t)s2v * 32 + c0);
    const uint4 v3 = *(const uint4*)(u + (size_t)s3v * 32 + c0);
    add8h(a, v0); add8h(a, v1); add8h(a, v2); add8h(a, v3);
  }
  for (; e < e1; ++e)
    add8h(a, *(const uint4*)(u + (size_t)ssrc[e] * 32 + c0));
  float* hp = A1 + nl * 33 + c0;
#pragma unroll
  for (int j = 0; j < 8; ++j) hp[j] = fmaxf(a[j] + b1[c0 + j], 0.f);
  __syncthreads();
  const int c = t & 31;
  const float b2v = b2[c];
  float rsum = 0.f, rq = 0.f;
#pragma unroll
  for (int rep = 0; rep < 8; ++rep) {
    const int row = (t >> 5) + rep * 8;
    const float* hr = A1 + row * 33;
    float acc = b2v;
#pragma unroll
    for (int k = 0; k < 32; ++k) acc = fmaf(hr[k], W2s[k * 33 + c], acc);
    acc = fmaxf(acc, 0.f);
    yout[(size_t)pm[row] * 32 + c] = f2h(acc);
    rsum += acc;
    rq += acc * acc;
  }
  rsum += __shfl_down(rsum, 32);
  rq += __shfl_down(rq, 32);
  __syncthreads();
  const int wv_ = t >> 6, lane = t & 63;
  if (lane < 32) {
    red[wv_ * 32 + lane] = rsum;
    red[128 + wv_ * 32 + lane] = rq;
  }
  __syncthreads();
  if (t < 32) {
    float aa = red[t] + red[32 + t] + red[64 + t] + red[96 + t];
    float bb = red[128 + t] + red[160 + t] + red[192 + t] + red[224 + t];
    unsafeAtomicAdd(&stats_out[t], aa);
    unsafeAtomicAdd(&stats_out[32 + t], bb);
  }
}

// layers 1..4: 64 (degree-sorted) nodes/block
__global__ __launch_bounds__(256) void k_layer(
    const u16t* __restrict__ yin, const u32t* __restrict__ rs, const int* __restrict__ ssrc,
    const u32t* __restrict__ perm,
    const float* __restrict__ stats, const float* __restrict__ gamma, const float* __restrict__ beta,
    const float* __restrict__ W1, const float* __restrict__ b1,
    const float* __restrict__ W2, const float* __restrict__ b2,
    u16t* __restrict__ yout, float* __restrict__ stats_out)
{
  __shared__ float W1s[32 * 33];
  __shared__ float W2s[32 * 33];
  __shared__ float A1[64 * 33];
  __shared__ float A2[64 * 33];
  __shared__ float red[256];
  __shared__ u32t pm[64];
  const int t = threadIdx.x;
  for (int id = t; id < 1024; id += 256) {
    int k = id >> 5, c = id & 31;
    W1s[k * 33 + c] = W1[id];
    W2s[k * 33 + c] = W2[id];
  }
  if (t < 64) pm[t] = perm[blockIdx.x * 64 + t];
  __syncthreads();
  const int nl = t >> 2, c0 = (t & 3) * 8;
  const int pn = (int)pm[nl];
  float sc[8], sh[8];
#pragma unroll
  for (int j = 0; j < 8; ++j) {
    const int c = c0 + j;
    const float mu = stats[c] * (1.f / NN);
    float var = fmaxf(stats[32 + c] * (1.f / NN) - mu * mu, 0.f);
    sc[j] = gamma[c] * rsqrtf(var + BN_EPS);
    sh[j] = beta[c] - mu * sc[j];
  }
  float a[8] = {};
  add8h(a, *(const uint4*)(yin + (size_t)pn * 32 + c0));
  const u32t e0 = rs[pn], e1 = rs[pn + 1];
  u32t e = e0;
  for (; e + 4 <= e1; e += 4) {
    const int s0v = ssrc[e], s1v = ssrc[e + 1], s2v = ssrc[e + 2], s3v = ssrc[e + 3];
    const uint4 v0 = *(const uint4*)(yin + (size_t)s0v * 32 + c0);
    const uint4 v1 = *(const uint4*)(yin + (size_t)s1v * 32 + c0);
    const uint4 v2 = *(const uint4*)(yin + (size_t)s2v * 32 + c0);
    const uint4 v3 = *(const uint4*)(yin + (size_t)s3v * 32 + c0);
    add8h(a, v0); add8h(a, v1); add8h(a, v2); add8h(a, v3);
  }
  for (; e < e1; ++e)
    add8h(a, *(const uint4*)(yin + (size_t)ssrc[e] * 32 + c0));
  const float cnt = (float)(e1 - e0 + 1u);
  float* hp = A1 + nl * 33 + c0;
#pragma unroll
  for (int j = 0; j < 8; ++j) hp[j] = sc[j] * a[j] + cnt * sh[j];
  __syncthreads();
  const int c = t & 31;
  const float b1v = b1[c];
#pragma unroll
  for (int rep = 0; rep < 8; ++rep) {
    const int row = (t >> 5) + rep * 8;
    const float* hr = A1 + row * 33;
    float acc = b1v;
#pragma unroll
    for (int k = 0; k < 32; ++k) acc = fmaf(hr[k], W1s[k * 33 + c], acc);
    A2[row * 33 + c] = fmaxf(acc, 0.f);
  }
  __syncthreads();
  const float b2v = b2[c];
  float rsum = 0.f, rq = 0.f;
#pragma unroll
  for (int rep = 0; rep < 8; ++rep) {
    const int row = (t >> 5) + rep * 8;
    const float* hr = A2 + row * 33;
    float acc = b2v;
#pragma unroll
    for (int k = 0; k < 32; ++k) acc = fmaf(hr[k], W2s[k * 33 + c], acc);
    acc = fmaxf(acc, 0.f);
    yout[(size_t)pm[row] * 32 + c] = f2h(acc);
    rsum += acc;
    rq += acc * acc;
  }
  rsum += __shfl_down(rsum, 32);
  rq += __shfl_down(rq, 32);
  __syncthreads();
  const int wv_ = t >> 6, lane = t & 63;
  if (lane < 32) {
    red[wv_ * 32 + lane] = rsum;
    red[128 + wv_ * 32 + lane] = rq;
  }
  __syncthreads();
  if (t < 32) {
    float aa = red[t] + red[32 + t] + red[64 + t] + red[96 + t];
    float bb = red[128 + t] + red[160 + t] + red[192 + t] + red[224 + t];
    unsafeAtomicAdd(&stats_out[t], aa);
    unsafeAtomicAdd(&stats_out[32 + t], bb);
  }
}

__global__ __launch_bounds__(64) void k_pool_xd(
    const u16t* __restrict__ y, const int* __restrict__ batch,
    const float* __restrict__ stats, const float* __restrict__ gamma,
    const float* __restrict__ beta, const float* __restrict__ Wxd,
    const float* __restrict__ bxd, u16t* __restrict__ xc)
{
  const int g = blockIdx.x, t = threadIdx.x;
  int lo = 0, n = NN;
  while (n > 0) {
    int h = n >> 1, m = lo + h;
    if (batch[m] < g) { lo = m + 1; n -= h + 1; } else n = h;
  }
  int hi = lo;
  n = NN - lo;
  while (n > 0) {
    int h = n >> 1, m = hi + h;
    if (batch[m] < g + 1) { hi = m + 1; n -= h + 1; } else n = h;
  }
  const int c = t & 31;
  const float mu = stats[4 * 64 + c] * (1.f / NN);
  float var = fmaxf(stats[4 * 64 + 32 + c] * (1.f / NN) - mu * mu, 0.f);
  const float sc = gamma[4 * 32 + c] * rsqrtf(var + BN_EPS);
  const float sh = beta[4 * 32 + c] - mu * sc;
  float acc = 0.f;
  for (int i = lo + (t >> 5); i < hi; i += 2) acc += h2f(y[(size_t)i * 32 + c]);
  acc += __shfl_down(acc, 32);
  __shared__ float pl[32];
  if (t < 32) pl[t] = acc * sc + (float)(hi - lo) * sh;
  __syncthreads();
#pragma unroll
  for (int rep = 0; rep < 2; ++rep) {
    const int o = t + rep * 64;
    float a = bxd[o];
#pragma unroll
    for (int cc = 0; cc < 32; ++cc) a = fmaf(pl[cc], Wxd[cc * 128 + o], a);
    xc[(size_t)g * 256 + o] = f2bf(fmaxf(a, 0.f));
  }
}

// ---------------- weight prep ----------------
__global__ __launch_bounds__(256) void k_prep(
    const float* __restrict__ w2, const float* __restrict__ w3,
    const float* __restrict__ wxt, const float* __restrict__ wf1, const float* __restrict__ wf2,
    u16t* __restrict__ W2k, u16t* __restrict__ W3k,
    u16t* __restrict__ WXT, u16t* __restrict__ WF1, u16t* __restrict__ WF2)
{
  const int i = blockIdx.x * 256 + threadIdx.x;
  if (i < 64 * 256) {
    int c2 = i >> 8, kk = i & 255, tt = kk >> 5, ci = kk & 31;
    W2k[i] = f2bf(w2[c2 * 256 + ci * 8 + tt]);
  }
  if (i < 128 * 512) {
    int c3 = i >> 9, kk = i & 511, tt = kk >> 6, ci = kk & 63;
    W3k[i] = f2bf(w3[c3 * 512 + ci * 8 + tt]);
  }
  if (i < 128 * 2944) {
    int nn = i / 2944, kk = i - nn * 2944;
    WXT[i] = f2bf(wxt[kk * 128 + nn]);
  }
  if (i < 1024 * 256) {
    int nn = i >> 8, kk = i & 255;
    WF1[i] = f2bf(wf1[kk * 1024 + nn]);
  }
  if (i < 128 * 1024) {
    int nn = i >> 10, kk = i & 1023;
    WF2[i] = f2bf(wf2[kk * 128 + nn]);
  }
}

// ---------------- fused per-graph CNN (unchanged from round 9) ----------------
__global__ __launch_bounds__(256, 4) void k_cnn(
    const float* __restrict__ xo,
    const float* __restrict__ w1, const float* __restrict__ b1,
    const u16t* __restrict__ W2k, const float* __restrict__ b2,
    const u16t* __restrict__ W3k, const float* __restrict__ b3,
    u16t* __restrict__ t3)
{
  __shared__ __align__(16) char smem[30720];
  float* xot = (float*)(smem);
  float* w1s = (float*)(smem + 3072);
  float* b2s = (float*)(smem + 4096);
  float* b3s = (float*)(smem + 4352);
  short* T1T = (short*)(smem + 4864);
  char*  T2B = smem + 20736;
  u16t*  stg = (u16t*)(smem + 4864);

  const int g = blockIdx.x, t = threadIdx.x;
  const int w = t >> 6, l = t & 63, col = l & 15, kg = l >> 4;

  for (int i = t; i < 768; i += 256) xot[i] = (i < 735) ? xo[(size_t)g * 735 + i] : 0.f;
  w1s[t] = w1[t];
  if (t < 64) b2s[t] = b2[t];
  if (t < 128) b3s[t] = b3[t];
  if (t < 192) {
    int r = 242 + (t >> 5), c = t & 31;
    T1T[r * 32 + c] = 0;
  }
  __syncthreads();

  {
    const int c = t >> 3, qg = t & 7;
    float wv[8];
#pragma unroll
    for (int j = 0; j < 8; ++j) wv[j] = w1s[c * 8 + j];
    const float bias = b1[c];
    const int q0 = qg * 31, qe = (q0 + 31 < 242) ? q0 + 31 : 242;
#pragma unroll 1
    for (int qc = q0; qc < qe; qc += 10) {
      const int cnt = (qe - qc < 10) ? qe - qc : 10;
      float xv[37];
#pragma unroll
      for (int j = 0; j < 37; ++j) xv[j] = xot[3 * qc + j];
#pragma unroll
      for (int j0 = 0; j0 < 10; ++j0) {
        if (j0 < cnt) {
          float a0 = bias, a1 = bias, a2 = bias;
#pragma unroll
          for (int tt = 0; tt < 8; ++tt) {
            a0 = fmaf(wv[tt], xv[3 * j0 + tt], a0);
            a1 = fmaf(wv[tt], xv[3 * j0 + 1 + tt], a1);
            a2 = fmaf(wv[tt], xv[3 * j0 + 2 + tt], a2);
          }
          float m = fmaxf(fmaxf(a0, a1), fmaxf(a2, 0.f));
          const int pos = qc + j0;
          T1T[pos * 32 + (c ^ ((pos & 3) << 3))] = (short)f2bf(m);
        }
      }
    }
  }
  __syncthreads();

  {
    bf16x8 am[8];
#pragma unroll
    for (int kk = 0; kk < 8; ++kk)
      am[kk] = *(const bf16x8*)(W2k + (w * 16 + col) * 256 + kk * 32 + kg * 8);
#pragma unroll 1
    for (int qt = 0; qt < 5; ++qt) {
      const int rbase = qt * 48 + col * 3;
      bf16x8 rv[10];
#pragma unroll
      for (int s = 0; s < 10; ++s) {
        const int row = rbase + s;
        rv[s] = *(const bf16x8*)(T1T + row * 32 + ((kg ^ (row & 3)) << 3));
      }
      f32x4 a0 = {0.f, 0.f, 0.f, 0.f}, a1 = a0, a2 = a0;
#pragma unroll
      for (int kk = 0; kk < 8; ++kk) {
        a0 = __builtin_amdgcn_mfma_f32_16x16x32_bf16(am[kk], rv[kk], a0, 0, 0, 0);
        a1 = __builtin_amdgcn_mfma_f32_16x16x32_bf16(am[kk], rv[kk + 1], a1, 0, 0, 0);
        a2 = __builtin_amdgcn_mfma_f32_16x16x32_bf16(am[kk], rv[kk + 2], a2, 0, 0, 0);
      }
      const int q = qt * 16 + col;
      if (q < 78) {
        union { u16t u[4]; uint2 v; } pk;
#pragma unroll
        for (int r = 0; r < 4; ++r) {
          const float bb = b2s[w * 16 + kg * 4 + r];
          float m = fmaxf(fmaxf(a0[r], a1[r]), a2[r]);
          pk.u[r] = f2bf(fmaxf(m + bb, 0.f));
        }
        const int boff = (q * 128 + (w * 16 + kg * 4) * 2) ^ ((q & 7) << 4);
        *(uint2*)(T2B + boff) = pk.v;
      }
    }
  }
  __syncthreads();

  {
#pragma unroll 1
    for (int mi = 0; mi < 2; ++mi) {
      const int m3 = w * 2 + mi;
      f32x4 acc[2][3];
#pragma unroll
      for (int qt = 0; qt < 2; ++qt)
#pragma unroll
        for (int r = 0; r < 3; ++r) acc[qt][r] = (f32x4){0.f, 0.f, 0.f, 0.f};
#pragma unroll 1
      for (int kh = 0; kh < 2; ++kh) {
        bf16x8 amh[8];
#pragma unroll
        for (int tt = 0; tt < 8; ++tt)
          amh[tt] = *(const bf16x8*)(W3k + (m3 * 16 + col) * 512 + (tt * 2 + kh) * 32 + kg * 8);
#pragma unroll
        for (int qt = 0; qt < 2; ++qt) {
          const int rbase = qt * 48 + col * 3;
          bf16x8 rv[10];
#pragma unroll
          for (int s = 0; s < 10; ++s) {
            int row = rbase + s;
            row = (row < 78) ? row : 77;
            const int boff = (row * 128 + kh * 64 + kg * 16) ^ ((row & 7) << 4);
            rv[s] = *(const bf16x8*)(T2B + boff);
          }
#pragma unroll
          for (int tt = 0; tt < 8; ++tt) {
            acc[qt][0] = __builtin_amdgcn_mfma_f32_16x16x32_bf16(amh[tt], rv[tt], acc[qt][0], 0, 0, 0);
            acc[qt][1] = __builtin_amdgcn_mfma_f32_16x16x32_bf16(amh[tt], rv[tt + 1], acc[qt][1], 0, 0, 0);
            acc[qt][2] = __builtin_amdgcn_mfma_f32_16x16x32_bf16(amh[tt], rv[tt + 2], acc[qt][2], 0, 0, 0);
          }
        }
      }
#pragma unroll
      for (int qt = 0; qt < 2; ++qt) {
        const int q = qt * 16 + col;
        if (q < 23) {
#pragma unroll
          for (int r = 0; r < 4; ++r) {
            const int c = m3 * 16 + kg * 4 + r;
            float m = fmaxf(fmaxf(acc[qt][0][r], acc[qt][1][r]), acc[qt][2][r]);
            stg[c * 23 + q] = f2bf(fmaxf(m + b3s[c], 0.f));
          }
        }
      }
    }
  }
  __syncthreads();

  {
    const uint4* s4 = (const uint4*)stg;
    uint4* d4 = (uint4*)(t3 + (size_t)g * 2944);
    for (int id = t; id < 368; id += 256) d4[id] = s4[id];
  }
}

// ---------------- bf16 MFMA GEMM ----------------
__global__ __launch_bounds__(256) void k_mgemm(
    const u16t* __restrict__ A, int lda,
    const u16t* __restrict__ WT, const float* __restrict__ bias,
    void* __restrict__ Cv, int ldc, int c_off, int M, int Kd,
    int relu_f, int out32)
{
  __shared__ __align__(16) u16t As[128 * 4 * 8];
  __shared__ __align__(16) u16t Ws2[64 * 4 * 8];
  const int t = threadIdx.x;
  const int w = t >> 6, l = t & 63, col = l & 15, kg = l >> 4;
  const int wm = w & 1, wn = w >> 1;
  const int m0 = blockIdx.x * 128, n0 = blockIdx.y * 64;
  f32x4 acc[4][2];
#pragma unroll
  for (int i = 0; i < 4; ++i)
#pragma unroll
    for (int j = 0; j < 2; ++j) acc[i][j] = (f32x4){0.f, 0.f, 0.f, 0.f};
  const int ar = t >> 1, ac = (t & 1) * 2;
  const int wr = t >> 2, wc = t & 3;
  const bool aok = (m0 + ar) < M;
  const u16t* Ap = A + (size_t)(m0 + ar) * lda;
  const u16t* Wp = WT + (size_t)(n0 + wr) * Kd;
  for (int k0 = 0; k0 < Kd; k0 += 32) {
    bf16x8 av0 = {0, 0, 0, 0, 0, 0, 0, 0}, av1 = {0, 0, 0, 0, 0, 0, 0, 0};
    if (aok) {
      av0 = *(const bf16x8*)(Ap + k0 + ac * 8);
      av1 = *(const bf16x8*)(Ap + k0 + (ac + 1) * 8);
    }
    const bf16x8 wv = *(const bf16x8*)(Wp + k0 + wc * 8);
    __syncthreads();
    *(bf16x8*)(As + (ar * 4 + (ac ^ (ar & 3))) * 8) = av0;
    *(bf16x8*)(As + (ar * 4 + ((ac + 1) ^ (ar & 3))) * 8) = av1;
    *(bf16x8*)(Ws2 + (wr * 4 + (wc ^ (wr & 3))) * 8) = wv;
    __syncthreads();
    bf16x8 af[4], bf[2];
#pragma unroll
    for (int i = 0; i < 4; ++i) {
      const int R = wm * 64 + i * 16 + col;
      af[i] = *(const bf16x8*)(As + (R * 4 + (kg ^ (R & 3))) * 8);
    }
#pragma unroll
    for (int j = 0; j < 2; ++j) {
      const int R = wn * 32 + j * 16 + col;
      bf[j] = *(const bf16x8*)(Ws2 + (R * 4 + (kg ^ (R & 3))) * 8);
    }
#pragma unroll
    for (int i = 0; i < 4; ++i)
#pragma unroll
      for (int j = 0; j < 2; ++j)
        acc[i][j] = __builtin_amdgcn_mfma_f32_16x16x32_bf16(af[i], bf[j], acc[i][j], 0, 0, 0);
  }
#pragma unroll
  for (int j = 0; j < 2; ++j) {
    const int gn = n0 + wn * 32 + j * 16 + col;
    const float bb = bias[gn];
#pragma unroll
    for (int i = 0; i < 4; ++i) {
      const int gmb = m0 + wm * 64 + i * 16 + kg * 4;
#pragma unroll
      for (int r = 0; r < 4; ++r) {
        const int gm = gmb + r;
        if (gm < M) {
          float v = acc[i][j][r] + bb;
          if (relu_f) v = fmaxf(v, 0.f);
          if (out32) ((float*)Cv)[(size_t)gm * ldc + c_off + gn] = v;
          else ((u16t*)Cv)[(size_t)gm * ldc + c_off + gn] = f2bf(v);
        }
      }
    }
  }
}

__global__ __launch_bounds__(256) void k_out(
    const float* __restrict__ h2, const float* __restrict__ Wo,
    const float* __restrict__ bo, float* __restrict__ out)
{
  __shared__ float Ws_[128];
  const int t = threadIdx.x;
  if (t < 128) Ws_[t] = Wo[t];
  __syncthreads();
  const int g = blockIdx.x * 32 + (t >> 3), l = t & 7;
  float acc = 0.f;
  if (g < NG) {
    const float* hr = h2 + (size_t)g * 128 + l * 16;
    const float* wr = Ws_ + l * 16;
#pragma unroll
    for (int j = 0; j < 16; ++j) acc = fmaf(hr[j], wr[j], acc);
  }
  acc += __shfl_down(acc, 4, 8);
  acc += __shfl_down(acc, 2, 8);
  acc += __shfl_down(acc, 1, 8);
  if (l == 0 && g < NG) out[g] = acc + bo[0];
}

extern "C" void kernel_launch(void* const* d_in, const int* in_sizes, int n_in,
                              void* d_out, int out_size, void* d_ws, size_t ws_size,
                              hipStream_t stream) {
  const float* x    = (const float*)d_in[0];
  const int*   ei   = (const int*)d_in[1];
  const int*   batch= (const int*)d_in[2];
  const float* xo   = (const float*)d_in[3];
  const float* g1W1 = (const float*)d_in[4];
  const float* g1b1 = (const float*)d_in[5];
  const float* g1W2 = (const float*)d_in[6];
  const float* g1b2 = (const float*)d_in[7];
  const float* gsW1 = (const float*)d_in[8];
  const float* gsb1 = (const float*)d_in[9];
  const float* gsW2 = (const float*)d_in[10];
  const float* gsb2 = (const float*)d_in[11];
  const float* bng  = (const float*)d_in[12];
  const float* bnb  = (const float*)d_in[13];
  const float* Wxd  = (const float*)d_in[14];
  const float* bxd  = (const float*)d_in[15];
  const float* c1W  = (const float*)d_in[16];
  const float* c1b  = (const float*)d_in[17];
  const float* c2W  = (const float*)d_in[18];
  const float* c2b  = (const float*)d_in[19];
  const float* c3W  = (const float*)d_in[20];
  const float* c3b  = (const float*)d_in[21];
  const float* Wxt  = (const float*)d_in[22];
  const float* bxt  = (const float*)d_in[23];
  const float* W1f  = (const float*)d_in[24];
  const float* b1f  = (const float*)d_in[25];
  const float* W2f  = (const float*)d_in[26];
  const float* b2f  = (const float*)d_in[27];
  const float* Wo   = (const float*)d_in[28];
  const float* bo   = (const float*)d_in[29];

  char* ws = (char*)d_ws;
  u16t*  U   = (u16t*)(ws + OFF_U);
  u16t*  YA  = (u16t*)(ws + OFF_YA);
  u16t*  YB  = (u16t*)(ws + OFF_U);
  float* ST  = (float*)(ws + OFF_ST);
  u32t*  RS  = (u32t*)(ws + OFF_RS);
  u32t*  CUR = (u32t*)(ws + OFF_CUR);
  u32t*  BS  = (u32t*)(ws + OFF_BSUM);
  u32t*  DH  = (u32t*)(ws + OFF_BSUM + 4096);
  u32t*  DC  = (u32t*)(ws + OFF_BSUM + 4352);
  u32t*  PERM= (u32t*)(ws + OFF_CUR);        // overlays CUR after k_scatter
  int*   SSRC= (int*)(ws + OFF_SSRC);
  u16t*  WK  = (u16t*)(ws + OFF_WK);
  u16t*  W2K = WK;
  u16t*  W3K = WK + 16384;
  u16t*  WXT = WK + 16384 + 65536;
  u16t*  WF1 = WK + 16384 + 65536 + 376832;
  u16t*  WF2 = WK + 16384 + 65536 + 376832 + 262144;
  u16t*  XC  = (u16t*)(ws + OFF_XC);
  u16t*  T3  = (u16t*)(ws + OFF_T3);
  u16t*  H1  = (u16t*)(ws + OFF_H1);
  float* H2  = (float*)(ws + OFF_H2);
  float* OUT = (float*)d_out;

  const int NBLK = (NN + 1023) / 1024;

  hipMemsetAsync(ST, 0, 5 * 64 * sizeof(float), stream);
  hipMemsetAsync(CUR, 0, NN * sizeof(u32t), stream);
  hipMemsetAsync(DH, 0, 64 * sizeof(u32t), stream);

  k_prep<<<(128 * 2944 + 255) / 256, 256, 0, stream>>>(c2W, c3W, Wxt, W1f, W2f,
                                                        W2K, W3K, WXT, WF1, WF2);

  k_hist<<<(NE + 255) / 256, 256, 0, stream>>>(ei, CUR);
  k_scan1<<<NBLK, 256, 0, stream>>>(CUR, BS);
  k_scan2<<<1, 256, 0, stream>>>(BS, RS, NBLK);
  k_scan3<<<NBLK, 256, 0, stream>>>(CUR, RS, BS);
  k_scatter<<<(NE + 255) / 256, 256, 0, stream>>>(ei, CUR, SSRC);

  // degree-sorted permutation (waves get uniform-degree nodes -> no gather divergence)
  k_dhist<<<NBLK, 256, 0, stream>>>(RS, DH);
  k_dscan<<<1, 64, 0, stream>>>(DH, DC);
  k_dscatter<<<NBLK, 256, 0, stream>>>(RS, DC, PERM);

  k_mlp1_first<<<2048, 256, 0, stream>>>(x, g1W1, U);
  k_agg0<<<NN / 64, 256, 0, stream>>>(U, RS, SSRC, PERM, g1b1, g1W2, g1b2, YA, ST + 0);
  const u16t* yin = YA;
  u16t* yout = YB;
  for (int lyr = 1; lyr <= 4; ++lyr) {
    k_layer<<<NN / 64, 256, 0, stream>>>(yin, RS, SSRC, PERM, ST + (lyr - 1) * 64,
                                         bng + (lyr - 1) * 32, bnb + (lyr - 1) * 32,
                                         gsW1 + (lyr - 1) * 1024, gsb1 + (lyr - 1) * 32,
                                         gsW2 + (lyr - 1) * 1024, gsb2 + (lyr - 1) * 32,
                                         yout, ST + lyr * 64);
    const u16t* tmp = yin;
    yin = yout;
    yout = (u16t*)tmp;
  }
  k_pool_xd<<<NG, 64, 0, stream>>>(yin, batch, ST, bng, bnb, Wxd, bxd, XC);

  k_cnn<<<NG, 256, 0, stream>>>(xo, c1W, c1b, W2K, c2b, W3K, c3b, T3);

  {
    dim3 grid((NG + 127) / 128, 2);
    k_mgemm<<<grid, 256, 0, stream>>>(T3, 2944, WXT, bxt, XC, 256, 128, NG, 2944, 0, 0);
  }
  {
    dim3 grid((NG + 127) / 128, 16);
    k_mgemm<<<grid, 256, 0, stream>>>(XC, 256, WF1, b1f, H1, 1024, 0, NG, 256, 1, 0);
  }
  {
    dim3 grid((NG + 127) / 128, 2);
    k_mgemm<<<grid, 256, 0, stream>>>(H1, 1024, WF2, b2f, H2, 128, 0, NG, 1024, 1, 1);
  }
  k_out<<<(NG + 31) / 32, 256, 0, stream>>>(H2, Wo, bo, OUT);
}